// Round 2
// 876.180 us; speedup vs baseline: 2.7167x; 2.7167x over previous
//
#include <hip/hip_runtime.h>
#include <cstddef>

#define B 32
#define T_ENC 512
#define T_DEC 32
#define E 256
#define VOCAB 32000
#define SOS 1

typedef __attribute__((ext_vector_type(8))) short short8;   // 8 x bf16
typedef __attribute__((ext_vector_type(4))) float floatx4;  // MFMA acc

// ---------------- workspace layout (float offsets) ----------------
static const size_t OFF_ENCWM  = 0;                                    // 4194304
static const size_t OFF_ENCWC  = OFF_ENCWM + (size_t)B * T_ENC * E;    // 4194304
static const size_t OFF_WEFFM  = OFF_ENCWC + (size_t)B * T_ENC * E;    // 256
static const size_t OFF_WEFFC  = OFF_WEFFM + E;                        // 256
static const size_t OFF_BSUM   = OFF_WEFFC + E;                        // 256
static const size_t OFF_XIH    = OFF_BSUM + E;                         // 262144
static const size_t OFF_WHHT   = OFF_XIH + (size_t)T_DEC * B * E;      // 65536
static const size_t OFF_VMT    = OFF_WHHT + (size_t)E * E;             // 65536 (unused)
static const size_t OFF_VCT    = OFF_VMT + (size_t)E * E;              // 65536 (unused)
static const size_t OFF_WCOMBT = OFF_VCT + (size_t)E * E;              // 131072
static const size_t OFF_ATTNB  = OFF_WCOMBT + (size_t)2 * E * E;       // 131072 floats (ushort x2)
static const size_t OFF_WPBF   = OFF_ATTNB + (size_t)T_DEC * B * E / 2;// 4096000 floats (ushort x2)

// ---------------- d_out scratch layout (float offsets) ----------------
// d_out is 32.768M floats; everything here is consumed before proj_mfma
// overwrites d_out at the end of the launch sequence.
static const size_t OUT_EMBX  = 0;         // 262144 (consumed by Xih gemm)
static const size_t OUT_BETA  = 262144;    // 524288: beta[b][s][t]
static const size_t OUT_ACOMB = 786432;    // 524288: [ctx | h] rows (b*32+s) x 512
static const size_t OUT_HALL  = 1310720;   // 262144: h[b][s][256]
static const size_t OUT_HV    = 1572864;   // 524288: [hVm | hVc] rows (b*32+s) x 512
static const size_t OUT_PE    = 2097152;   // 1048576: g_pe[b][t][64] (sm:0-31, sc:32-63)
static const size_t OUT_VMC   = 3145728;   // 131072: [Vm ; Vc]
static const size_t OUT_ZERO  = 3276800;   // 512 zeros

// ---------------- helpers ----------------
__device__ __forceinline__ float ftanh(float x) {
  float ax = __builtin_fabsf(x);
  float e  = __expf(-2.f * ax);
  float r  = (1.f - e) * __builtin_amdgcn_rcpf(1.f + e);
  return __builtin_copysignf(r, x);
}

__device__ __forceinline__ float fsigmoid(float z) {
  return __builtin_amdgcn_rcpf(1.f + __expf(-z));
}

__device__ __forceinline__ float wredsum(float s) {
  s += __shfl_xor(s, 1, 64);  s += __shfl_xor(s, 2, 64);  s += __shfl_xor(s, 4, 64);
  s += __shfl_xor(s, 8, 64);  s += __shfl_xor(s, 16, 64); s += __shfl_xor(s, 32, 64);
  return s;
}

__device__ __forceinline__ float wredmax(float s) {
  s = fmaxf(s, __shfl_xor(s, 1, 64));  s = fmaxf(s, __shfl_xor(s, 2, 64));
  s = fmaxf(s, __shfl_xor(s, 4, 64));  s = fmaxf(s, __shfl_xor(s, 8, 64));
  s = fmaxf(s, __shfl_xor(s, 16, 64)); s = fmaxf(s, __shfl_xor(s, 32, 64));
  return s;
}

__device__ __forceinline__ unsigned short f2bf(float f) {
  unsigned int u = __float_as_uint(f);
  u = (u + 0x7fffu + ((u >> 16) & 1u)) >> 16;   // RNE
  return (unsigned short)u;
}

// Inclusive scan over 512 values held by tid<512; ALL 1024 threads must call.
__device__ __forceinline__ float scan512(float v, int tid, volatile float* wtot)
{
  const int lane = tid & 63, w = tid >> 6;
#pragma unroll
  for (int off = 1; off < 64; off <<= 1) {
    float y = __shfl_up(v, off, 64);
    if (lane >= off) v += y;
  }
  __syncthreads();                    // protect wtot reuse across consecutive scans
  if (tid < 512 && lane == 63) wtot[w] = v;
  __syncthreads();
  float add = 0.f;
#pragma unroll
  for (int i = 0; i < 7; i++) if (i < w) add += wtot[i];
  return v + add;
}

// ---------------- w_eff = (g/||vv||)*vv ----------------
__global__ __launch_bounds__(256) void weff_kernel(
    const float* __restrict__ vvm, const float* __restrict__ gm, float* __restrict__ w_effm,
    const float* __restrict__ vvc, const float* __restrict__ gc, float* __restrict__ w_effc)
{
  const float* vv = blockIdx.x ? vvc : vvm;
  const float* g  = blockIdx.x ? gc  : gm;
  float* out      = blockIdx.x ? w_effc : w_effm;
  __shared__ float red[256];
  int tid = threadIdx.x;
  float v = vv[tid];
  red[tid] = v * v;
  __syncthreads();
  for (int off = 128; off > 0; off >>= 1) {
    if (tid < off) red[tid] += red[tid + off];
    __syncthreads();
  }
  float norm = sqrtf(red[0]);
  out[tid] = (g[0] / norm) * v;
}

// ---------------- bsum = b_ih + b_hh ----------------
__global__ __launch_bounds__(256) void prep_bias(
    const float* __restrict__ b_ih, const float* __restrict__ b_hh, float* __restrict__ bsum)
{
  bsum[threadIdx.x] = b_ih[threadIdx.x] + b_hh[threadIdx.x];
}

// ---------------- out[c*R + r] = in[r*C + c] ----------------
__global__ __launch_bounds__(256) void transpose_k(
    const float* __restrict__ in, float* __restrict__ out, int R, int C)
{
  __shared__ float tl[32][33];
  const int tx = threadIdx.x & 31, ty = threadIdx.x >> 5;
  const int c0 = blockIdx.x * 32, r0 = blockIdx.y * 32;
#pragma unroll
  for (int k = 0; k < 4; k++)
    tl[ty + 8 * k][tx] = in[(size_t)(r0 + ty + 8 * k) * C + c0 + tx];
  __syncthreads();
#pragma unroll
  for (int k = 0; k < 4; k++)
    out[(size_t)(c0 + ty + 8 * k) * R + r0 + tx] = tl[tx][ty + 8 * k];
}

// ---------------- Vmc = [Vm ; Vc], zero512 = 0 ----------------
__global__ __launch_bounds__(256) void concat_v(
    const float* __restrict__ Vm, const float* __restrict__ Vc,
    float* __restrict__ Vmc, float* __restrict__ zero512)
{
  const int i = (blockIdx.x * 256 + threadIdx.x) * 4;   // grid 128 -> i < 131072
  float4 v;
  if (i < E * E) v = *(const float4*)(Vm + i);
  else           v = *(const float4*)(Vc + (i - E * E));
  *(float4*)(Vmc + i) = v;
  if (blockIdx.x < 2) zero512[blockIdx.x * 256 + threadIdx.x] = 0.f;
}

// ---------------- gather embeddings ----------------
__global__ __launch_bounds__(256) void gather_emb(
    const int* __restrict__ dec, const float* __restrict__ emb, float* __restrict__ embX)
{
  int r = blockIdx.x, d = threadIdx.x;
  int s = r >> 5, b = r & 31;
  int tok = (s == 0) ? SOS : dec[b * T_DEC + s - 1];
  embX[(size_t)r * E + d] = emb[(size_t)tok * E + d];
}

// ---------------- f32 -> bf16 convert ----------------
__global__ __launch_bounds__(256) void cvt_bf16(
    const float* __restrict__ src, unsigned short* __restrict__ dst)
{
  size_t i = ((size_t)blockIdx.x * 256 + threadIdx.x) * 4;
  float4 v = *(const float4*)(src + i);
  ushort4 o;
  o.x = f2bf(v.x); o.y = f2bf(v.y); o.z = f2bf(v.z); o.w = f2bf(v.w);
  *(ushort4*)(dst + i) = o;
}

// ---------------- Y[r,n] = bias[n] + sum_k A[r,k]*W[n,k] ----------------
__global__ __launch_bounds__(256) void gemm_xwt(
    const float* __restrict__ A, const float* __restrict__ W,
    const float* __restrict__ bias, float* __restrict__ Y,
    int M, int N, int K)
{
  __shared__ float As[64][68];
  __shared__ float Ws[64][68];
  const int tid = threadIdx.x;
  const int tx = tid & 15, ty = tid >> 4;
  const int row0 = blockIdx.y * 64, col0 = blockIdx.x * 64;
  float acc[4][4];
#pragma unroll
  for (int i = 0; i < 4; i++)
#pragma unroll
    for (int j = 0; j < 4; j++) acc[i][j] = 0.f;

  for (int k0 = 0; k0 < K; k0 += 64) {
#pragma unroll
    for (int s = 0; s < 4; s++) {
      int i = (s << 4) + ty;
      int j = tx << 2;
      float4 av = *(const float4*)(A + (size_t)(row0 + i) * K + k0 + j);
      As[j][i] = av.x; As[j + 1][i] = av.y; As[j + 2][i] = av.z; As[j + 3][i] = av.w;
      float4 wv = *(const float4*)(W + (size_t)(col0 + i) * K + k0 + j);
      Ws[j][i] = wv.x; Ws[j + 1][i] = wv.y; Ws[j + 2][i] = wv.z; Ws[j + 3][i] = wv.w;
    }
    __syncthreads();
#pragma unroll
    for (int kk = 0; kk < 64; kk++) {
      const float4 af = *(const float4*)&As[kk][ty << 2];
      const float4 bf = *(const float4*)&Ws[kk][tx << 2];
      acc[0][0] += af.x * bf.x; acc[0][1] += af.x * bf.y; acc[0][2] += af.x * bf.z; acc[0][3] += af.x * bf.w;
      acc[1][0] += af.y * bf.x; acc[1][1] += af.y * bf.y; acc[1][2] += af.y * bf.z; acc[1][3] += af.y * bf.w;
      acc[2][0] += af.z * bf.x; acc[2][1] += af.z * bf.y; acc[2][2] += af.z * bf.z; acc[2][3] += af.z * bf.w;
      acc[3][0] += af.w * bf.x; acc[3][1] += af.w * bf.y; acc[3][2] += af.w * bf.z; acc[3][3] += af.w * bf.w;
    }
    __syncthreads();
  }
  const float4 bv = *(const float4*)(bias + col0 + (tx << 2));
#pragma unroll
  for (int i = 0; i < 4; i++) {
    float4 o;
    o.x = acc[i][0] + bv.x; o.y = acc[i][1] + bv.y;
    o.z = acc[i][2] + bv.z; o.w = acc[i][3] + bv.w;
    *(float4*)(Y + (size_t)(row0 + (ty << 2) + i) * N + col0 + (tx << 2)) = o;
  }
}

// ---------------- h-chain: h[s+1] = tanh(Xih + W_hh h[s]), W_hh in registers
// One block per batch element; W_hh column-slice cached in VGPRs so the
// sequential part is pure VALU + LDS reduction (no per-step weight traffic).
__global__ __launch_bounds__(1024) void hchain_kernel(
    const float* __restrict__ Xih, const float* __restrict__ W_hhT,
    const float* __restrict__ h0,
    float* __restrict__ A_comb, float* __restrict__ h_all)
{
  __shared__ float h_s[E];
  __shared__ float red[1024];
  const int b = blockIdx.x, tid = threadIdx.x;
  const int c = tid >> 8, d = tid & 255, k0 = c * 64;
  float wreg[64];
#pragma unroll
  for (int j = 0; j < 64; ++j) wreg[j] = W_hhT[(size_t)(k0 + j) * E + d];
  if (tid < E) h_s[tid] = h0[(size_t)b * E + tid];
  __syncthreads();
  for (int s = 0; s < T_DEC; ++s) {
    float acc = 0.f;
#pragma unroll
    for (int j = 0; j < 64; j += 4) {
      float4 hh = *(const float4*)&h_s[k0 + j];
      acc += hh.x * wreg[j] + hh.y * wreg[j + 1] + hh.z * wreg[j + 2] + hh.w * wreg[j + 3];
    }
    red[tid] = acc;
    __syncthreads();
    if (tid < E) {
      float v = red[tid] + red[256 + tid] + red[512 + tid] + red[768 + tid]
              + Xih[((size_t)s * B + b) * E + tid];
      float hh = ftanh(v);
      h_s[tid] = hh;
      A_comb[((size_t)(b * T_DEC + s)) * (2 * E) + E + tid] = hh;  // h half of [ctx|h]
      h_all[((size_t)(b * T_DEC + s)) * E + tid] = hh;
    }
    __syncthreads();
  }
}

// ---------------- energies for ALL (b,s,t): fully parallel ----------------
// Block: (b, 16 t's). Stages hV[b] (64KB LDS), each wave owns 4 t-rows in
// registers, loops s. Results lane-transposed: g_pe[b][t][lane] with
// lane 0..31 = sm(s)+embias, lane 32..63 = sc(s)+ecbias.
__global__ __launch_bounds__(256) void energy_kernel(
    const float* __restrict__ encWm, const float* __restrict__ encWc,
    const float* __restrict__ g_hv,
    const float* __restrict__ w_effm, const float* __restrict__ w_effc,
    const float* __restrict__ vbm, const float* __restrict__ rmp,
    const float* __restrict__ vbc, const float* __restrict__ rcp_,
    float* __restrict__ g_pe)
{
  __shared__ float hvm[T_DEC * E];   // 32 KB
  __shared__ float hvc[T_DEC * E];   // 32 KB
  const int b = blockIdx.x, t0 = blockIdx.y << 4;
  const int tid = threadIdx.x, lane = tid & 63, w = tid >> 6;
  const float* hvb = g_hv + ((size_t)b * T_DEC) * (2 * E);
  for (int i = tid * 4; i < T_DEC * 2 * E; i += 1024) {
    float4 v = *(const float4*)(hvb + i);
    int s = i >> 9, dd = i & 511;
    if (dd < E) *(float4*)&hvm[s * E + dd]     = v;
    else        *(float4*)&hvc[s * E + dd - E] = v;
  }
  __syncthreads();
  const float embias = vbm[0] + rmp[0];
  const float ecbias = vbc[0] + rcp_[0];
  const float4 wm4 = *(const float4*)(w_effm + lane * 4);
  const float4 wc4 = *(const float4*)(w_effc + lane * 4);
  const int t = t0 + (w << 2);
  const size_t rb = (((size_t)b * T_ENC + t) << 8) + lane * 4;
  const float4 em0 = *(const float4*)(encWm + rb);
  const float4 em1 = *(const float4*)(encWm + rb + 256);
  const float4 em2 = *(const float4*)(encWm + rb + 512);
  const float4 em3 = *(const float4*)(encWm + rb + 768);
  const float4 ec0 = *(const float4*)(encWc + rb);
  const float4 ec1 = *(const float4*)(encWc + rb + 256);
  const float4 ec2 = *(const float4*)(encWc + rb + 512);
  const float4 ec3 = *(const float4*)(encWc + rb + 768);
  float pv0 = 0.f, pv1 = 0.f, pv2 = 0.f, pv3 = 0.f;
  for (int s = 0; s < T_DEC; ++s) {
    const float4 hm4 = *(const float4*)&hvm[(s << 8) + lane * 4];
    const float4 hc4 = *(const float4*)&hvc[(s << 8) + lane * 4];
    float a0 = wm4.x * ftanh(em0.x + hm4.x) + wm4.y * ftanh(em0.y + hm4.y)
             + wm4.z * ftanh(em0.z + hm4.z) + wm4.w * ftanh(em0.w + hm4.w);
    float a1 = wm4.x * ftanh(em1.x + hm4.x) + wm4.y * ftanh(em1.y + hm4.y)
             + wm4.z * ftanh(em1.z + hm4.z) + wm4.w * ftanh(em1.w + hm4.w);
    float a2 = wm4.x * ftanh(em2.x + hm4.x) + wm4.y * ftanh(em2.y + hm4.y)
             + wm4.z * ftanh(em2.z + hm4.z) + wm4.w * ftanh(em2.w + hm4.w);
    float a3 = wm4.x * ftanh(em3.x + hm4.x) + wm4.y * ftanh(em3.y + hm4.y)
             + wm4.z * ftanh(em3.z + hm4.z) + wm4.w * ftanh(em3.w + hm4.w);
    float c0 = wc4.x * ftanh(ec0.x + hc4.x) + wc4.y * ftanh(ec0.y + hc4.y)
             + wc4.z * ftanh(ec0.z + hc4.z) + wc4.w * ftanh(ec0.w + hc4.w);
    float c1 = wc4.x * ftanh(ec1.x + hc4.x) + wc4.y * ftanh(ec1.y + hc4.y)
             + wc4.z * ftanh(ec1.z + hc4.z) + wc4.w * ftanh(ec1.w + hc4.w);
    float c2 = wc4.x * ftanh(ec2.x + hc4.x) + wc4.y * ftanh(ec2.y + hc4.y)
             + wc4.z * ftanh(ec2.z + hc4.z) + wc4.w * ftanh(ec2.w + hc4.w);
    float c3 = wc4.x * ftanh(ec3.x + hc4.x) + wc4.y * ftanh(ec3.y + hc4.y)
             + wc4.z * ftanh(ec3.z + hc4.z) + wc4.w * ftanh(ec3.w + hc4.w);
    a0 = wredsum(a0); a1 = wredsum(a1); a2 = wredsum(a2); a3 = wredsum(a3);
    c0 = wredsum(c0); c1 = wredsum(c1); c2 = wredsum(c2); c3 = wredsum(c3);
    if (lane == s) {
      pv0 = a0 + embias; pv1 = a1 + embias; pv2 = a2 + embias; pv3 = a3 + embias;
    }
    if (lane == 32 + s) {
      pv0 = c0 + ecbias; pv1 = c1 + ecbias; pv2 = c2 + ecbias; pv3 = c3 + ecbias;
    }
  }
  const size_t ob = (((size_t)b * T_ENC + t) << 6) + lane;
  g_pe[ob]       = pv0;
  g_pe[ob + 64]  = pv1;
  g_pe[ob + 128] = pv2;
  g_pe[ob + 192] = pv3;
}

// ---------------- alpha/beta recurrence (sequential over s, per b) --------
__global__ __launch_bounds__(1024) void scan_kernel(
    const float* __restrict__ g_pe, const float* __restrict__ noise,
    float* __restrict__ beta_all)
{
  __shared__ float tmp_s[T_ENC], c2_s[T_ENC];
  __shared__ float wtot[8], wmax[8];
  const int b = blockIdx.x, tid = threadIdx.x;
  const int lane = tid & 63, w = tid >> 6;
  const bool val = tid < T_ENC;
  float aprev = (tid == 0) ? 1.f : 0.f;
  const float* pe = g_pe + ((size_t)b << 15);   // b*512*64

  for (int s = 0; s < T_DEC; ++s) {
    float p = 0.f, ec = -1e30f;
    if (val) {
      float sm = pe[((size_t)tid << 6) + s];
      ec       = pe[((size_t)tid << 6) + 32 + s];
      p = fsigmoid(sm + noise[((size_t)s * B + b) * T_ENC + tid]);
    }
    float omp = fminf(fmaxf(1.f - p, 1e-10f), 1.f);
    float lg  = val ? __logf(omp) : 0.f;
    float incl = scan512(lg, tid, wtot);
    float cp  = __expf(incl - lg);                     // exclusive cumprod
    float cpc = fminf(fmaxf(cp, 1e-10f), 1.f);
    float ao  = val ? aprev * __builtin_amdgcn_rcpf(cpc) : 0.f;
    float s2  = scan512(ao, tid, wtot);
    float alpha_new = p * cp * s2;

    float mxw = wredmax(ec);
    if (val && lane == 0) wmax[w] = mxw;
    __syncthreads();
    float mx = wmax[0];
#pragma unroll
    for (int i = 1; i < 8; i++) mx = fmaxf(mx, wmax[i]);

    float eu = val ? __expf(ec - mx) : 0.f;
    float c1 = scan512(eu, tid, wtot);
    if (val) tmp_s[tid] = c1;
    __syncthreads();
    float denom = val ? (c1 - ((tid >= 8) ? tmp_s[tid - 8] : 0.f)) : 1.f;
    denom = fmaxf(denom, 1e-10f);
    float r = val ? alpha_new * __builtin_amdgcn_rcpf(denom) : 0.f;
    float c2 = scan512(r, tid, wtot);
    if (val) c2_s[tid] = c2;
    __syncthreads();
    if (val) {
      int hi = (tid + 7 < T_ENC - 1) ? (tid + 7) : (T_ENC - 1);
      float ms2 = c2_s[hi] - ((tid > 0) ? c2_s[tid - 1] : 0.f);
      beta_all[((size_t)(b * T_DEC + s)) * T_ENC + tid] = eu * ms2;
    }
    aprev = alpha_new;
    __syncthreads();
  }
}

// ---------------- context: ctx[b,s,:] = sum_t beta[b,s,t] * enc[b,t,:] -----
__global__ __launch_bounds__(256) void context_kernel(
    const float* __restrict__ beta_all, const float* __restrict__ enc,
    float* __restrict__ A_comb)
{
  __shared__ float smem[T_ENC * 36];                 // [t][36] padded, 73.7 KB
  const int b = blockIdx.x, e0 = blockIdx.y << 6;
  const int tid = threadIdx.x;
  const float* bp = beta_all + (size_t)b * T_DEC * T_ENC;
  for (int i = tid; i < T_DEC * T_ENC; i += 256) {
    int s2 = i >> 9, t = i & 511;
    smem[t * 36 + s2] = bp[i];
  }
  __syncthreads();
  const int el = tid & 63, tg = tid >> 6;
  float4 a8[8];
#pragma unroll
  for (int u = 0; u < 8; ++u) a8[u] = (float4){0.f, 0.f, 0.f, 0.f};
  const float* ep = enc + (size_t)b * T_ENC * E + e0 + el;
  for (int t = tg; t < T_ENC; t += 4) {
    float v = ep[(size_t)t * E];
    const float4* bt = (const float4*)&smem[t * 36];
#pragma unroll
    for (int u = 0; u < 8; ++u) {
      float4 bv = bt[u];
      a8[u].x += bv.x * v; a8[u].y += bv.y * v;
      a8[u].z += bv.z * v; a8[u].w += bv.w * v;
    }
  }
  __syncthreads();
#pragma unroll
  for (int u = 0; u < 8; ++u) {
    smem[((tg * T_DEC + u * 4 + 0) << 6) + el] = a8[u].x;
    smem[((tg * T_DEC + u * 4 + 1) << 6) + el] = a8[u].y;
    smem[((tg * T_DEC + u * 4 + 2) << 6) + el] = a8[u].z;
    smem[((tg * T_DEC + u * 4 + 3) << 6) + el] = a8[u].w;
  }
  __syncthreads();
  for (int o = tid; o < T_DEC * 64; o += 256) {
    int s2 = o >> 6, e = o & 63;
    float v = smem[(s2 << 6) + e] + smem[((T_DEC + s2) << 6) + e]
            + smem[((2 * T_DEC + s2) << 6) + e] + smem[((3 * T_DEC + s2) << 6) + e];
    A_comb[((size_t)(b * T_DEC + s2)) * (2 * E) + e0 + e] = v;
  }
}

// ---------------- attn = tanh(A_comb[1024,512] @ Wt[512,256]) -> bf16 ------
__global__ __launch_bounds__(256) void comb_tanh_kernel(
    const float* __restrict__ A, const float* __restrict__ Wt,
    unsigned short* __restrict__ attn_bf)
{
  __shared__ float As[64][68];
  __shared__ float Ws[64][68];
  const int tid = threadIdx.x, tx = tid & 15, ty = tid >> 4;
  const int row0 = blockIdx.y * 64, col0 = blockIdx.x * 64;
  float acc[4][4];
#pragma unroll
  for (int i = 0; i < 4; i++)
#pragma unroll
    for (int jj = 0; jj < 4; jj++) acc[i][jj] = 0.f;

  for (int k0 = 0; k0 < 2 * E; k0 += 64) {
#pragma unroll
    for (int ss = 0; ss < 4; ss++) {
      int i = (ss << 4) + ty;
      int jj = tx << 2;
      float4 av = *(const float4*)(A + (size_t)(row0 + i) * (2 * E) + k0 + jj);
      As[jj][i] = av.x; As[jj + 1][i] = av.y; As[jj + 2][i] = av.z; As[jj + 3][i] = av.w;
      float4 wv = *(const float4*)(Wt + (size_t)(k0 + i) * E + col0 + jj);
      *(float4*)&Ws[i][jj] = wv;
    }
    __syncthreads();
#pragma unroll
    for (int kk = 0; kk < 64; kk++) {
      const float4 af = *(const float4*)&As[kk][ty << 2];
      const float4 bf = *(const float4*)&Ws[kk][tx << 2];
      acc[0][0] += af.x * bf.x; acc[0][1] += af.x * bf.y; acc[0][2] += af.x * bf.z; acc[0][3] += af.x * bf.w;
      acc[1][0] += af.y * bf.x; acc[1][1] += af.y * bf.y; acc[1][2] += af.y * bf.z; acc[1][3] += af.y * bf.w;
      acc[2][0] += af.z * bf.x; acc[2][1] += af.z * bf.y; acc[2][2] += af.z * bf.z; acc[2][3] += af.z * bf.w;
      acc[3][0] += af.w * bf.x; acc[3][1] += af.w * bf.y; acc[3][2] += af.w * bf.z; acc[3][3] += af.w * bf.w;
    }
    __syncthreads();
  }
#pragma unroll
  for (int i = 0; i < 4; i++) {
    ushort4 o;
    o.x = f2bf(ftanh(acc[i][0])); o.y = f2bf(ftanh(acc[i][1]));
    o.z = f2bf(ftanh(acc[i][2])); o.w = f2bf(ftanh(acc[i][3]));
    *(ushort4*)(attn_bf + (size_t)(row0 + (ty << 2) + i) * E + col0 + (tx << 2)) = o;
  }
}

// ---------------- projection: out = attn @ W_proj.T + b_proj (bf16 MFMA) ---
__global__ __launch_bounds__(256) void proj_mfma(
    const unsigned short* __restrict__ A, const unsigned short* __restrict__ Bw,
    const float* __restrict__ bias, float* __restrict__ Y)
{
  __shared__ float tile[64][68];
  const int tid = threadIdx.x;
  const int wave = tid >> 6, lane = tid & 63;
  const int m = lane & 15, q = lane >> 4;
  const int rowa = blockIdx.y * 64 + wave * 16;
  const int col0 = blockIdx.x * 64;
  floatx4 acc0 = {0.f, 0.f, 0.f, 0.f}, acc1 = acc0, acc2 = acc0, acc3 = acc0;
  const unsigned short* ar = A + (size_t)(rowa + m) * E + q * 8;
  const unsigned short* br = Bw + (size_t)(col0 + m) * E + q * 8;
#pragma unroll
  for (int k0 = 0; k0 < E; k0 += 32) {
    short8 af = *(const short8*)(ar + k0);
    short8 b0 = *(const short8*)(br + k0);
    short8 b1 = *(const short8*)(br + (size_t)16 * E + k0);
    short8 b2 = *(const short8*)(br + (size_t)32 * E + k0);
    short8 b3 = *(const short8*)(br + (size_t)48 * E + k0);
    acc0 = __builtin_amdgcn_mfma_f32_16x16x32_bf16(af, b0, acc0, 0, 0, 0);
    acc1 = __builtin_amdgcn_mfma_f32_16x16x32_bf16(af, b1, acc1, 0, 0, 0);
    acc2 = __builtin_amdgcn_mfma_f32_16x16x32_bf16(af, b2, acc2, 0, 0, 0);
    acc3 = __builtin_amdgcn_mfma_f32_16x16x32_bf16(af, b3, acc3, 0, 0, 0);
  }
  const int rl = wave * 16 + q * 4;
#pragma unroll
  for (int r = 0; r < 4; r++) {
    tile[rl + r][ 0 + m] = acc0[r];
    tile[rl + r][16 + m] = acc1[r];
    tile[rl + r][32 + m] = acc2[r];
    tile[rl + r][48 + m] = acc3[r];
  }
  __syncthreads();
  const int row = tid >> 2, seg = tid & 3;
  const size_t yb = ((size_t)blockIdx.y * 64 + row) * VOCAB + col0;
#pragma unroll
  for (int u = 0; u < 4; u++) {
    int cc = seg * 16 + u * 4;
    float4 v = *(const float4*)&tile[row][cc];
    float4 bb = *(const float4*)(bias + col0 + cc);
    v.x += bb.x; v.y += bb.y; v.z += bb.z; v.w += bb.w;
    *(float4*)(Y + yb + cc) = v;
  }
}

// ---------------- launch ----------------
extern "C" void kernel_launch(void* const* d_in, const int* in_sizes, int n_in,
                              void* d_out, int out_size, void* d_ws, size_t ws_size,
                              hipStream_t stream)
{
  (void)in_sizes; (void)n_in; (void)out_size; (void)ws_size;
  const float* enc    = (const float*)d_in[0];
  const int*   dec    = (const int*)d_in[1];
  const float* h0     = (const float*)d_in[2];
  const float* noise  = (const float*)d_in[3];
  const float* emb    = (const float*)d_in[4];
  const float* W_ih   = (const float*)d_in[5];
  const float* b_ih   = (const float*)d_in[6];
  const float* W_hh   = (const float*)d_in[7];
  const float* b_hh   = (const float*)d_in[8];
  const float* Wm     = (const float*)d_in[9];
  const float* Vm     = (const float*)d_in[10];
  const float* bm     = (const float*)d_in[11];
  const float* vvm    = (const float*)d_in[12];
  const float* gm     = (const float*)d_in[13];
  const float* vbm    = (const float*)d_in[14];
  const float* rmp    = (const float*)d_in[15];
  const float* Wc     = (const float*)d_in[16];
  const float* Vc     = (const float*)d_in[17];
  const float* bc     = (const float*)d_in[18];
  const float* vvc    = (const float*)d_in[19];
  const float* gc     = (const float*)d_in[20];
  const float* vbc    = (const float*)d_in[21];
  const float* rcp_   = (const float*)d_in[22];
  const float* W_comb = (const float*)d_in[23];
  const float* W_proj = (const float*)d_in[24];
  const float* b_proj = (const float*)d_in[25];

  float* ws = (float*)d_ws;
  float* encWm   = ws + OFF_ENCWM;
  float* encWc   = ws + OFF_ENCWC;
  float* w_effm  = ws + OFF_WEFFM;
  float* w_effc  = ws + OFF_WEFFC;
  float* bsum    = ws + OFF_BSUM;
  float* Xih     = ws + OFF_XIH;
  float* W_hhT   = ws + OFF_WHHT;
  float* W_combT = ws + OFF_WCOMBT;
  unsigned short* attn_bf = (unsigned short*)(ws + OFF_ATTNB);
  unsigned short* Wp_bf   = (unsigned short*)(ws + OFF_WPBF);

  float* outF = (float*)d_out;
  float* embX     = outF + OUT_EMBX;     // scratch in d_out, all consumed
  float* beta_all = outF + OUT_BETA;     //   before proj_mfma overwrites it
  float* A_comb   = outF + OUT_ACOMB;
  float* h_all    = outF + OUT_HALL;
  float* g_hv     = outF + OUT_HV;
  float* g_pe     = outF + OUT_PE;
  float* Vmc      = outF + OUT_VMC;
  float* zero512  = outF + OUT_ZERO;

  // ---- step-invariant prep ----
  weff_kernel<<<2, 256, 0, stream>>>(vvm, gm, w_effm, vvc, gc, w_effc);
  prep_bias<<<1, 256, 0, stream>>>(b_ih, b_hh, bsum);
  transpose_k<<<dim3(8, 8), 256, 0, stream>>>(W_hh, W_hhT, E, E);
  transpose_k<<<dim3(16, 8), 256, 0, stream>>>(W_comb, W_combT, E, 2 * E);
  concat_v<<<128, 256, 0, stream>>>(Vm, Vc, Vmc, zero512);
  gather_emb<<<T_DEC * B, 256, 0, stream>>>(dec, emb, embX);
  gemm_xwt<<<dim3(E / 64, (T_DEC * B) / 64), 256, 0, stream>>>(embX, W_ih, bsum, Xih,
                                                               T_DEC * B, E, E);
  gemm_xwt<<<dim3(E / 64, (B * T_ENC) / 64), 256, 0, stream>>>(enc, Wm, bm, encWm, B * T_ENC, E, E);
  gemm_xwt<<<dim3(E / 64, (B * T_ENC) / 64), 256, 0, stream>>>(enc, Wc, bc, encWc, B * T_ENC, E, E);
  cvt_bf16<<<(VOCAB * E) / 1024, 256, 0, stream>>>(W_proj, Wp_bf);

  // ---- sequential part 1: the h-chain (tiny, register-cached W_hh) ----
  hchain_kernel<<<B, 1024, 0, stream>>>(Xih, W_hhT, h0, A_comb, h_all);

  // ---- hV = [Vm;Vc] h for all (b,s): one parallel GEMM ----
  gemm_xwt<<<dim3((2 * E) / 64, (T_DEC * B) / 64), 256, 0, stream>>>(
      h_all, Vmc, zero512, g_hv, T_DEC * B, 2 * E, E);

  // ---- energies for all (b,s,t): fully parallel, encW read ONCE ----
  energy_kernel<<<dim3(B, T_ENC / 16), 256, 0, stream>>>(
      encWm, encWc, g_hv, w_effm, w_effc, vbm, rmp, vbc, rcp_, g_pe);

  // ---- sequential part 2: alpha/beta scans per b ----
  scan_kernel<<<B, 1024, 0, stream>>>(g_pe, noise, beta_all);

  // ---- hoisted epilogue: context, attn, projection ----
  context_kernel<<<dim3(B, 4), 256, 0, stream>>>(beta_all, enc, A_comb);
  comb_tanh_kernel<<<dim3(E / 64, (T_DEC * B) / 64), 256, 0, stream>>>(A_comb, W_combT, attn_bf);
  proj_mfma<<<dim3(VOCAB / 64, (T_DEC * B) / 64), 256, 0, stream>>>(attn_bf, Wp_bf, b_proj, outF);
}

// Round 3
// 633.857 us; speedup vs baseline: 3.7552x; 1.3823x over previous
//
#include <hip/hip_runtime.h>
#include <cstddef>

#define B 32
#define T_ENC 512
#define T_DEC 32
#define E 256
#define VOCAB 32000
#define SOS 1

typedef __attribute__((ext_vector_type(8))) short short8;   // 8 x bf16
typedef __attribute__((ext_vector_type(4))) float floatx4;  // MFMA acc

// ---------------- workspace layout (float offsets) ----------------
static const size_t OFF_ENCW   = 0;                                    // 8388608: fused [16384][512]
static const size_t OFF_WEFFM  = OFF_ENCW + (size_t)B * T_ENC * 2 * E; // 256
static const size_t OFF_WEFFC  = OFF_WEFFM + E;                        // 256
static const size_t OFF_BSUM   = OFF_WEFFC + E;                        // 256
static const size_t OFF_XIH    = OFF_BSUM + E;                         // 262144
static const size_t OFF_WHHT   = OFF_XIH + (size_t)T_DEC * B * E;      // 65536
static const size_t OFF_VMT    = OFF_WHHT + (size_t)E * E;             // 65536 (unused)
static const size_t OFF_VCT    = OFF_VMT + (size_t)E * E;              // 65536 (unused)
static const size_t OFF_WCOMBT = OFF_VCT + (size_t)E * E;              // 131072
static const size_t OFF_ATTNB  = OFF_WCOMBT + (size_t)2 * E * E;       // 131072 floats (ushort x2)
static const size_t OFF_WPBF   = OFF_ATTNB + (size_t)T_DEC * B * E / 2;// 4096000 floats (ushort x2)

// ---------------- d_out scratch layout (float offsets) ----------------
// d_out is 32.768M floats; everything here is consumed before proj_mfma
// overwrites d_out at the end of the launch sequence.
static const size_t OUT_EMBX  = 0;         // 262144 (consumed by Xih gemm)
static const size_t OUT_BETA  = 262144;    // 524288: beta[b][s][t]
static const size_t OUT_ACOMB = 786432;    // 524288: [ctx | h] rows (b*32+s) x 512
static const size_t OUT_HALL  = 1310720;   // 262144: h[b][s][256]
static const size_t OUT_HV    = 1572864;   // 524288: [hVm | hVc] rows (b*32+s) x 512
static const size_t OUT_PE    = 2097152;   // 1048576: g_pe[b][t][64] (sm:0-31, sc:32-63)
static const size_t OUT_VMC   = 3145728;   // 131072: [Vm ; Vc]
static const size_t OUT_ZERO  = 3276800;   // 512 zeros
static const size_t OUT_WHI   = 3277312;   // 65536 floats = 131072 ushort: W split hi [512][256]
static const size_t OUT_WLO   = 3342848;   // 65536 floats: W split lo
static const size_t OUT_B512  = 3408384;   // 512: [bm ; bc]

// ---------------- helpers ----------------
__device__ __forceinline__ float ftanh(float x) {
  float ax = __builtin_fabsf(x);
  float e  = __expf(-2.f * ax);
  float r  = (1.f - e) * __builtin_amdgcn_rcpf(1.f + e);
  return __builtin_copysignf(r, x);
}

__device__ __forceinline__ float fsigmoid(float z) {
  return __builtin_amdgcn_rcpf(1.f + __expf(-z));
}

__device__ __forceinline__ float wredsum(float s) {
  s += __shfl_xor(s, 1, 64);  s += __shfl_xor(s, 2, 64);  s += __shfl_xor(s, 4, 64);
  s += __shfl_xor(s, 8, 64);  s += __shfl_xor(s, 16, 64); s += __shfl_xor(s, 32, 64);
  return s;
}

__device__ __forceinline__ float wredmax(float s) {
  s = fmaxf(s, __shfl_xor(s, 1, 64));  s = fmaxf(s, __shfl_xor(s, 2, 64));
  s = fmaxf(s, __shfl_xor(s, 4, 64));  s = fmaxf(s, __shfl_xor(s, 8, 64));
  s = fmaxf(s, __shfl_xor(s, 16, 64)); s = fmaxf(s, __shfl_xor(s, 32, 64));
  return s;
}

__device__ __forceinline__ unsigned short f2bf(float f) {
  unsigned int u = __float_as_uint(f);
  u = (u + 0x7fffu + ((u >> 16) & 1u)) >> 16;   // RNE
  return (unsigned short)u;
}

__device__ __forceinline__ float bf2f(unsigned short h) {
  return __uint_as_float((unsigned int)h << 16);
}

// exclusive prefix (across 64 lanes) of per-lane totals; returns prefix sum
// of lanes [0, lane). All 64 lanes must call.
__device__ __forceinline__ float wexcl(float tot, int lane) {
  float v = tot;
#pragma unroll
  for (int off = 1; off < 64; off <<= 1) {
    float y = __shfl_up(v, off, 64);
    if (lane >= off) v += y;
  }
  return v - tot;
}

// ---------------- merged tiny prep: weff x2, biases, concat V, W split -----
__global__ __launch_bounds__(256) void prep_misc(
    const float* __restrict__ vvm, const float* __restrict__ gm, float* __restrict__ w_effm,
    const float* __restrict__ vvc, const float* __restrict__ gc, float* __restrict__ w_effc,
    const float* __restrict__ b_ih, const float* __restrict__ b_hh, float* __restrict__ bsum,
    const float* __restrict__ bm, const float* __restrict__ bc, float* __restrict__ bias512,
    const float* __restrict__ Vm, const float* __restrict__ Vc,
    float* __restrict__ Vmc, float* __restrict__ zero512,
    const float* __restrict__ Wm, const float* __restrict__ Wc,
    unsigned short* __restrict__ Whi, unsigned short* __restrict__ Wlo)
{
  __shared__ float red[256];
  const int blk = blockIdx.x, tid = threadIdx.x;
  if (blk < 2) {
    const float* vv = blk ? vvc : vvm;
    const float* g  = blk ? gc  : gm;
    float* out      = blk ? w_effc : w_effm;
    float v = vv[tid];
    red[tid] = v * v;
    __syncthreads();
    for (int off = 128; off > 0; off >>= 1) {
      if (tid < off) red[tid] += red[tid + off];
      __syncthreads();
    }
    float norm = sqrtf(red[0]);
    out[tid] = (g[0] / norm) * v;
  } else if (blk == 2) {
    bsum[tid] = b_ih[tid] + b_hh[tid];
    bias512[tid]       = bm[tid];
    bias512[256 + tid] = bc[tid];
    zero512[tid] = 0.f;
    zero512[256 + tid] = 0.f;
  } else if (blk < 131) {
    int i = (blk - 3) * 1024 + tid * 4;
    float4 v = (i < E * E) ? *(const float4*)(Vm + i) : *(const float4*)(Vc + i - E * E);
    *(float4*)(Vmc + i) = v;
  } else {
    int i = (blk - 131) * 1024 + tid * 4;
    float4 v = (i < E * E) ? *(const float4*)(Wm + i) : *(const float4*)(Wc + i - E * E);
    ushort4 h, l;
    h.x = f2bf(v.x); l.x = f2bf(v.x - bf2f(h.x));
    h.y = f2bf(v.y); l.y = f2bf(v.y - bf2f(h.y));
    h.z = f2bf(v.z); l.z = f2bf(v.z - bf2f(h.z));
    h.w = f2bf(v.w); l.w = f2bf(v.w - bf2f(h.w));
    *(ushort4*)(Whi + i) = h;
    *(ushort4*)(Wlo + i) = l;
  }
}

// ---------------- two transposes in one launch ----------------
__global__ __launch_bounds__(256) void transpose2(
    const float* __restrict__ W_hh, float* __restrict__ W_hhT,
    const float* __restrict__ W_comb, float* __restrict__ W_combT)
{
  __shared__ float tl[32][33];
  const int blk = blockIdx.x;
  const float* in; float* out; int C, bx, by;
  if (blk < 64) { in = W_hh;   out = W_hhT;   C = 256; bx = blk & 7;  by = blk >> 3; }
  else { int k = blk - 64; in = W_comb; out = W_combT; C = 512; bx = k & 15; by = k >> 4; }
  const int R = 256;
  const int tx = threadIdx.x & 31, ty = threadIdx.x >> 5;
  const int c0 = bx * 32, r0 = by * 32;
#pragma unroll
  for (int k = 0; k < 4; k++)
    tl[ty + 8 * k][tx] = in[(size_t)(r0 + ty + 8 * k) * C + c0 + tx];
  __syncthreads();
#pragma unroll
  for (int k = 0; k < 4; k++)
    out[(size_t)(c0 + ty + 8 * k) * R + r0 + tx] = tl[tx][ty + 8 * k];
}

// ---------------- gather embeddings ----------------
__global__ __launch_bounds__(256) void gather_emb(
    const int* __restrict__ dec, const float* __restrict__ emb, float* __restrict__ embX)
{
  int r = blockIdx.x, d = threadIdx.x;
  int s = r >> 5, b = r & 31;
  int tok = (s == 0) ? SOS : dec[b * T_DEC + s - 1];
  embX[(size_t)r * E + d] = emb[(size_t)tok * E + d];
}

// ---------------- f32 -> bf16 convert ----------------
__global__ __launch_bounds__(256) void cvt_bf16(
    const float* __restrict__ src, unsigned short* __restrict__ dst)
{
  size_t i = ((size_t)blockIdx.x * 256 + threadIdx.x) * 4;
  float4 v = *(const float4*)(src + i);
  ushort4 o;
  o.x = f2bf(v.x); o.y = f2bf(v.y); o.z = f2bf(v.z); o.w = f2bf(v.w);
  *(ushort4*)(dst + i) = o;
}

// ---------------- Y[r,n] = bias[n] + sum_k A[r,k]*W[n,k] (f32, small) ------
__global__ __launch_bounds__(256) void gemm_xwt(
    const float* __restrict__ A, const float* __restrict__ W,
    const float* __restrict__ bias, float* __restrict__ Y,
    int M, int N, int K)
{
  __shared__ float As[64][68];
  __shared__ float Ws[64][68];
  const int tid = threadIdx.x;
  const int tx = tid & 15, ty = tid >> 4;
  const int row0 = blockIdx.y * 64, col0 = blockIdx.x * 64;
  float acc[4][4];
#pragma unroll
  for (int i = 0; i < 4; i++)
#pragma unroll
    for (int j = 0; j < 4; j++) acc[i][j] = 0.f;

  for (int k0 = 0; k0 < K; k0 += 64) {
#pragma unroll
    for (int s = 0; s < 4; s++) {
      int i = (s << 4) + ty;
      int j = tx << 2;
      float4 av = *(const float4*)(A + (size_t)(row0 + i) * K + k0 + j);
      As[j][i] = av.x; As[j + 1][i] = av.y; As[j + 2][i] = av.z; As[j + 3][i] = av.w;
      float4 wv = *(const float4*)(W + (size_t)(col0 + i) * K + k0 + j);
      Ws[j][i] = wv.x; Ws[j + 1][i] = wv.y; Ws[j + 2][i] = wv.z; Ws[j + 3][i] = wv.w;
    }
    __syncthreads();
#pragma unroll
    for (int kk = 0; kk < 64; kk++) {
      const float4 af = *(const float4*)&As[kk][ty << 2];
      const float4 bf = *(const float4*)&Ws[kk][tx << 2];
      acc[0][0] += af.x * bf.x; acc[0][1] += af.x * bf.y; acc[0][2] += af.x * bf.z; acc[0][3] += af.x * bf.w;
      acc[1][0] += af.y * bf.x; acc[1][1] += af.y * bf.y; acc[1][2] += af.y * bf.z; acc[1][3] += af.y * bf.w;
      acc[2][0] += af.z * bf.x; acc[2][1] += af.z * bf.y; acc[2][2] += af.z * bf.z; acc[2][3] += af.z * bf.w;
      acc[3][0] += af.w * bf.x; acc[3][1] += af.w * bf.y; acc[3][2] += af.w * bf.z; acc[3][3] += af.w * bf.w;
    }
    __syncthreads();
  }
  const float4 bv = *(const float4*)(bias + col0 + (tx << 2));
#pragma unroll
  for (int i = 0; i < 4; i++) {
    float4 o;
    o.x = acc[i][0] + bv.x; o.y = acc[i][1] + bv.y;
    o.z = acc[i][2] + bv.z; o.w = acc[i][3] + bv.w;
    *(float4*)(Y + (size_t)(row0 + (ty << 2) + i) * N + col0 + (tx << 2)) = o;
  }
}

// ---------------- encW = [enc@Wm.T+bm ; enc@Wc.T+bc] via split-bf16 MFMA ---
// 256 blocks (64 rows each), 4 waves; wave w owns cols [w*128, w*128+128).
// A split on the fly into LDS; 4 MFMA products (hi*hi+lo*hi+hi*lo+lo*lo)
// give ~2^-17 relative accuracy (f32-equivalent for this use).
__global__ __launch_bounds__(256) void enc_mfma(
    const float* __restrict__ A,
    const unsigned short* __restrict__ Whi, const unsigned short* __restrict__ Wlo,
    const float* __restrict__ bias512, float* __restrict__ Y)
{
  __shared__ unsigned short a_hi[64][264];
  __shared__ unsigned short a_lo[64][264];
  const int tid = threadIdx.x;
  const int row0 = blockIdx.x * 64;
#pragma unroll
  for (int u = 0; u < 16; ++u) {
    int f = tid + (u << 8);
    int r = f >> 6, c = (f & 63) << 2;
    float4 v = *(const float4*)(A + (size_t)(row0 + r) * E + c);
    ushort4 h, l;
    h.x = f2bf(v.x); l.x = f2bf(v.x - bf2f(h.x));
    h.y = f2bf(v.y); l.y = f2bf(v.y - bf2f(h.y));
    h.z = f2bf(v.z); l.z = f2bf(v.z - bf2f(h.z));
    h.w = f2bf(v.w); l.w = f2bf(v.w - bf2f(h.w));
    *(ushort4*)&a_hi[r][c] = h;
    *(ushort4*)&a_lo[r][c] = l;
  }
  __syncthreads();
  const int lane = tid & 63, w = tid >> 6;
  const int m = lane & 15, q = lane >> 4;
  const int colbase = w << 7;
#pragma unroll
  for (int cp = 0; cp < 4; ++cp) {          // 32-col pair of 16-col MFMA tiles
    const int c0 = colbase + (cp << 5);
    floatx4 acc[4][2] = {};
    for (int k0 = 0; k0 < E; k0 += 32) {
      const size_t w0 = (size_t)(c0 + m) * E + (q << 3) + k0;
      const size_t w1 = (size_t)(c0 + 16 + m) * E + (q << 3) + k0;
      short8 bh0 = *(const short8*)(Whi + w0);
      short8 bl0 = *(const short8*)(Wlo + w0);
      short8 bh1 = *(const short8*)(Whi + w1);
      short8 bl1 = *(const short8*)(Wlo + w1);
#pragma unroll
      for (int rg = 0; rg < 4; ++rg) {
        short8 ah = *(const short8*)&a_hi[(rg << 4) + m][(q << 3) + k0];
        short8 al = *(const short8*)&a_lo[(rg << 4) + m][(q << 3) + k0];
        acc[rg][0] = __builtin_amdgcn_mfma_f32_16x16x32_bf16(ah, bh0, acc[rg][0], 0, 0, 0);
        acc[rg][0] = __builtin_amdgcn_mfma_f32_16x16x32_bf16(al, bh0, acc[rg][0], 0, 0, 0);
        acc[rg][0] = __builtin_amdgcn_mfma_f32_16x16x32_bf16(ah, bl0, acc[rg][0], 0, 0, 0);
        acc[rg][0] = __builtin_amdgcn_mfma_f32_16x16x32_bf16(al, bl0, acc[rg][0], 0, 0, 0);
        acc[rg][1] = __builtin_amdgcn_mfma_f32_16x16x32_bf16(ah, bh1, acc[rg][1], 0, 0, 0);
        acc[rg][1] = __builtin_amdgcn_mfma_f32_16x16x32_bf16(al, bh1, acc[rg][1], 0, 0, 0);
        acc[rg][1] = __builtin_amdgcn_mfma_f32_16x16x32_bf16(ah, bl1, acc[rg][1], 0, 0, 0);
        acc[rg][1] = __builtin_amdgcn_mfma_f32_16x16x32_bf16(al, bl1, acc[rg][1], 0, 0, 0);
      }
    }
    const float bia0 = bias512[c0 + m], bia1 = bias512[c0 + 16 + m];
#pragma unroll
    for (int rg = 0; rg < 4; ++rg)
#pragma unroll
      for (int r = 0; r < 4; ++r) {
        const size_t row = row0 + (rg << 4) + (q << 2) + r;
        Y[row * (2 * E) + c0 + m]      = acc[rg][0][r] + bia0;
        Y[row * (2 * E) + c0 + 16 + m] = acc[rg][1][r] + bia1;
      }
  }
}

// ---------------- h-chain: h[s+1] = tanh(Xih + W_hh h[s]), W_hh in regs ----
__global__ __launch_bounds__(1024) void hchain_kernel(
    const float* __restrict__ Xih, const float* __restrict__ W_hhT,
    const float* __restrict__ h0,
    float* __restrict__ A_comb, float* __restrict__ h_all)
{
  __shared__ float h_s[E];
  __shared__ float red[1024];
  const int b = blockIdx.x, tid = threadIdx.x;
  const int c = tid >> 8, d = tid & 255, k0 = c * 64;
  float wreg[64];
#pragma unroll
  for (int j = 0; j < 64; ++j) wreg[j] = W_hhT[(size_t)(k0 + j) * E + d];
  if (tid < E) h_s[tid] = h0[(size_t)b * E + tid];
  __syncthreads();
  for (int s = 0; s < T_DEC; ++s) {
    float acc = 0.f;
#pragma unroll
    for (int j = 0; j < 64; j += 4) {
      float4 hh = *(const float4*)&h_s[k0 + j];
      acc += hh.x * wreg[j] + hh.y * wreg[j + 1] + hh.z * wreg[j + 2] + hh.w * wreg[j + 3];
    }
    red[tid] = acc;
    __syncthreads();
    if (tid < E) {
      float v = red[tid] + red[256 + tid] + red[512 + tid] + red[768 + tid]
              + Xih[((size_t)s * B + b) * E + tid];
      float hh = ftanh(v);
      h_s[tid] = hh;
      A_comb[((size_t)(b * T_DEC + s)) * (2 * E) + E + tid] = hh;
      h_all[((size_t)(b * T_DEC + s)) * E + tid] = hh;
    }
    __syncthreads();
  }
}

// ---------------- energies for ALL (b,s,t): fully parallel ----------------
__global__ __launch_bounds__(256) void energy_kernel(
    const float* __restrict__ encW, const float* __restrict__ g_hv,
    const float* __restrict__ w_effm, const float* __restrict__ w_effc,
    const float* __restrict__ vbm, const float* __restrict__ rmp,
    const float* __restrict__ vbc, const float* __restrict__ rcp_,
    float* __restrict__ g_pe)
{
  __shared__ float hvm[T_DEC * E];   // 32 KB
  __shared__ float hvc[T_DEC * E];   // 32 KB
  const int b = blockIdx.x, t0 = blockIdx.y << 4;
  const int tid = threadIdx.x, lane = tid & 63, w = tid >> 6;
  const float* hvb = g_hv + ((size_t)b * T_DEC) * (2 * E);
  for (int i = tid * 4; i < T_DEC * 2 * E; i += 1024) {
    float4 v = *(const float4*)(hvb + i);
    int s = i >> 9, dd = i & 511;
    if (dd < E) *(float4*)&hvm[s * E + dd]     = v;
    else        *(float4*)&hvc[s * E + dd - E] = v;
  }
  __syncthreads();
  const float embias = vbm[0] + rmp[0];
  const float ecbias = vbc[0] + rcp_[0];
  const float4 wm4 = *(const float4*)(w_effm + lane * 4);
  const float4 wc4 = *(const float4*)(w_effc + lane * 4);
  const int t = t0 + (w << 2);
  const size_t rb = ((size_t)(b * T_ENC + t)) * (2 * E) + lane * 4;
  const float4 em0 = *(const float4*)(encW + rb);
  const float4 em1 = *(const float4*)(encW + rb + 512);
  const float4 em2 = *(const float4*)(encW + rb + 1024);
  const float4 em3 = *(const float4*)(encW + rb + 1536);
  const float4 ec0 = *(const float4*)(encW + rb + 256);
  const float4 ec1 = *(const float4*)(encW + rb + 768);
  const float4 ec2 = *(const float4*)(encW + rb + 1280);
  const float4 ec3 = *(const float4*)(encW + rb + 1792);
  float pv0 = 0.f, pv1 = 0.f, pv2 = 0.f, pv3 = 0.f;
  for (int s = 0; s < T_DEC; ++s) {
    const float4 hm4 = *(const float4*)&hvm[(s << 8) + lane * 4];
    const float4 hc4 = *(const float4*)&hvc[(s << 8) + lane * 4];
    float a0 = wm4.x * ftanh(em0.x + hm4.x) + wm4.y * ftanh(em0.y + hm4.y)
             + wm4.z * ftanh(em0.z + hm4.z) + wm4.w * ftanh(em0.w + hm4.w);
    float a1 = wm4.x * ftanh(em1.x + hm4.x) + wm4.y * ftanh(em1.y + hm4.y)
             + wm4.z * ftanh(em1.z + hm4.z) + wm4.w * ftanh(em1.w + hm4.w);
    float a2 = wm4.x * ftanh(em2.x + hm4.x) + wm4.y * ftanh(em2.y + hm4.y)
             + wm4.z * ftanh(em2.z + hm4.z) + wm4.w * ftanh(em2.w + hm4.w);
    float a3 = wm4.x * ftanh(em3.x + hm4.x) + wm4.y * ftanh(em3.y + hm4.y)
             + wm4.z * ftanh(em3.z + hm4.z) + wm4.w * ftanh(em3.w + hm4.w);
    float c0 = wc4.x * ftanh(ec0.x + hc4.x) + wc4.y * ftanh(ec0.y + hc4.y)
             + wc4.z * ftanh(ec0.z + hc4.z) + wc4.w * ftanh(ec0.w + hc4.w);
    float c1 = wc4.x * ftanh(ec1.x + hc4.x) + wc4.y * ftanh(ec1.y + hc4.y)
             + wc4.z * ftanh(ec1.z + hc4.z) + wc4.w * ftanh(ec1.w + hc4.w);
    float c2 = wc4.x * ftanh(ec2.x + hc4.x) + wc4.y * ftanh(ec2.y + hc4.y)
             + wc4.z * ftanh(ec2.z + hc4.z) + wc4.w * ftanh(ec2.w + hc4.w);
    float c3 = wc4.x * ftanh(ec3.x + hc4.x) + wc4.y * ftanh(ec3.y + hc4.y)
             + wc4.z * ftanh(ec3.z + hc4.z) + wc4.w * ftanh(ec3.w + hc4.w);
    a0 = wredsum(a0); a1 = wredsum(a1); a2 = wredsum(a2); a3 = wredsum(a3);
    c0 = wredsum(c0); c1 = wredsum(c1); c2 = wredsum(c2); c3 = wredsum(c3);
    if (lane == s) {
      pv0 = a0 + embias; pv1 = a1 + embias; pv2 = a2 + embias; pv3 = a3 + embias;
    }
    if (lane == 32 + s) {
      pv0 = c0 + ecbias; pv1 = c1 + ecbias; pv2 = c2 + ecbias; pv3 = c3 + ecbias;
    }
  }
  const size_t ob = (((size_t)b * T_ENC + t) << 6) + lane;
  g_pe[ob]       = pv0;
  g_pe[ob + 64]  = pv1;
  g_pe[ob + 128] = pv2;
  g_pe[ob + 192] = pv3;
}

// ---------------- alpha/beta recurrence: ONE WAVE per b, zero barriers -----
// Each lane owns t in [lane*8, lane*8+8). Scans = serial-in-lane + 6-shfl
// wave scan of lane totals. Neighbor taps (t-8, t+7, t-1) are shfl up/down.
__global__ __launch_bounds__(64) void scan_kernel(
    const float* __restrict__ g_pe, const float* __restrict__ noise,
    float* __restrict__ beta_all)
{
  const int b = blockIdx.x, lane = threadIdx.x;
  const float* pe = g_pe + ((size_t)b << 15);   // b*512*64
  float alpha[8];
#pragma unroll
  for (int i = 0; i < 8; ++i) alpha[i] = 0.f;
  if (lane == 0) alpha[0] = 1.f;

  for (int s = 0; s < T_DEC; ++s) {
    const float* nrow = noise + ((size_t)s * B + b) * T_ENC + lane * 8;
    float4 n0 = *(const float4*)nrow;
    float4 n1 = *(const float4*)(nrow + 4);
    float nz[8] = {n0.x, n0.y, n0.z, n0.w, n1.x, n1.y, n1.z, n1.w};
    float p[8], ec[8];
#pragma unroll
    for (int i = 0; i < 8; ++i) {
      const size_t base = ((size_t)(lane * 8 + i)) << 6;
      float sm = pe[base + s];
      ec[i]    = pe[base + 32 + s];
      p[i] = fsigmoid(sm + nz[i]);
    }
    // scan1: inclusive cumsum of log(clamp(1-p))
    float lgv[8], lci[8], run = 0.f;
#pragma unroll
    for (int i = 0; i < 8; ++i) {
      float omp = fminf(fmaxf(1.f - p[i], 1e-10f), 1.f);
      lgv[i] = __logf(omp);
      run += lgv[i];
      lci[i] = run;
    }
    float ex1 = wexcl(run, lane);
    float cp[8], ao[8];
#pragma unroll
    for (int i = 0; i < 8; ++i) {
      float incl = lci[i] + ex1;
      cp[i] = __expf(incl - lgv[i]);               // exclusive cumprod
      float cpc = fminf(fmaxf(cp[i], 1e-10f), 1.f);
      ao[i] = alpha[i] * __builtin_amdgcn_rcpf(cpc);
    }
    // scan2: cumsum of ao
    float run2 = 0.f, lc2[8];
#pragma unroll
    for (int i = 0; i < 8; ++i) { run2 += ao[i]; lc2[i] = run2; }
    float ex2 = wexcl(run2, lane);
    float alpha_new[8];
#pragma unroll
    for (int i = 0; i < 8; ++i) alpha_new[i] = p[i] * cp[i] * (lc2[i] + ex2);
    // global max of ec
    float mloc = ec[0];
#pragma unroll
    for (int i = 1; i < 8; ++i) mloc = fmaxf(mloc, ec[i]);
    float mx = wredmax(mloc);
    float eu[8];
#pragma unroll
    for (int i = 0; i < 8; ++i) eu[i] = __expf(ec[i] - mx);
    // scan3: cumsum of eu -> c1
    float run3 = 0.f, c1[8];
#pragma unroll
    for (int i = 0; i < 8; ++i) { run3 += eu[i]; c1[i] = run3; }
    float ex3 = wexcl(run3, lane);
#pragma unroll
    for (int i = 0; i < 8; ++i) c1[i] += ex3;
    // denom[t] = c1[t] - c1[t-8]; t-8 lives at (lane-1, i)
    float r[8];
#pragma unroll
    for (int i = 0; i < 8; ++i) {
      float up = __shfl_up(c1[i], 1, 64);
      float prev = (lane == 0) ? 0.f : up;
      float denom = fmaxf(c1[i] - prev, 1e-10f);
      r[i] = alpha_new[i] * __builtin_amdgcn_rcpf(denom);
    }
    // scan4: cumsum of r -> c2
    float run4 = 0.f, c2[8];
#pragma unroll
    for (int i = 0; i < 8; ++i) { run4 += r[i]; c2[i] = run4; }
    float ex4 = wexcl(run4, lane);
#pragma unroll
    for (int i = 0; i < 8; ++i) c2[i] += ex4;
    // ms2[t] = c2[min(t+7,511)] - c2[t-1]
    float c2_7 = c2[7];
    float dn[8];
#pragma unroll
    for (int i = 0; i < 8; ++i) dn[i] = __shfl_down(c2[i], 1, 64);
    float up7 = __shfl_up(c2_7, 1, 64);
    float beta[8];
#pragma unroll
    for (int i = 0; i < 8; ++i) {
      float hi = (i == 0) ? c2_7 : ((lane == 63) ? c2_7 : dn[i - 1]);
      float lo = (i == 0) ? ((lane == 0) ? 0.f : up7) : c2[i - 1];
      beta[i] = eu[i] * (hi - lo);
    }
    float* bp = beta_all + ((size_t)(b * T_DEC + s)) * T_ENC + lane * 8;
    *(float4*)bp       = (float4){beta[0], beta[1], beta[2], beta[3]};
    *(float4*)(bp + 4) = (float4){beta[4], beta[5], beta[6], beta[7]};
#pragma unroll
    for (int i = 0; i < 8; ++i) alpha[i] = alpha_new[i];
  }
}

// ---------------- context: ctx[b,s,:] = sum_t beta[b,s,t] * enc[b,t,:] -----
__global__ __launch_bounds__(256) void context_kernel(
    const float* __restrict__ beta_all, const float* __restrict__ enc,
    float* __restrict__ A_comb)
{
  __shared__ float smem[T_ENC * 36];                 // [t][36] padded, 73.7 KB
  const int b = blockIdx.x, e0 = blockIdx.y << 6;
  const int tid = threadIdx.x;
  const float* bp = beta_all + (size_t)b * T_DEC * T_ENC;
  for (int i = tid; i < T_DEC * T_ENC; i += 256) {
    int s2 = i >> 9, t = i & 511;
    smem[t * 36 + s2] = bp[i];
  }
  __syncthreads();
  const int el = tid & 63, tg = tid >> 6;
  float4 a8[8];
#pragma unroll
  for (int u = 0; u < 8; ++u) a8[u] = (float4){0.f, 0.f, 0.f, 0.f};
  const float* ep = enc + (size_t)b * T_ENC * E + e0 + el;
  for (int t = tg; t < T_ENC; t += 4) {
    float v = ep[(size_t)t * E];
    const float4* bt = (const float4*)&smem[t * 36];
#pragma unroll
    for (int u = 0; u < 8; ++u) {
      float4 bv = bt[u];
      a8[u].x += bv.x * v; a8[u].y += bv.y * v;
      a8[u].z += bv.z * v; a8[u].w += bv.w * v;
    }
  }
  __syncthreads();
#pragma unroll
  for (int u = 0; u < 8; ++u) {
    smem[((tg * T_DEC + u * 4 + 0) << 6) + el] = a8[u].x;
    smem[((tg * T_DEC + u * 4 + 1) << 6) + el] = a8[u].y;
    smem[((tg * T_DEC + u * 4 + 2) << 6) + el] = a8[u].z;
    smem[((tg * T_DEC + u * 4 + 3) << 6) + el] = a8[u].w;
  }
  __syncthreads();
  for (int o = tid; o < T_DEC * 64; o += 256) {
    int s2 = o >> 6, e = o & 63;
    float v = smem[(s2 << 6) + e] + smem[((T_DEC + s2) << 6) + e]
            + smem[((2 * T_DEC + s2) << 6) + e] + smem[((3 * T_DEC + s2) << 6) + e];
    A_comb[((size_t)(b * T_DEC + s2)) * (2 * E) + e0 + e] = v;
  }
}

// ---------------- attn = tanh(A_comb[1024,512] @ Wt[512,256]) -> bf16 ------
__global__ __launch_bounds__(256) void comb_tanh_kernel(
    const float* __restrict__ A, const float* __restrict__ Wt,
    unsigned short* __restrict__ attn_bf)
{
  __shared__ float As[64][68];
  __shared__ float Ws[64][68];
  const int tid = threadIdx.x, tx = tid & 15, ty = tid >> 4;
  const int row0 = blockIdx.y * 64, col0 = blockIdx.x * 64;
  float acc[4][4];
#pragma unroll
  for (int i = 0; i < 4; i++)
#pragma unroll
    for (int jj = 0; jj < 4; jj++) acc[i][jj] = 0.f;

  for (int k0 = 0; k0 < 2 * E; k0 += 64) {
#pragma unroll
    for (int ss = 0; ss < 4; ss++) {
      int i = (ss << 4) + ty;
      int jj = tx << 2;
      float4 av = *(const float4*)(A + (size_t)(row0 + i) * (2 * E) + k0 + jj);
      As[jj][i] = av.x; As[jj + 1][i] = av.y; As[jj + 2][i] = av.z; As[jj + 3][i] = av.w;
      float4 wv = *(const float4*)(Wt + (size_t)(k0 + i) * E + col0 + jj);
      *(float4*)&Ws[i][jj] = wv;
    }
    __syncthreads();
#pragma unroll
    for (int kk = 0; kk < 64; kk++) {
      const float4 af = *(const float4*)&As[kk][ty << 2];
      const float4 bf = *(const float4*)&Ws[kk][tx << 2];
      acc[0][0] += af.x * bf.x; acc[0][1] += af.x * bf.y; acc[0][2] += af.x * bf.z; acc[0][3] += af.x * bf.w;
      acc[1][0] += af.y * bf.x; acc[1][1] += af.y * bf.y; acc[1][2] += af.y * bf.z; acc[1][3] += af.y * bf.w;
      acc[2][0] += af.z * bf.x; acc[2][1] += af.z * bf.y; acc[2][2] += af.z * bf.z; acc[2][3] += af.z * bf.w;
      acc[3][0] += af.w * bf.x; acc[3][1] += af.w * bf.y; acc[3][2] += af.w * bf.z; acc[3][3] += af.w * bf.w;
    }
    __syncthreads();
  }
#pragma unroll
  for (int i = 0; i < 4; i++) {
    ushort4 o;
    o.x = f2bf(ftanh(acc[i][0])); o.y = f2bf(ftanh(acc[i][1]));
    o.z = f2bf(ftanh(acc[i][2])); o.w = f2bf(ftanh(acc[i][3]));
    *(ushort4*)(attn_bf + (size_t)(row0 + (ty << 2) + i) * E + col0 + (tx << 2)) = o;
  }
}

// ---------------- projection: one block per 64-col W panel, loop M ---------
// W panel staged once in LDS (read exactly once from HBM); A (512 KB) stays
// L2-resident across its 16 re-reads. Output written via proven LDS-staged
// full-line stores.
__global__ __launch_bounds__(256) void proj_mfma(
    const unsigned short* __restrict__ A, const unsigned short* __restrict__ Bw,
    const float* __restrict__ bias, float* __restrict__ Y)
{
  __shared__ unsigned short wl[64][264];   // 33.8 KB, padded (2-way free)
  __shared__ float tile[64][68];           // 17.4 KB
  const int tid = threadIdx.x;
  const int wave = tid >> 6, lane = tid & 63;
  const int m = lane & 15, q = lane >> 4;
  const int col0 = blockIdx.x * 64;
#pragma unroll
  for (int u = 0; u < 16; ++u) {
    int f = tid + (u << 8);
    int r = f >> 6, c = (f & 63) << 2;
    *(ushort4*)&wl[r][c] = *(const ushort4*)(Bw + (size_t)(col0 + r) * E + c);
  }
  __syncthreads();

  for (int mt = 0; mt < 16; ++mt) {
    const int rowa = mt * 64 + wave * 16;
    floatx4 acc0 = {0.f, 0.f, 0.f, 0.f}, acc1 = acc0, acc2 = acc0, acc3 = acc0;
    const unsigned short* ar = A + (size_t)(rowa + m) * E + q * 8;
#pragma unroll
    for (int k0 = 0; k0 < E; k0 += 32) {
      short8 af = *(const short8*)(ar + k0);
      short8 b0 = *(const short8*)&wl[ 0 + m][q * 8 + k0];
      short8 b1 = *(const short8*)&wl[16 + m][q * 8 + k0];
      short8 b2 = *(const short8*)&wl[32 + m][q * 8 + k0];
      short8 b3 = *(const short8*)&wl[48 + m][q * 8 + k0];
      acc0 = __builtin_amdgcn_mfma_f32_16x16x32_bf16(af, b0, acc0, 0, 0, 0);
      acc1 = __builtin_amdgcn_mfma_f32_16x16x32_bf16(af, b1, acc1, 0, 0, 0);
      acc2 = __builtin_amdgcn_mfma_f32_16x16x32_bf16(af, b2, acc2, 0, 0, 0);
      acc3 = __builtin_amdgcn_mfma_f32_16x16x32_bf16(af, b3, acc3, 0, 0, 0);
    }
    const int rl = wave * 16 + q * 4;
#pragma unroll
    for (int r = 0; r < 4; r++) {
      tile[rl + r][ 0 + m] = acc0[r];
      tile[rl + r][16 + m] = acc1[r];
      tile[rl + r][32 + m] = acc2[r];
      tile[rl + r][48 + m] = acc3[r];
    }
    __syncthreads();
    const int row = tid >> 2, seg = tid & 3;
    const size_t yb = ((size_t)mt * 64 + row) * VOCAB + col0;
#pragma unroll
    for (int u = 0; u < 4; u++) {
      int cc = seg * 16 + u * 4;
      float4 v = *(const float4*)&tile[row][cc];
      float4 bb = *(const float4*)(bias + col0 + cc);
      v.x += bb.x; v.y += bb.y; v.z += bb.z; v.w += bb.w;
      *(float4*)(Y + yb + cc) = v;
    }
    __syncthreads();
  }
}

// ---------------- launch ----------------
extern "C" void kernel_launch(void* const* d_in, const int* in_sizes, int n_in,
                              void* d_out, int out_size, void* d_ws, size_t ws_size,
                              hipStream_t stream)
{
  (void)in_sizes; (void)n_in; (void)out_size; (void)ws_size;
  const float* enc    = (const float*)d_in[0];
  const int*   dec    = (const int*)d_in[1];
  const float* h0     = (const float*)d_in[2];
  const float* noise  = (const float*)d_in[3];
  const float* emb    = (const float*)d_in[4];
  const float* W_ih   = (const float*)d_in[5];
  const float* b_ih   = (const float*)d_in[6];
  const float* W_hh   = (const float*)d_in[7];
  const float* b_hh   = (const float*)d_in[8];
  const float* Wm     = (const float*)d_in[9];
  const float* Vm     = (const float*)d_in[10];
  const float* bm     = (const float*)d_in[11];
  const float* vvm    = (const float*)d_in[12];
  const float* gm     = (const float*)d_in[13];
  const float* vbm    = (const float*)d_in[14];
  const float* rmp    = (const float*)d_in[15];
  const float* Wc     = (const float*)d_in[16];
  const float* Vc     = (const float*)d_in[17];
  const float* bc     = (const float*)d_in[18];
  const float* vvc    = (const float*)d_in[19];
  const float* gc     = (const float*)d_in[20];
  const float* vbc    = (const float*)d_in[21];
  const float* rcp_   = (const float*)d_in[22];
  const float* W_comb = (const float*)d_in[23];
  const float* W_proj = (const float*)d_in[24];
  const float* b_proj = (const float*)d_in[25];

  float* ws = (float*)d_ws;
  float* encW    = ws + OFF_ENCW;
  float* w_effm  = ws + OFF_WEFFM;
  float* w_effc  = ws + OFF_WEFFC;
  float* bsum    = ws + OFF_BSUM;
  float* Xih     = ws + OFF_XIH;
  float* W_hhT   = ws + OFF_WHHT;
  float* W_combT = ws + OFF_WCOMBT;
  unsigned short* attn_bf = (unsigned short*)(ws + OFF_ATTNB);
  unsigned short* Wp_bf   = (unsigned short*)(ws + OFF_WPBF);

  float* outF = (float*)d_out;
  float* embX     = outF + OUT_EMBX;     // scratch in d_out, all consumed
  float* beta_all = outF + OUT_BETA;     //   before proj_mfma overwrites it
  float* A_comb   = outF + OUT_ACOMB;
  float* h_all    = outF + OUT_HALL;
  float* g_hv     = outF + OUT_HV;
  float* g_pe     = outF + OUT_PE;
  float* Vmc      = outF + OUT_VMC;
  float* zero512  = outF + OUT_ZERO;
  unsigned short* Whi = (unsigned short*)(outF + OUT_WHI);
  unsigned short* Wlo = (unsigned short*)(outF + OUT_WLO);
  float* bias512  = outF + OUT_B512;

  // ---- step-invariant prep ----
  prep_misc<<<259, 256, 0, stream>>>(vvm, gm, w_effm, vvc, gc, w_effc,
                                     b_ih, b_hh, bsum, bm, bc, bias512,
                                     Vm, Vc, Vmc, zero512, Wm, Wc, Whi, Wlo);
  transpose2<<<192, 256, 0, stream>>>(W_hh, W_hhT, W_comb, W_combT);
  gather_emb<<<T_DEC * B, 256, 0, stream>>>(dec, emb, embX);
  gemm_xwt<<<dim3(E / 64, (T_DEC * B) / 64), 256, 0, stream>>>(embX, W_ih, bsum, Xih,
                                                               T_DEC * B, E, E);
  // encW (both matrices) via split-bf16 MFMA, read enc once
  enc_mfma<<<(B * T_ENC) / 64, 256, 0, stream>>>(enc, Whi, Wlo, bias512, encW);
  cvt_bf16<<<(VOCAB * E) / 1024, 256, 0, stream>>>(W_proj, Wp_bf);

  // ---- sequential part 1: the h-chain ----
  hchain_kernel<<<B, 1024, 0, stream>>>(Xih, W_hhT, h0, A_comb, h_all);

  // ---- hV = [Vm;Vc] h for all (b,s) ----
  gemm_xwt<<<dim3((2 * E) / 64, (T_DEC * B) / 64), 256, 0, stream>>>(
      h_all, Vmc, zero512, g_hv, T_DEC * B, 2 * E, E);

  // ---- energies for all (b,s,t), fused encW read once ----
  energy_kernel<<<dim3(B, T_ENC / 16), 256, 0, stream>>>(
      encW, g_hv, w_effm, w_effc, vbm, rmp, vbc, rcp_, g_pe);

  // ---- sequential part 2: alpha/beta scans, one wave per b ----
  scan_kernel<<<B, 64, 0, stream>>>(g_pe, noise, beta_all);

  // ---- hoisted epilogue ----
  context_kernel<<<dim3(B, 4), 256, 0, stream>>>(beta_all, enc, A_comb);
  comb_tanh_kernel<<<dim3(E / 64, (T_DEC * B) / 64), 256, 0, stream>>>(A_comb, W_combT, attn_bf);
  proj_mfma<<<VOCAB / 64, 256, 0, stream>>>(attn_bf, Wp_bf, b_proj, outF);
}

// Round 4
// 595.868 us; speedup vs baseline: 3.9947x; 1.0638x over previous
//
#include <hip/hip_runtime.h>
#include <cstddef>

#define B 32
#define T_ENC 512
#define T_DEC 32
#define E 256
#define VOCAB 32000
#define SOS 1

typedef __attribute__((ext_vector_type(8))) short short8;   // 8 x bf16
typedef __attribute__((ext_vector_type(4))) float floatx4;  // MFMA acc

// ---------------- workspace layout (float offsets) ----------------
static const size_t OFF_ENCW   = 0;                                    // 8388608: fused [16384][512]
static const size_t OFF_WEFFM  = OFF_ENCW + (size_t)B * T_ENC * 2 * E; // 256
static const size_t OFF_WEFFC  = OFF_WEFFM + E;                        // 256
static const size_t OFF_BSUM   = OFF_WEFFC + E;                        // 256
static const size_t OFF_XIH    = OFF_BSUM + E;                         // 262144
static const size_t OFF_WHHT   = OFF_XIH + (size_t)T_DEC * B * E;      // 65536
static const size_t OFF_VMT    = OFF_WHHT + (size_t)E * E;             // 65536 (unused)
static const size_t OFF_VCT    = OFF_VMT + (size_t)E * E;              // 65536 (unused)
static const size_t OFF_WCOMBT = OFF_VCT + (size_t)E * E;              // 131072
static const size_t OFF_ATTNB  = OFF_WCOMBT + (size_t)2 * E * E;       // 131072 floats (ushort x2)
static const size_t OFF_WPBF   = OFF_ATTNB + (size_t)T_DEC * B * E / 2;// 4096000 floats (ushort x2)

// ---------------- d_out scratch layout (float offsets) ----------------
static const size_t OUT_EMBX  = 0;         // 262144 (consumed by Xih gemm)
static const size_t OUT_BETA  = 262144;    // 524288: beta[b][s][t]
static const size_t OUT_ACOMB = 786432;    // 524288: [ctx | h] rows (b*32+s) x 512
static const size_t OUT_HALL  = 1310720;   // 262144: h[b][s][256]
static const size_t OUT_HV    = 1572864;   // 524288: [hVm | hVc] rows (b*32+s) x 512
static const size_t OUT_PE    = 2097152;   // 1048576: g_pe[b][col][t], col = type*32+s
static const size_t OUT_VMC   = 3145728;   // 131072: [Vm ; Vc]
static const size_t OUT_ZERO  = 3276800;   // 512 zeros
static const size_t OUT_WHI   = 3277312;   // 65536 floats = 131072 ushort: W split hi [512][256]
static const size_t OUT_WLO   = 3342848;   // 65536 floats: W split lo
static const size_t OUT_B512  = 3408384;   // 512: [bm ; bc]

// ---------------- helpers ----------------
__device__ __forceinline__ float ftanh(float x) {
  float ax = __builtin_fabsf(x);
  float e  = __expf(-2.f * ax);
  float r  = (1.f - e) * __builtin_amdgcn_rcpf(1.f + e);
  return __builtin_copysignf(r, x);
}

__device__ __forceinline__ float fsigmoid(float z) {
  return __builtin_amdgcn_rcpf(1.f + __expf(-z));
}

__device__ __forceinline__ float wredmax(float s) {
  s = fmaxf(s, __shfl_xor(s, 1, 64));  s = fmaxf(s, __shfl_xor(s, 2, 64));
  s = fmaxf(s, __shfl_xor(s, 4, 64));  s = fmaxf(s, __shfl_xor(s, 8, 64));
  s = fmaxf(s, __shfl_xor(s, 16, 64)); s = fmaxf(s, __shfl_xor(s, 32, 64));
  return s;
}

__device__ __forceinline__ unsigned short f2bf(float f) {
  unsigned int u = __float_as_uint(f);
  u = (u + 0x7fffu + ((u >> 16) & 1u)) >> 16;   // RNE
  return (unsigned short)u;
}

__device__ __forceinline__ float bf2f(unsigned short h) {
  return __uint_as_float((unsigned int)h << 16);
}

// exclusive prefix (across 64 lanes) of per-lane totals
__device__ __forceinline__ float wexcl(float tot, int lane) {
  float v = tot;
#pragma unroll
  for (int off = 1; off < 64; off <<= 1) {
    float y = __shfl_up(v, off, 64);
    if (lane >= off) v += y;
  }
  return v - tot;
}

// ---------------- merged tiny prep: weff x2, biases, concat V, W split -----
__global__ __launch_bounds__(256) void prep_misc(
    const float* __restrict__ vvm, const float* __restrict__ gm, float* __restrict__ w_effm,
    const float* __restrict__ vvc, const float* __restrict__ gc, float* __restrict__ w_effc,
    const float* __restrict__ b_ih, const float* __restrict__ b_hh, float* __restrict__ bsum,
    const float* __restrict__ bm, const float* __restrict__ bc, float* __restrict__ bias512,
    const float* __restrict__ Vm, const float* __restrict__ Vc,
    float* __restrict__ Vmc, float* __restrict__ zero512,
    const float* __restrict__ Wm, const float* __restrict__ Wc,
    unsigned short* __restrict__ Whi, unsigned short* __restrict__ Wlo)
{
  __shared__ float red[256];
  const int blk = blockIdx.x, tid = threadIdx.x;
  if (blk < 2) {
    const float* vv = blk ? vvc : vvm;
    const float* g  = blk ? gc  : gm;
    float* out      = blk ? w_effc : w_effm;
    float v = vv[tid];
    red[tid] = v * v;
    __syncthreads();
    for (int off = 128; off > 0; off >>= 1) {
      if (tid < off) red[tid] += red[tid + off];
      __syncthreads();
    }
    float norm = sqrtf(red[0]);
    out[tid] = (g[0] / norm) * v;
  } else if (blk == 2) {
    bsum[tid] = b_ih[tid] + b_hh[tid];
    bias512[tid]       = bm[tid];
    bias512[256 + tid] = bc[tid];
    zero512[tid] = 0.f;
    zero512[256 + tid] = 0.f;
  } else if (blk < 131) {
    int i = (blk - 3) * 1024 + tid * 4;
    float4 v = (i < E * E) ? *(const float4*)(Vm + i) : *(const float4*)(Vc + i - E * E);
    *(float4*)(Vmc + i) = v;
  } else {
    int i = (blk - 131) * 1024 + tid * 4;
    float4 v = (i < E * E) ? *(const float4*)(Wm + i) : *(const float4*)(Wc + i - E * E);
    ushort4 h, l;
    h.x = f2bf(v.x); l.x = f2bf(v.x - bf2f(h.x));
    h.y = f2bf(v.y); l.y = f2bf(v.y - bf2f(h.y));
    h.z = f2bf(v.z); l.z = f2bf(v.z - bf2f(h.z));
    h.w = f2bf(v.w); l.w = f2bf(v.w - bf2f(h.w));
    *(ushort4*)(Whi + i) = h;
    *(ushort4*)(Wlo + i) = l;
  }
}

// ---------------- two transposes in one launch ----------------
__global__ __launch_bounds__(256) void transpose2(
    const float* __restrict__ W_hh, float* __restrict__ W_hhT,
    const float* __restrict__ W_comb, float* __restrict__ W_combT)
{
  __shared__ float tl[32][33];
  const int blk = blockIdx.x;
  const float* in; float* out; int C, bx, by;
  if (blk < 64) { in = W_hh;   out = W_hhT;   C = 256; bx = blk & 7;  by = blk >> 3; }
  else { int k = blk - 64; in = W_comb; out = W_combT; C = 512; bx = k & 15; by = k >> 4; }
  const int R = 256;
  const int tx = threadIdx.x & 31, ty = threadIdx.x >> 5;
  const int c0 = bx * 32, r0 = by * 32;
#pragma unroll
  for (int k = 0; k < 4; k++)
    tl[ty + 8 * k][tx] = in[(size_t)(r0 + ty + 8 * k) * C + c0 + tx];
  __syncthreads();
#pragma unroll
  for (int k = 0; k < 4; k++)
    out[(size_t)(c0 + ty + 8 * k) * R + r0 + tx] = tl[tx][ty + 8 * k];
}

// ---------------- gather embeddings ----------------
__global__ __launch_bounds__(256) void gather_emb(
    const int* __restrict__ dec, const float* __restrict__ emb, float* __restrict__ embX)
{
  int r = blockIdx.x, d = threadIdx.x;
  int s = r >> 5, b = r & 31;
  int tok = (s == 0) ? SOS : dec[b * T_DEC + s - 1];
  embX[(size_t)r * E + d] = emb[(size_t)tok * E + d];
}

// ---------------- f32 -> bf16 convert ----------------
__global__ __launch_bounds__(256) void cvt_bf16(
    const float* __restrict__ src, unsigned short* __restrict__ dst)
{
  size_t i = ((size_t)blockIdx.x * 256 + threadIdx.x) * 4;
  float4 v = *(const float4*)(src + i);
  ushort4 o;
  o.x = f2bf(v.x); o.y = f2bf(v.y); o.z = f2bf(v.z); o.w = f2bf(v.w);
  *(ushort4*)(dst + i) = o;
}

// ---------------- Y[r,n] = bias[n] + sum_k A[r,k]*W[n,k] (f32, small) ------
__global__ __launch_bounds__(256) void gemm_xwt(
    const float* __restrict__ A, const float* __restrict__ W,
    const float* __restrict__ bias, float* __restrict__ Y,
    int M, int N, int K)
{
  __shared__ float As[64][68];
  __shared__ float Ws[64][68];
  const int tid = threadIdx.x;
  const int tx = tid & 15, ty = tid >> 4;
  const int row0 = blockIdx.y * 64, col0 = blockIdx.x * 64;
  float acc[4][4];
#pragma unroll
  for (int i = 0; i < 4; i++)
#pragma unroll
    for (int j = 0; j < 4; j++) acc[i][j] = 0.f;

  for (int k0 = 0; k0 < K; k0 += 64) {
#pragma unroll
    for (int s = 0; s < 4; s++) {
      int i = (s << 4) + ty;
      int j = tx << 2;
      float4 av = *(const float4*)(A + (size_t)(row0 + i) * K + k0 + j);
      As[j][i] = av.x; As[j + 1][i] = av.y; As[j + 2][i] = av.z; As[j + 3][i] = av.w;
      float4 wv = *(const float4*)(W + (size_t)(col0 + i) * K + k0 + j);
      Ws[j][i] = wv.x; Ws[j + 1][i] = wv.y; Ws[j + 2][i] = wv.z; Ws[j + 3][i] = wv.w;
    }
    __syncthreads();
#pragma unroll
    for (int kk = 0; kk < 64; kk++) {
      const float4 af = *(const float4*)&As[kk][ty << 2];
      const float4 bf = *(const float4*)&Ws[kk][tx << 2];
      acc[0][0] += af.x * bf.x; acc[0][1] += af.x * bf.y; acc[0][2] += af.x * bf.z; acc[0][3] += af.x * bf.w;
      acc[1][0] += af.y * bf.x; acc[1][1] += af.y * bf.y; acc[1][2] += af.y * bf.z; acc[1][3] += af.y * bf.w;
      acc[2][0] += af.z * bf.x; acc[2][1] += af.z * bf.y; acc[2][2] += af.z * bf.z; acc[2][3] += af.z * bf.w;
      acc[3][0] += af.w * bf.x; acc[3][1] += af.w * bf.y; acc[3][2] += af.w * bf.z; acc[3][3] += af.w * bf.w;
    }
    __syncthreads();
  }
  const float4 bv = *(const float4*)(bias + col0 + (tx << 2));
#pragma unroll
  for (int i = 0; i < 4; i++) {
    float4 o;
    o.x = acc[i][0] + bv.x; o.y = acc[i][1] + bv.y;
    o.z = acc[i][2] + bv.z; o.w = acc[i][3] + bv.w;
    *(float4*)(Y + (size_t)(row0 + (ty << 2) + i) * N + col0 + (tx << 2)) = o;
  }
}

// ---------------- encW = [enc@Wm.T+bm ; enc@Wc.T+bc] via split-bf16 MFMA ---
__global__ __launch_bounds__(256) void enc_mfma(
    const float* __restrict__ A,
    const unsigned short* __restrict__ Whi, const unsigned short* __restrict__ Wlo,
    const float* __restrict__ bias512, float* __restrict__ Y)
{
  __shared__ unsigned short a_hi[64][264];
  __shared__ unsigned short a_lo[64][264];
  const int tid = threadIdx.x;
  const int row0 = blockIdx.x * 64;
#pragma unroll
  for (int u = 0; u < 16; ++u) {
    int f = tid + (u << 8);
    int r = f >> 6, c = (f & 63) << 2;
    float4 v = *(const float4*)(A + (size_t)(row0 + r) * E + c);
    ushort4 h, l;
    h.x = f2bf(v.x); l.x = f2bf(v.x - bf2f(h.x));
    h.y = f2bf(v.y); l.y = f2bf(v.y - bf2f(h.y));
    h.z = f2bf(v.z); l.z = f2bf(v.z - bf2f(h.z));
    h.w = f2bf(v.w); l.w = f2bf(v.w - bf2f(h.w));
    *(ushort4*)&a_hi[r][c] = h;
    *(ushort4*)&a_lo[r][c] = l;
  }
  __syncthreads();
  const int lane = tid & 63, w = tid >> 6;
  const int m = lane & 15, q = lane >> 4;
  const int colbase = w << 7;
#pragma unroll
  for (int cp = 0; cp < 4; ++cp) {
    const int c0 = colbase + (cp << 5);
    floatx4 acc[4][2] = {};
    for (int k0 = 0; k0 < E; k0 += 32) {
      const size_t w0 = (size_t)(c0 + m) * E + (q << 3) + k0;
      const size_t w1 = (size_t)(c0 + 16 + m) * E + (q << 3) + k0;
      short8 bh0 = *(const short8*)(Whi + w0);
      short8 bl0 = *(const short8*)(Wlo + w0);
      short8 bh1 = *(const short8*)(Whi + w1);
      short8 bl1 = *(const short8*)(Wlo + w1);
#pragma unroll
      for (int rg = 0; rg < 4; ++rg) {
        short8 ah = *(const short8*)&a_hi[(rg << 4) + m][(q << 3) + k0];
        short8 al = *(const short8*)&a_lo[(rg << 4) + m][(q << 3) + k0];
        acc[rg][0] = __builtin_amdgcn_mfma_f32_16x16x32_bf16(ah, bh0, acc[rg][0], 0, 0, 0);
        acc[rg][0] = __builtin_amdgcn_mfma_f32_16x16x32_bf16(al, bh0, acc[rg][0], 0, 0, 0);
        acc[rg][0] = __builtin_amdgcn_mfma_f32_16x16x32_bf16(ah, bl0, acc[rg][0], 0, 0, 0);
        acc[rg][0] = __builtin_amdgcn_mfma_f32_16x16x32_bf16(al, bl0, acc[rg][0], 0, 0, 0);
        acc[rg][1] = __builtin_amdgcn_mfma_f32_16x16x32_bf16(ah, bh1, acc[rg][1], 0, 0, 0);
        acc[rg][1] = __builtin_amdgcn_mfma_f32_16x16x32_bf16(al, bh1, acc[rg][1], 0, 0, 0);
        acc[rg][1] = __builtin_amdgcn_mfma_f32_16x16x32_bf16(ah, bl1, acc[rg][1], 0, 0, 0);
        acc[rg][1] = __builtin_amdgcn_mfma_f32_16x16x32_bf16(al, bl1, acc[rg][1], 0, 0, 0);
      }
    }
    const float bia0 = bias512[c0 + m], bia1 = bias512[c0 + 16 + m];
#pragma unroll
    for (int rg = 0; rg < 4; ++rg)
#pragma unroll
      for (int r = 0; r < 4; ++r) {
        const size_t row = row0 + (rg << 4) + (q << 2) + r;
        Y[row * (2 * E) + c0 + m]      = acc[rg][0][r] + bia0;
        Y[row * (2 * E) + c0 + 16 + m] = acc[rg][1][r] + bia1;
      }
  }
}

// ---------------- h-chain: h[s+1] = tanh(Xih + W_hh h[s]), W_hh in regs ----
__global__ __launch_bounds__(1024) void hchain_kernel(
    const float* __restrict__ Xih, const float* __restrict__ W_hhT,
    const float* __restrict__ h0,
    float* __restrict__ A_comb, float* __restrict__ h_all)
{
  __shared__ float h_s[E];
  __shared__ float red[1024];
  const int b = blockIdx.x, tid = threadIdx.x;
  const int c = tid >> 8, d = tid & 255, k0 = c * 64;
  float wreg[64];
#pragma unroll
  for (int j = 0; j < 64; ++j) wreg[j] = W_hhT[(size_t)(k0 + j) * E + d];
  if (tid < E) h_s[tid] = h0[(size_t)b * E + tid];
  __syncthreads();
  for (int s = 0; s < T_DEC; ++s) {
    float acc = 0.f;
#pragma unroll
    for (int j = 0; j < 64; j += 4) {
      float4 hh = *(const float4*)&h_s[k0 + j];
      acc += hh.x * wreg[j] + hh.y * wreg[j + 1] + hh.z * wreg[j + 2] + hh.w * wreg[j + 3];
    }
    red[tid] = acc;
    __syncthreads();
    if (tid < E) {
      float v = red[tid] + red[256 + tid] + red[512 + tid] + red[768 + tid]
              + Xih[((size_t)s * B + b) * E + tid];
      float hh = ftanh(v);
      h_s[tid] = hh;
      A_comb[((size_t)(b * T_DEC + s)) * (2 * E) + E + tid] = hh;
      h_all[((size_t)(b * T_DEC + s)) * E + tid] = hh;
    }
    __syncthreads();
  }
}

// ---------------- energies for ALL (b,s,t): fully parallel ----------------
// Grid (B, T_ENC/16, 2): block = 16 t's x 16 s's. hV half staged in 32KB LDS
// (5 blocks/CU). Wave w owns t-rows t0+w*4..+3. Per s: 8 partial dots per
// lane reduced by a MERGED multi-value butterfly (identical xor-tree order
// to wredsum): after 6 stages lane l holds S[l&7] (j=(type<<2)|row); lane
// captures steps s_local ≡ l>>3 (mod 8) into pv0/pv1 and stores to the
// TRANSPOSED g_pe[b][col][t] layout (col = type*32 + s).
__global__ __launch_bounds__(256) void energy_kernel(
    const float* __restrict__ encW, const float* __restrict__ g_hv,
    const float* __restrict__ w_effm, const float* __restrict__ w_effc,
    const float* __restrict__ vbm, const float* __restrict__ rmp,
    const float* __restrict__ vbc, const float* __restrict__ rcp_,
    float* __restrict__ g_pe)
{
  __shared__ float hv_s[16 * 512];   // 32 KB: rows s0..s0+15 of [hVm|hVc]
  const int b = blockIdx.x, t0 = blockIdx.y << 4, s0 = blockIdx.z << 4;
  const int tid = threadIdx.x, lane = tid & 63, w = tid >> 6;
  const float* hvb = g_hv + ((size_t)(b * T_DEC + s0)) * 512;
  for (int i = tid * 4; i < 16 * 512; i += 1024)
    *(float4*)&hv_s[i] = *(const float4*)(hvb + i);
  __syncthreads();

  const float embias = vbm[0] + rmp[0];
  const float ecbias = vbc[0] + rcp_[0];
  const float bias_l = ((lane >> 2) & 1) ? ecbias : embias;
  const float4 wm4 = *(const float4*)(w_effm + lane * 4);
  const float4 wc4 = *(const float4*)(w_effc + lane * 4);
  const int t = t0 + (w << 2);
  const size_t rb = ((size_t)(b * T_ENC + t)) * 512 + lane * 4;
  const float4 em0 = *(const float4*)(encW + rb);
  const float4 em1 = *(const float4*)(encW + rb + 512);
  const float4 em2 = *(const float4*)(encW + rb + 1024);
  const float4 em3 = *(const float4*)(encW + rb + 1536);
  const float4 ec0 = *(const float4*)(encW + rb + 256);
  const float4 ec1 = *(const float4*)(encW + rb + 768);
  const float4 ec2 = *(const float4*)(encW + rb + 1280);
  const float4 ec3 = *(const float4*)(encW + rb + 1792);

  const bool sb0 = lane & 1, sb1 = lane & 2, sb2 = lane & 4;
  const int myr = lane >> 3;     // step residue this lane captures
  float pv0 = 0.f, pv1 = 0.f;

  for (int sl = 0; sl < 16; ++sl) {
    const float4 hm4 = *(const float4*)&hv_s[(sl << 9) + lane * 4];
    const float4 hc4 = *(const float4*)&hv_s[(sl << 9) + 256 + lane * 4];
    float v0 = wm4.x * ftanh(em0.x + hm4.x) + wm4.y * ftanh(em0.y + hm4.y)
             + wm4.z * ftanh(em0.z + hm4.z) + wm4.w * ftanh(em0.w + hm4.w);
    float v1 = wm4.x * ftanh(em1.x + hm4.x) + wm4.y * ftanh(em1.y + hm4.y)
             + wm4.z * ftanh(em1.z + hm4.z) + wm4.w * ftanh(em1.w + hm4.w);
    float v2 = wm4.x * ftanh(em2.x + hm4.x) + wm4.y * ftanh(em2.y + hm4.y)
             + wm4.z * ftanh(em2.z + hm4.z) + wm4.w * ftanh(em2.w + hm4.w);
    float v3 = wm4.x * ftanh(em3.x + hm4.x) + wm4.y * ftanh(em3.y + hm4.y)
             + wm4.z * ftanh(em3.z + hm4.z) + wm4.w * ftanh(em3.w + hm4.w);
    float v4 = wc4.x * ftanh(ec0.x + hc4.x) + wc4.y * ftanh(ec0.y + hc4.y)
             + wc4.z * ftanh(ec0.z + hc4.z) + wc4.w * ftanh(ec0.w + hc4.w);
    float v5 = wc4.x * ftanh(ec1.x + hc4.x) + wc4.y * ftanh(ec1.y + hc4.y)
             + wc4.z * ftanh(ec1.z + hc4.z) + wc4.w * ftanh(ec1.w + hc4.w);
    float v6 = wc4.x * ftanh(ec2.x + hc4.x) + wc4.y * ftanh(ec2.y + hc4.y)
             + wc4.z * ftanh(ec2.z + hc4.z) + wc4.w * ftanh(ec2.w + hc4.w);
    float v7 = wc4.x * ftanh(ec3.x + hc4.x) + wc4.y * ftanh(ec3.y + hc4.y)
             + wc4.z * ftanh(ec3.z + hc4.z) + wc4.w * ftanh(ec3.w + hc4.w);
    // merged butterfly: j = (type<<2)|row packed as v0..v7 (v4.. = c-type)
    float a0 = sb0 ? v1 : v0;  a0 += __shfl_xor(a0, 1, 64);
    float a1 = sb0 ? v3 : v2;  a1 += __shfl_xor(a1, 1, 64);
    float a2 = sb0 ? v5 : v4;  a2 += __shfl_xor(a2, 1, 64);
    float a3 = sb0 ? v7 : v6;  a3 += __shfl_xor(a3, 1, 64);
    float c0 = sb1 ? a1 : a0;  c0 += __shfl_xor(c0, 2, 64);
    float c1 = sb1 ? a3 : a2;  c1 += __shfl_xor(c1, 2, 64);
    float dd = sb2 ? c1 : c0;  dd += __shfl_xor(dd, 4, 64);
    dd += __shfl_xor(dd, 8, 64);
    dd += __shfl_xor(dd, 16, 64);
    dd += __shfl_xor(dd, 32, 64);
    // lane l now holds S[ (l&7) ] = S[(type<<2)|row] with type=(l>>2)&1, row=l&3
    float val = dd + bias_l;
    if ((sl & 7) == myr) {
      if (sl & 8) pv1 = val; else pv0 = val;
    }
  }
  // store to transposed layout g_pe[b][col][t], col = type*32 + s
  const int row_l = lane & 3, type = (lane >> 2) & 1;
  const int tS = t0 + (w << 2) + row_l;
  const int col = type * 32 + s0 + myr;
  g_pe[((size_t)((b << 6) + col)) * 512 + tS]     = pv0;
  g_pe[((size_t)((b << 6) + col + 8)) * 512 + tS] = pv1;
}

// ---------------- alpha/beta recurrence: ONE WAVE per b, zero barriers -----
// g_pe now [b][col][t]: per-step reads are contiguous float4s.
__global__ __launch_bounds__(64) void scan_kernel(
    const float* __restrict__ g_pe, const float* __restrict__ noise,
    float* __restrict__ beta_all)
{
  const int b = blockIdx.x, lane = threadIdx.x;
  const float* pe = g_pe + ((size_t)b << 15);   // b*64*512
  float alpha[8];
#pragma unroll
  for (int i = 0; i < 8; ++i) alpha[i] = 0.f;
  if (lane == 0) alpha[0] = 1.f;

  for (int s = 0; s < T_DEC; ++s) {
    const float* nrow = noise + ((size_t)s * B + b) * T_ENC + lane * 8;
    float4 n0 = *(const float4*)nrow;
    float4 n1 = *(const float4*)(nrow + 4);
    float nz[8] = {n0.x, n0.y, n0.z, n0.w, n1.x, n1.y, n1.z, n1.w};
    const float* psm = pe + (size_t)s * 512 + lane * 8;
    const float* pec = pe + (size_t)(32 + s) * 512 + lane * 8;
    float4 m0 = *(const float4*)psm;
    float4 m1 = *(const float4*)(psm + 4);
    float4 e0 = *(const float4*)pec;
    float4 e1 = *(const float4*)(pec + 4);
    float smv[8] = {m0.x, m0.y, m0.z, m0.w, m1.x, m1.y, m1.z, m1.w};
    float ec[8]  = {e0.x, e0.y, e0.z, e0.w, e1.x, e1.y, e1.z, e1.w};
    float p[8];
#pragma unroll
    for (int i = 0; i < 8; ++i) p[i] = fsigmoid(smv[i] + nz[i]);
    // scan1: inclusive cumsum of log(clamp(1-p))
    float lgv[8], lci[8], run = 0.f;
#pragma unroll
    for (int i = 0; i < 8; ++i) {
      float omp = fminf(fmaxf(1.f - p[i], 1e-10f), 1.f);
      lgv[i] = __logf(omp);
      run += lgv[i];
      lci[i] = run;
    }
    float ex1 = wexcl(run, lane);
    float cp[8], ao[8];
#pragma unroll
    for (int i = 0; i < 8; ++i) {
      float incl = lci[i] + ex1;
      cp[i] = __expf(incl - lgv[i]);               // exclusive cumprod
      float cpc = fminf(fmaxf(cp[i], 1e-10f), 1.f);
      ao[i] = alpha[i] * __builtin_amdgcn_rcpf(cpc);
    }
    float run2 = 0.f, lc2[8];
#pragma unroll
    for (int i = 0; i < 8; ++i) { run2 += ao[i]; lc2[i] = run2; }
    float ex2 = wexcl(run2, lane);
    float alpha_new[8];
#pragma unroll
    for (int i = 0; i < 8; ++i) alpha_new[i] = p[i] * cp[i] * (lc2[i] + ex2);
    float mloc = ec[0];
#pragma unroll
    for (int i = 1; i < 8; ++i) mloc = fmaxf(mloc, ec[i]);
    float mx = wredmax(mloc);
    float eu[8];
#pragma unroll
    for (int i = 0; i < 8; ++i) eu[i] = __expf(ec[i] - mx);
    float run3 = 0.f, c1[8];
#pragma unroll
    for (int i = 0; i < 8; ++i) { run3 += eu[i]; c1[i] = run3; }
    float ex3 = wexcl(run3, lane);
#pragma unroll
    for (int i = 0; i < 8; ++i) c1[i] += ex3;
    float r[8];
#pragma unroll
    for (int i = 0; i < 8; ++i) {
      float up = __shfl_up(c1[i], 1, 64);
      float prev = (lane == 0) ? 0.f : up;
      float denom = fmaxf(c1[i] - prev, 1e-10f);
      r[i] = alpha_new[i] * __builtin_amdgcn_rcpf(denom);
    }
    float run4 = 0.f, c2[8];
#pragma unroll
    for (int i = 0; i < 8; ++i) { run4 += r[i]; c2[i] = run4; }
    float ex4 = wexcl(run4, lane);
#pragma unroll
    for (int i = 0; i < 8; ++i) c2[i] += ex4;
    float c2_7 = c2[7];
    float dn[8];
#pragma unroll
    for (int i = 0; i < 8; ++i) dn[i] = __shfl_down(c2[i], 1, 64);
    float up7 = __shfl_up(c2_7, 1, 64);
    float beta[8];
#pragma unroll
    for (int i = 0; i < 8; ++i) {
      float hi = (i == 0) ? c2_7 : ((lane == 63) ? c2_7 : dn[i - 1]);
      float lo = (i == 0) ? ((lane == 0) ? 0.f : up7) : c2[i - 1];
      beta[i] = eu[i] * (hi - lo);
    }
    float* bp = beta_all + ((size_t)(b * T_DEC + s)) * T_ENC + lane * 8;
    *(float4*)bp       = (float4){beta[0], beta[1], beta[2], beta[3]};
    *(float4*)(bp + 4) = (float4){beta[4], beta[5], beta[6], beta[7]};
#pragma unroll
    for (int i = 0; i < 8; ++i) alpha[i] = alpha_new[i];
  }
}

// ---------------- context: ctx[b,s,:] = sum_t beta[b,s,t] * enc[b,t,:] -----
__global__ __launch_bounds__(256) void context_kernel(
    const float* __restrict__ beta_all, const float* __restrict__ enc,
    float* __restrict__ A_comb)
{
  __shared__ float smem[T_ENC * 36];                 // [t][36] padded, 73.7 KB
  const int b = blockIdx.x, e0 = blockIdx.y << 6;
  const int tid = threadIdx.x;
  const float* bp = beta_all + (size_t)b * T_DEC * T_ENC;
  for (int i = tid; i < T_DEC * T_ENC; i += 256) {
    int s2 = i >> 9, t = i & 511;
    smem[t * 36 + s2] = bp[i];
  }
  __syncthreads();
  const int el = tid & 63, tg = tid >> 6;
  float4 a8[8];
#pragma unroll
  for (int u = 0; u < 8; ++u) a8[u] = (float4){0.f, 0.f, 0.f, 0.f};
  const float* ep = enc + (size_t)b * T_ENC * E + e0 + el;
  for (int t = tg; t < T_ENC; t += 4) {
    float v = ep[(size_t)t * E];
    const float4* bt = (const float4*)&smem[t * 36];
#pragma unroll
    for (int u = 0; u < 8; ++u) {
      float4 bv = bt[u];
      a8[u].x += bv.x * v; a8[u].y += bv.y * v;
      a8[u].z += bv.z * v; a8[u].w += bv.w * v;
    }
  }
  __syncthreads();
#pragma unroll
  for (int u = 0; u < 8; ++u) {
    smem[((tg * T_DEC + u * 4 + 0) << 6) + el] = a8[u].x;
    smem[((tg * T_DEC + u * 4 + 1) << 6) + el] = a8[u].y;
    smem[((tg * T_DEC + u * 4 + 2) << 6) + el] = a8[u].z;
    smem[((tg * T_DEC + u * 4 + 3) << 6) + el] = a8[u].w;
  }
  __syncthreads();
  for (int o = tid; o < T_DEC * 64; o += 256) {
    int s2 = o >> 6, e = o & 63;
    float v = smem[(s2 << 6) + e] + smem[((T_DEC + s2) << 6) + e]
            + smem[((2 * T_DEC + s2) << 6) + e] + smem[((3 * T_DEC + s2) << 6) + e];
    A_comb[((size_t)(b * T_DEC + s2)) * (2 * E) + e0 + e] = v;
  }
}

// ---------------- attn = tanh(A_comb[1024,512] @ Wt[512,256]) -> bf16 ------
__global__ __launch_bounds__(256) void comb_tanh_kernel(
    const float* __restrict__ A, const float* __restrict__ Wt,
    unsigned short* __restrict__ attn_bf)
{
  __shared__ float As[64][68];
  __shared__ float Ws[64][68];
  const int tid = threadIdx.x, tx = tid & 15, ty = tid >> 4;
  const int row0 = blockIdx.y * 64, col0 = blockIdx.x * 64;
  float acc[4][4];
#pragma unroll
  for (int i = 0; i < 4; i++)
#pragma unroll
    for (int jj = 0; jj < 4; jj++) acc[i][jj] = 0.f;

  for (int k0 = 0; k0 < 2 * E; k0 += 64) {
#pragma unroll
    for (int ss = 0; ss < 4; ss++) {
      int i = (ss << 4) + ty;
      int jj = tx << 2;
      float4 av = *(const float4*)(A + (size_t)(row0 + i) * (2 * E) + k0 + jj);
      As[jj][i] = av.x; As[jj + 1][i] = av.y; As[jj + 2][i] = av.z; As[jj + 3][i] = av.w;
      float4 wv = *(const float4*)(Wt + (size_t)(k0 + i) * E + col0 + jj);
      *(float4*)&Ws[i][jj] = wv;
    }
    __syncthreads();
#pragma unroll
    for (int kk = 0; kk < 64; kk++) {
      const float4 af = *(const float4*)&As[kk][ty << 2];
      const float4 bf = *(const float4*)&Ws[kk][tx << 2];
      acc[0][0] += af.x * bf.x; acc[0][1] += af.x * bf.y; acc[0][2] += af.x * bf.z; acc[0][3] += af.x * bf.w;
      acc[1][0] += af.y * bf.x; acc[1][1] += af.y * bf.y; acc[1][2] += af.y * bf.z; acc[1][3] += af.y * bf.w;
      acc[2][0] += af.z * bf.x; acc[2][1] += af.z * bf.y; acc[2][2] += af.z * bf.z; acc[2][3] += af.z * bf.w;
      acc[3][0] += af.w * bf.x; acc[3][1] += af.w * bf.y; acc[3][2] += af.w * bf.z; acc[3][3] += af.w * bf.w;
    }
    __syncthreads();
  }
#pragma unroll
  for (int i = 0; i < 4; i++) {
    ushort4 o;
    o.x = f2bf(ftanh(acc[i][0])); o.y = f2bf(ftanh(acc[i][1]));
    o.z = f2bf(ftanh(acc[i][2])); o.w = f2bf(ftanh(acc[i][3]));
    *(ushort4*)(attn_bf + (size_t)(row0 + (ty << 2) + i) * E + col0 + (tx << 2)) = o;
  }
}

// ---------------- projection: one block per 64-col W panel, loop M ---------
__global__ __launch_bounds__(256) void proj_mfma(
    const unsigned short* __restrict__ A, const unsigned short* __restrict__ Bw,
    const float* __restrict__ bias, float* __restrict__ Y)
{
  __shared__ unsigned short wl[64][264];   // 33.8 KB
  __shared__ float tile[64][68];           // 17.4 KB
  const int tid = threadIdx.x;
  const int wave = tid >> 6, lane = tid & 63;
  const int m = lane & 15, q = lane >> 4;
  const int col0 = blockIdx.x * 64;
#pragma unroll
  for (int u = 0; u < 16; ++u) {
    int f = tid + (u << 8);
    int r = f >> 6, c = (f & 63) << 2;
    *(ushort4*)&wl[r][c] = *(const ushort4*)(Bw + (size_t)(col0 + r) * E + c);
  }
  __syncthreads();

  for (int mt = 0; mt < 16; ++mt) {
    const int rowa = mt * 64 + wave * 16;
    floatx4 acc0 = {0.f, 0.f, 0.f, 0.f}, acc1 = acc0, acc2 = acc0, acc3 = acc0;
    const unsigned short* ar = A + (size_t)(rowa + m) * E + q * 8;
#pragma unroll
    for (int k0 = 0; k0 < E; k0 += 32) {
      short8 af = *(const short8*)(ar + k0);
      short8 b0 = *(const short8*)&wl[ 0 + m][q * 8 + k0];
      short8 b1 = *(const short8*)&wl[16 + m][q * 8 + k0];
      short8 b2 = *(const short8*)&wl[32 + m][q * 8 + k0];
      short8 b3 = *(const short8*)&wl[48 + m][q * 8 + k0];
      acc0 = __builtin_amdgcn_mfma_f32_16x16x32_bf16(af, b0, acc0, 0, 0, 0);
      acc1 = __builtin_amdgcn_mfma_f32_16x16x32_bf16(af, b1, acc1, 0, 0, 0);
      acc2 = __builtin_amdgcn_mfma_f32_16x16x32_bf16(af, b2, acc2, 0, 0, 0);
      acc3 = __builtin_amdgcn_mfma_f32_16x16x32_bf16(af, b3, acc3, 0, 0, 0);
    }
    const int rl = wave * 16 + q * 4;
#pragma unroll
    for (int r = 0; r < 4; r++) {
      tile[rl + r][ 0 + m] = acc0[r];
      tile[rl + r][16 + m] = acc1[r];
      tile[rl + r][32 + m] = acc2[r];
      tile[rl + r][48 + m] = acc3[r];
    }
    __syncthreads();
    const int row = tid >> 2, seg = tid & 3;
    const size_t yb = ((size_t)mt * 64 + row) * VOCAB + col0;
#pragma unroll
    for (int u = 0; u < 4; u++) {
      int cc = seg * 16 + u * 4;
      float4 v = *(const float4*)&tile[row][cc];
      float4 bb = *(const float4*)(bias + col0 + cc);
      v.x += bb.x; v.y += bb.y; v.z += bb.z; v.w += bb.w;
      *(float4*)(Y + yb + cc) = v;
    }
    __syncthreads();
  }
}

// ---------------- launch ----------------
extern "C" void kernel_launch(void* const* d_in, const int* in_sizes, int n_in,
                              void* d_out, int out_size, void* d_ws, size_t ws_size,
                              hipStream_t stream)
{
  (void)in_sizes; (void)n_in; (void)out_size; (void)ws_size;
  const float* enc    = (const float*)d_in[0];
  const int*   dec    = (const int*)d_in[1];
  const float* h0     = (const float*)d_in[2];
  const float* noise  = (const float*)d_in[3];
  const float* emb    = (const float*)d_in[4];
  const float* W_ih   = (const float*)d_in[5];
  const float* b_ih   = (const float*)d_in[6];
  const float* W_hh   = (const float*)d_in[7];
  const float* b_hh   = (const float*)d_in[8];
  const float* Wm     = (const float*)d_in[9];
  const float* Vm     = (const float*)d_in[10];
  const float* bm     = (const float*)d_in[11];
  const float* vvm    = (const float*)d_in[12];
  const float* gm     = (const float*)d_in[13];
  const float* vbm    = (const float*)d_in[14];
  const float* rmp    = (const float*)d_in[15];
  const float* Wc     = (const float*)d_in[16];
  const float* Vc     = (const float*)d_in[17];
  const float* bc     = (const float*)d_in[18];
  const float* vvc    = (const float*)d_in[19];
  const float* gc     = (const float*)d_in[20];
  const float* vbc    = (const float*)d_in[21];
  const float* rcp_   = (const float*)d_in[22];
  const float* W_comb = (const float*)d_in[23];
  const float* W_proj = (const float*)d_in[24];
  const float* b_proj = (const float*)d_in[25];

  float* ws = (float*)d_ws;
  float* encW    = ws + OFF_ENCW;
  float* w_effm  = ws + OFF_WEFFM;
  float* w_effc  = ws + OFF_WEFFC;
  float* bsum    = ws + OFF_BSUM;
  float* Xih     = ws + OFF_XIH;
  float* W_hhT   = ws + OFF_WHHT;
  float* W_combT = ws + OFF_WCOMBT;
  unsigned short* attn_bf = (unsigned short*)(ws + OFF_ATTNB);
  unsigned short* Wp_bf   = (unsigned short*)(ws + OFF_WPBF);

  float* outF = (float*)d_out;
  float* embX     = outF + OUT_EMBX;     // scratch in d_out, all consumed
  float* beta_all = outF + OUT_BETA;     //   before proj_mfma overwrites it
  float* A_comb   = outF + OUT_ACOMB;
  float* h_all    = outF + OUT_HALL;
  float* g_hv     = outF + OUT_HV;
  float* g_pe     = outF + OUT_PE;
  float* Vmc      = outF + OUT_VMC;
  float* zero512  = outF + OUT_ZERO;
  unsigned short* Whi = (unsigned short*)(outF + OUT_WHI);
  unsigned short* Wlo = (unsigned short*)(outF + OUT_WLO);
  float* bias512  = outF + OUT_B512;

  // ---- step-invariant prep ----
  prep_misc<<<259, 256, 0, stream>>>(vvm, gm, w_effm, vvc, gc, w_effc,
                                     b_ih, b_hh, bsum, bm, bc, bias512,
                                     Vm, Vc, Vmc, zero512, Wm, Wc, Whi, Wlo);
  transpose2<<<192, 256, 0, stream>>>(W_hh, W_hhT, W_comb, W_combT);
  gather_emb<<<T_DEC * B, 256, 0, stream>>>(dec, emb, embX);
  gemm_xwt<<<dim3(E / 64, (T_DEC * B) / 64), 256, 0, stream>>>(embX, W_ih, bsum, Xih,
                                                               T_DEC * B, E, E);
  enc_mfma<<<(B * T_ENC) / 64, 256, 0, stream>>>(enc, Whi, Wlo, bias512, encW);
  cvt_bf16<<<(VOCAB * E) / 1024, 256, 0, stream>>>(W_proj, Wp_bf);

  // ---- sequential part 1: the h-chain ----
  hchain_kernel<<<B, 1024, 0, stream>>>(Xih, W_hhT, h0, A_comb, h_all);

  // ---- hV = [Vm;Vc] h for all (b,s) ----
  gemm_xwt<<<dim3((2 * E) / 64, (T_DEC * B) / 64), 256, 0, stream>>>(
      h_all, Vmc, zero512, g_hv, T_DEC * B, 2 * E, E);

  // ---- energies for all (b,s,t): merged butterfly + s-split for occupancy
  energy_kernel<<<dim3(B, T_ENC / 16, 2), 256, 0, stream>>>(
      encW, g_hv, w_effm, w_effc, vbm, rmp, vbc, rcp_, g_pe);

  // ---- sequential part 2: alpha/beta scans, one wave per b ----
  scan_kernel<<<B, 64, 0, stream>>>(g_pe, noise, beta_all);

  // ---- hoisted epilogue ----
  context_kernel<<<dim3(B, 4), 256, 0, stream>>>(beta_all, enc, A_comb);
  comb_tanh_kernel<<<dim3(E / 64, (T_DEC * B) / 64), 256, 0, stream>>>(A_comb, W_combT, attn_bf);
  proj_mfma<<<VOCAB / 64, 256, 0, stream>>>(attn_bf, Wp_bf, b_proj, outF);
}

// Round 5
// 580.110 us; speedup vs baseline: 4.1032x; 1.0272x over previous
//
#include <hip/hip_runtime.h>
#include <cstddef>

#define B 32
#define T_ENC 512
#define T_DEC 32
#define E 256
#define VOCAB 32000
#define SOS 1

typedef __attribute__((ext_vector_type(8))) short short8;   // 8 x bf16
typedef __attribute__((ext_vector_type(4))) float floatx4;  // MFMA acc

// ---------------- workspace layout (float offsets) ----------------
static const size_t OFF_ENCW   = 0;                                    // 8388608: fused [16384][512]
static const size_t OFF_WEFFM  = OFF_ENCW + (size_t)B * T_ENC * 2 * E; // 256
static const size_t OFF_WEFFC  = OFF_WEFFM + E;                        // 256
static const size_t OFF_BSUM   = OFF_WEFFC + E;                        // 256
static const size_t OFF_XIH    = OFF_BSUM + E;                         // 262144
static const size_t OFF_WHHT   = OFF_XIH + (size_t)T_DEC * B * E;      // 65536
static const size_t OFF_VMT    = OFF_WHHT + (size_t)E * E;             // 65536 (unused)
static const size_t OFF_VCT    = OFF_VMT + (size_t)E * E;              // 65536 (unused)
static const size_t OFF_WCOMBT = OFF_VCT + (size_t)E * E;              // 131072
static const size_t OFF_ATTNB  = OFF_WCOMBT + (size_t)2 * E * E;       // 131072 floats (ushort x2)
static const size_t OFF_WPBF   = OFF_ATTNB + (size_t)T_DEC * B * E / 2;// 4096000 floats (ushort x2)

// ---------------- d_out scratch layout (float offsets) ----------------
static const size_t OUT_EMBX  = 0;         // 262144 (consumed by Xih gemm)
static const size_t OUT_BETA  = 262144;    // 524288: beta[b][s][t]
static const size_t OUT_ACOMB = 786432;    // 524288: [ctx | h] rows (b*32+s) x 512
static const size_t OUT_HALL  = 1310720;   // 262144: h[b][s][256]
static const size_t OUT_HV    = 1572864;   // 524288: [hVm | hVc] rows (b*32+s) x 512
static const size_t OUT_PE    = 2097152;   // 1048576: g_pe[b][col][t], col = type*32+s
static const size_t OUT_VMC   = 3145728;   // 131072: [Vm ; Vc]
static const size_t OUT_ZERO  = 3276800;   // 512 zeros
static const size_t OUT_WHI   = 3277312;   // 65536 floats = 131072 ushort: W split hi [512][256]
static const size_t OUT_WLO   = 3342848;   // 65536 floats: W split lo
static const size_t OUT_B512  = 3408384;   // 512: [bm ; bc]

// ---------------- helpers ----------------
__device__ __forceinline__ float ftanh(float x) {
  float ax = __builtin_fabsf(x);
  float e  = __expf(-2.f * ax);
  float r  = (1.f - e) * __builtin_amdgcn_rcpf(1.f + e);
  return __builtin_copysignf(r, x);
}

__device__ __forceinline__ float fsigmoid(float z) {
  return __builtin_amdgcn_rcpf(1.f + __expf(-z));
}

__device__ __forceinline__ float wredmax(float s) {
  s = fmaxf(s, __shfl_xor(s, 1, 64));  s = fmaxf(s, __shfl_xor(s, 2, 64));
  s = fmaxf(s, __shfl_xor(s, 4, 64));  s = fmaxf(s, __shfl_xor(s, 8, 64));
  s = fmaxf(s, __shfl_xor(s, 16, 64)); s = fmaxf(s, __shfl_xor(s, 32, 64));
  return s;
}

__device__ __forceinline__ unsigned short f2bf(float f) {
  unsigned int u = __float_as_uint(f);
  u = (u + 0x7fffu + ((u >> 16) & 1u)) >> 16;   // RNE
  return (unsigned short)u;
}

__device__ __forceinline__ float bf2f(unsigned short h) {
  return __uint_as_float((unsigned int)h << 16);
}

// exclusive prefix (across 64 lanes) of per-lane totals
__device__ __forceinline__ float wexcl(float tot, int lane) {
  float v = tot;
#pragma unroll
  for (int off = 1; off < 64; off <<= 1) {
    float y = __shfl_up(v, off, 64);
    if (lane >= off) v += y;
  }
  return v - tot;
}

// sum_i w_i * tanh(x_i) where inputs are PRE-SCALED by -2 (s2 = -2x):
// tanh(x) = (1 - e^{-2x})/(1 + e^{-2x}); num fused with w. Safe (no abs)
// because |x| < ~12 here -> e in [e^-24, e^24], no overflow.
__device__ __forceinline__ float dot4_wtanh(float4 s2a, float4 s2b, float4 w4) {
  float e, num, acc;
  e = __expf(s2a.x + s2b.x); num = __builtin_fmaf(-e, w4.x, w4.x);
  acc = num * __builtin_amdgcn_rcpf(1.f + e);
  e = __expf(s2a.y + s2b.y); num = __builtin_fmaf(-e, w4.y, w4.y);
  acc = __builtin_fmaf(num, __builtin_amdgcn_rcpf(1.f + e), acc);
  e = __expf(s2a.z + s2b.z); num = __builtin_fmaf(-e, w4.z, w4.z);
  acc = __builtin_fmaf(num, __builtin_amdgcn_rcpf(1.f + e), acc);
  e = __expf(s2a.w + s2b.w); num = __builtin_fmaf(-e, w4.w, w4.w);
  acc = __builtin_fmaf(num, __builtin_amdgcn_rcpf(1.f + e), acc);
  return acc;
}

__device__ __forceinline__ float4 scalem2(float4 v) {
  float4 r; r.x = -2.f * v.x; r.y = -2.f * v.y; r.z = -2.f * v.z; r.w = -2.f * v.w;
  return r;
}

// ---------------- merged tiny prep: weff x2, biases, concat V, W split -----
__global__ __launch_bounds__(256) void prep_misc(
    const float* __restrict__ vvm, const float* __restrict__ gm, float* __restrict__ w_effm,
    const float* __restrict__ vvc, const float* __restrict__ gc, float* __restrict__ w_effc,
    const float* __restrict__ b_ih, const float* __restrict__ b_hh, float* __restrict__ bsum,
    const float* __restrict__ bm, const float* __restrict__ bc, float* __restrict__ bias512,
    const float* __restrict__ Vm, const float* __restrict__ Vc,
    float* __restrict__ Vmc, float* __restrict__ zero512,
    const float* __restrict__ Wm, const float* __restrict__ Wc,
    unsigned short* __restrict__ Whi, unsigned short* __restrict__ Wlo)
{
  __shared__ float red[256];
  const int blk = blockIdx.x, tid = threadIdx.x;
  if (blk < 2) {
    const float* vv = blk ? vvc : vvm;
    const float* g  = blk ? gc  : gm;
    float* out      = blk ? w_effc : w_effm;
    float v = vv[tid];
    red[tid] = v * v;
    __syncthreads();
    for (int off = 128; off > 0; off >>= 1) {
      if (tid < off) red[tid] += red[tid + off];
      __syncthreads();
    }
    float norm = sqrtf(red[0]);
    out[tid] = (g[0] / norm) * v;
  } else if (blk == 2) {
    bsum[tid] = b_ih[tid] + b_hh[tid];
    bias512[tid]       = bm[tid];
    bias512[256 + tid] = bc[tid];
    zero512[tid] = 0.f;
    zero512[256 + tid] = 0.f;
  } else if (blk < 131) {
    int i = (blk - 3) * 1024 + tid * 4;
    float4 v = (i < E * E) ? *(const float4*)(Vm + i) : *(const float4*)(Vc + i - E * E);
    *(float4*)(Vmc + i) = v;
  } else {
    int i = (blk - 131) * 1024 + tid * 4;
    float4 v = (i < E * E) ? *(const float4*)(Wm + i) : *(const float4*)(Wc + i - E * E);
    ushort4 h, l;
    h.x = f2bf(v.x); l.x = f2bf(v.x - bf2f(h.x));
    h.y = f2bf(v.y); l.y = f2bf(v.y - bf2f(h.y));
    h.z = f2bf(v.z); l.z = f2bf(v.z - bf2f(h.z));
    h.w = f2bf(v.w); l.w = f2bf(v.w - bf2f(h.w));
    *(ushort4*)(Whi + i) = h;
    *(ushort4*)(Wlo + i) = l;
  }
}

// ---------------- two transposes in one launch ----------------
__global__ __launch_bounds__(256) void transpose2(
    const float* __restrict__ W_hh, float* __restrict__ W_hhT,
    const float* __restrict__ W_comb, float* __restrict__ W_combT)
{
  __shared__ float tl[32][33];
  const int blk = blockIdx.x;
  const float* in; float* out; int C, bx, by;
  if (blk < 64) { in = W_hh;   out = W_hhT;   C = 256; bx = blk & 7;  by = blk >> 3; }
  else { int k = blk - 64; in = W_comb; out = W_combT; C = 512; bx = k & 15; by = k >> 4; }
  const int R = 256;
  const int tx = threadIdx.x & 31, ty = threadIdx.x >> 5;
  const int c0 = bx * 32, r0 = by * 32;
#pragma unroll
  for (int k = 0; k < 4; k++)
    tl[ty + 8 * k][tx] = in[(size_t)(r0 + ty + 8 * k) * C + c0 + tx];
  __syncthreads();
#pragma unroll
  for (int k = 0; k < 4; k++)
    out[(size_t)(c0 + ty + 8 * k) * R + r0 + tx] = tl[tx][ty + 8 * k];
}

// ---------------- gather embeddings ----------------
__global__ __launch_bounds__(256) void gather_emb(
    const int* __restrict__ dec, const float* __restrict__ emb, float* __restrict__ embX)
{
  int r = blockIdx.x, d = threadIdx.x;
  int s = r >> 5, b = r & 31;
  int tok = (s == 0) ? SOS : dec[b * T_DEC + s - 1];
  embX[(size_t)r * E + d] = emb[(size_t)tok * E + d];
}

// ---------------- f32 -> bf16 convert ----------------
__global__ __launch_bounds__(256) void cvt_bf16(
    const float* __restrict__ src, unsigned short* __restrict__ dst)
{
  size_t i = ((size_t)blockIdx.x * 256 + threadIdx.x) * 4;
  float4 v = *(const float4*)(src + i);
  ushort4 o;
  o.x = f2bf(v.x); o.y = f2bf(v.y); o.z = f2bf(v.z); o.w = f2bf(v.w);
  *(ushort4*)(dst + i) = o;
}

// ---------------- Y[r,n] = bias[n] + sum_k A[r,k]*W[n,k] (f32, small) ------
__global__ __launch_bounds__(256) void gemm_xwt(
    const float* __restrict__ A, const float* __restrict__ W,
    const float* __restrict__ bias, float* __restrict__ Y,
    int M, int N, int K)
{
  __shared__ float As[64][68];
  __shared__ float Ws[64][68];
  const int tid = threadIdx.x;
  const int tx = tid & 15, ty = tid >> 4;
  const int row0 = blockIdx.y * 64, col0 = blockIdx.x * 64;
  float acc[4][4];
#pragma unroll
  for (int i = 0; i < 4; i++)
#pragma unroll
    for (int j = 0; j < 4; j++) acc[i][j] = 0.f;

  for (int k0 = 0; k0 < K; k0 += 64) {
#pragma unroll
    for (int s = 0; s < 4; s++) {
      int i = (s << 4) + ty;
      int j = tx << 2;
      float4 av = *(const float4*)(A + (size_t)(row0 + i) * K + k0 + j);
      As[j][i] = av.x; As[j + 1][i] = av.y; As[j + 2][i] = av.z; As[j + 3][i] = av.w;
      float4 wv = *(const float4*)(W + (size_t)(col0 + i) * K + k0 + j);
      Ws[j][i] = wv.x; Ws[j + 1][i] = wv.y; Ws[j + 2][i] = wv.z; Ws[j + 3][i] = wv.w;
    }
    __syncthreads();
#pragma unroll
    for (int kk = 0; kk < 64; kk++) {
      const float4 af = *(const float4*)&As[kk][ty << 2];
      const float4 bf = *(const float4*)&Ws[kk][tx << 2];
      acc[0][0] += af.x * bf.x; acc[0][1] += af.x * bf.y; acc[0][2] += af.x * bf.z; acc[0][3] += af.x * bf.w;
      acc[1][0] += af.y * bf.x; acc[1][1] += af.y * bf.y; acc[1][2] += af.y * bf.z; acc[1][3] += af.y * bf.w;
      acc[2][0] += af.z * bf.x; acc[2][1] += af.z * bf.y; acc[2][2] += af.z * bf.z; acc[2][3] += af.z * bf.w;
      acc[3][0] += af.w * bf.x; acc[3][1] += af.w * bf.y; acc[3][2] += af.w * bf.z; acc[3][3] += af.w * bf.w;
    }
    __syncthreads();
  }
  const float4 bv = *(const float4*)(bias + col0 + (tx << 2));
#pragma unroll
  for (int i = 0; i < 4; i++) {
    float4 o;
    o.x = acc[i][0] + bv.x; o.y = acc[i][1] + bv.y;
    o.z = acc[i][2] + bv.z; o.w = acc[i][3] + bv.w;
    *(float4*)(Y + (size_t)(row0 + (ty << 2) + i) * N + col0 + (tx << 2)) = o;
  }
}

// ---------------- encW = [enc@Wm.T+bm ; enc@Wc.T+bc] via split-bf16 MFMA ---
__global__ __launch_bounds__(256) void enc_mfma(
    const float* __restrict__ A,
    const unsigned short* __restrict__ Whi, const unsigned short* __restrict__ Wlo,
    const float* __restrict__ bias512, float* __restrict__ Y)
{
  __shared__ unsigned short a_hi[64][264];
  __shared__ unsigned short a_lo[64][264];
  const int tid = threadIdx.x;
  const int row0 = blockIdx.x * 64;
#pragma unroll
  for (int u = 0; u < 16; ++u) {
    int f = tid + (u << 8);
    int r = f >> 6, c = (f & 63) << 2;
    float4 v = *(const float4*)(A + (size_t)(row0 + r) * E + c);
    ushort4 h, l;
    h.x = f2bf(v.x); l.x = f2bf(v.x - bf2f(h.x));
    h.y = f2bf(v.y); l.y = f2bf(v.y - bf2f(h.y));
    h.z = f2bf(v.z); l.z = f2bf(v.z - bf2f(h.z));
    h.w = f2bf(v.w); l.w = f2bf(v.w - bf2f(h.w));
    *(ushort4*)&a_hi[r][c] = h;
    *(ushort4*)&a_lo[r][c] = l;
  }
  __syncthreads();
  const int lane = tid & 63, w = tid >> 6;
  const int m = lane & 15, q = lane >> 4;
  const int colbase = w << 7;
#pragma unroll
  for (int cp = 0; cp < 4; ++cp) {
    const int c0 = colbase + (cp << 5);
    floatx4 acc[4][2] = {};
    for (int k0 = 0; k0 < E; k0 += 32) {
      const size_t w0 = (size_t)(c0 + m) * E + (q << 3) + k0;
      const size_t w1 = (size_t)(c0 + 16 + m) * E + (q << 3) + k0;
      short8 bh0 = *(const short8*)(Whi + w0);
      short8 bl0 = *(const short8*)(Wlo + w0);
      short8 bh1 = *(const short8*)(Whi + w1);
      short8 bl1 = *(const short8*)(Wlo + w1);
#pragma unroll
      for (int rg = 0; rg < 4; ++rg) {
        short8 ah = *(const short8*)&a_hi[(rg << 4) + m][(q << 3) + k0];
        short8 al = *(const short8*)&a_lo[(rg << 4) + m][(q << 3) + k0];
        acc[rg][0] = __builtin_amdgcn_mfma_f32_16x16x32_bf16(ah, bh0, acc[rg][0], 0, 0, 0);
        acc[rg][0] = __builtin_amdgcn_mfma_f32_16x16x32_bf16(al, bh0, acc[rg][0], 0, 0, 0);
        acc[rg][0] = __builtin_amdgcn_mfma_f32_16x16x32_bf16(ah, bl0, acc[rg][0], 0, 0, 0);
        acc[rg][0] = __builtin_amdgcn_mfma_f32_16x16x32_bf16(al, bl0, acc[rg][0], 0, 0, 0);
        acc[rg][1] = __builtin_amdgcn_mfma_f32_16x16x32_bf16(ah, bh1, acc[rg][1], 0, 0, 0);
        acc[rg][1] = __builtin_amdgcn_mfma_f32_16x16x32_bf16(al, bh1, acc[rg][1], 0, 0, 0);
        acc[rg][1] = __builtin_amdgcn_mfma_f32_16x16x32_bf16(ah, bl1, acc[rg][1], 0, 0, 0);
        acc[rg][1] = __builtin_amdgcn_mfma_f32_16x16x32_bf16(al, bl1, acc[rg][1], 0, 0, 0);
      }
    }
    const float bia0 = bias512[c0 + m], bia1 = bias512[c0 + 16 + m];
#pragma unroll
    for (int rg = 0; rg < 4; ++rg)
#pragma unroll
      for (int r = 0; r < 4; ++r) {
        const size_t row = row0 + (rg << 4) + (q << 2) + r;
        Y[row * (2 * E) + c0 + m]      = acc[rg][0][r] + bia0;
        Y[row * (2 * E) + c0 + 16 + m] = acc[rg][1][r] + bia1;
      }
  }
}

// ---------------- h-chain: h[s+1] = tanh(Xih + W_hh h[s]), W_hh in regs ----
__global__ __launch_bounds__(1024) void hchain_kernel(
    const float* __restrict__ Xih, const float* __restrict__ W_hhT,
    const float* __restrict__ h0,
    float* __restrict__ A_comb, float* __restrict__ h_all)
{
  __shared__ float h_s[E];
  __shared__ float red[1024];
  const int b = blockIdx.x, tid = threadIdx.x;
  const int c = tid >> 8, d = tid & 255, k0 = c * 64;
  float wreg[64];
#pragma unroll
  for (int j = 0; j < 64; ++j) wreg[j] = W_hhT[(size_t)(k0 + j) * E + d];
  if (tid < E) h_s[tid] = h0[(size_t)b * E + tid];
  __syncthreads();
  for (int s = 0; s < T_DEC; ++s) {
    float acc = 0.f;
#pragma unroll
    for (int j = 0; j < 64; j += 4) {
      float4 hh = *(const float4*)&h_s[k0 + j];
      acc += hh.x * wreg[j] + hh.y * wreg[j + 1] + hh.z * wreg[j + 2] + hh.w * wreg[j + 3];
    }
    red[tid] = acc;
    __syncthreads();
    if (tid < E) {
      float v = red[tid] + red[256 + tid] + red[512 + tid] + red[768 + tid]
              + Xih[((size_t)s * B + b) * E + tid];
      float hh = ftanh(v);
      h_s[tid] = hh;
      A_comb[((size_t)(b * T_DEC + s)) * (2 * E) + E + tid] = hh;
      h_all[((size_t)(b * T_DEC + s)) * E + tid] = hh;
    }
    __syncthreads();
  }
}

// ---------------- energies for ALL (b,s,t): fully parallel ----------------
// Grid (B, 16, 2), 512 threads (8 waves): block = 32 t's x 16 s's. Exactly
// 1024 blocks = 4/CU x 256 CU -> single full round, 32 waves/CU.
// hV half (pre-scaled by -2) staged in 32KB LDS. Wave w owns t-rows
// t0+w*4..+3; enc rows pre-scaled by -2 in registers. Per s: 8 partial dots
// reduced by a CORRECT two-register multi-value butterfly (keep+send per
// stage) -- bit-identical tree to wredsum. Lane l ends with S[l&7]; lane
// captures steps sl ≡ l>>3 (mod 8) and stores to g_pe[b][col][t].
__global__ __launch_bounds__(512) void energy_kernel(
    const float* __restrict__ encW, const float* __restrict__ g_hv,
    const float* __restrict__ w_effm, const float* __restrict__ w_effc,
    const float* __restrict__ vbm, const float* __restrict__ rmp,
    const float* __restrict__ vbc, const float* __restrict__ rcp_,
    float* __restrict__ g_pe)
{
  __shared__ float hv_s[16 * 512];   // 32 KB: rows s0..s0+15 of -2*[hVm|hVc]
  const int b = blockIdx.x, t0 = blockIdx.y << 5, s0 = blockIdx.z << 4;
  const int tid = threadIdx.x, lane = tid & 63, w = tid >> 6;
  const float* hvb = g_hv + ((size_t)(b * T_DEC + s0)) * 512;
  for (int i = tid * 4; i < 16 * 512; i += 2048) {
    float4 v = *(const float4*)(hvb + i);
    *(float4*)&hv_s[i] = scalem2(v);
  }
  __syncthreads();

  const float embias = vbm[0] + rmp[0];
  const float ecbias = vbc[0] + rcp_[0];
  const float bias_l = ((lane >> 2) & 1) ? ecbias : embias;
  const float4 wm4 = *(const float4*)(w_effm + lane * 4);
  const float4 wc4 = *(const float4*)(w_effc + lane * 4);
  const int t = t0 + (w << 2);
  const size_t rb = ((size_t)(b * T_ENC + t)) * 512 + lane * 4;
  const float4 em0 = scalem2(*(const float4*)(encW + rb));
  const float4 em1 = scalem2(*(const float4*)(encW + rb + 512));
  const float4 em2 = scalem2(*(const float4*)(encW + rb + 1024));
  const float4 em3 = scalem2(*(const float4*)(encW + rb + 1536));
  const float4 ec0 = scalem2(*(const float4*)(encW + rb + 256));
  const float4 ec1 = scalem2(*(const float4*)(encW + rb + 768));
  const float4 ec2 = scalem2(*(const float4*)(encW + rb + 1280));
  const float4 ec3 = scalem2(*(const float4*)(encW + rb + 1792));

  const bool sb0 = lane & 1, sb1 = lane & 2, sb2 = lane & 4;
  const int myr = lane >> 3;     // step residue this lane captures
  float pv0 = 0.f, pv1 = 0.f;

  for (int sl = 0; sl < 16; ++sl) {
    const float4 hm4 = *(const float4*)&hv_s[(sl << 9) + lane * 4];
    const float4 hc4 = *(const float4*)&hv_s[(sl << 9) + 256 + lane * 4];
    float v0 = dot4_wtanh(em0, hm4, wm4);
    float v1 = dot4_wtanh(em1, hm4, wm4);
    float v2 = dot4_wtanh(em2, hm4, wm4);
    float v3 = dot4_wtanh(em3, hm4, wm4);
    float v4 = dot4_wtanh(ec0, hc4, wc4);
    float v5 = dot4_wtanh(ec1, hc4, wc4);
    float v6 = dot4_wtanh(ec2, hc4, wc4);
    float v7 = dot4_wtanh(ec3, hc4, wc4);
    // CORRECT merged butterfly: keep + send registers per stage.
    // stage 1 (xor 1): pair (v0,v1),(v2,v3),(v4,v5),(v6,v7)
    float k0_ = sb0 ? v1 : v0, s0_ = sb0 ? v0 : v1; k0_ += __shfl_xor(s0_, 1, 64);
    float k1_ = sb0 ? v3 : v2, s1_ = sb0 ? v2 : v3; k1_ += __shfl_xor(s1_, 1, 64);
    float k2_ = sb0 ? v5 : v4, s2_ = sb0 ? v4 : v5; k2_ += __shfl_xor(s2_, 1, 64);
    float k3_ = sb0 ? v7 : v6, s3_ = sb0 ? v6 : v7; k3_ += __shfl_xor(s3_, 1, 64);
    // stage 2 (xor 2)
    float kA = sb1 ? k1_ : k0_, sA = sb1 ? k0_ : k1_; kA += __shfl_xor(sA, 2, 64);
    float kB = sb1 ? k3_ : k2_, sB = sb1 ? k2_ : k3_; kB += __shfl_xor(sB, 2, 64);
    // stage 3 (xor 4)
    float dd = sb2 ? kB : kA, sD = sb2 ? kA : kB; dd += __shfl_xor(sD, 4, 64);
    // stages 4-6: plain butterfly
    dd += __shfl_xor(dd, 8, 64);
    dd += __shfl_xor(dd, 16, 64);
    dd += __shfl_xor(dd, 32, 64);
    // lane l holds S[l&7], j=(type<<2)|row with type=(l>>2)&1, row=l&3
    float val = dd + bias_l;
    if ((sl & 7) == myr) {
      if (sl & 8) pv1 = val; else pv0 = val;
    }
  }
  // store to transposed layout g_pe[b][col][t], col = type*32 + s
  const int row_l = lane & 3, type = (lane >> 2) & 1;
  const int tS = t + row_l;
  const int col = type * 32 + s0 + myr;
  g_pe[((size_t)((b << 6) + col)) * 512 + tS]     = pv0;
  g_pe[((size_t)((b << 6) + col + 8)) * 512 + tS] = pv1;
}

// ---------------- alpha/beta recurrence: ONE WAVE per b, zero barriers -----
__global__ __launch_bounds__(64) void scan_kernel(
    const float* __restrict__ g_pe, const float* __restrict__ noise,
    float* __restrict__ beta_all)
{
  const int b = blockIdx.x, lane = threadIdx.x;
  const float* pe = g_pe + ((size_t)b << 15);   // b*64*512
  float alpha[8];
#pragma unroll
  for (int i = 0; i < 8; ++i) alpha[i] = 0.f;
  if (lane == 0) alpha[0] = 1.f;

  for (int s = 0; s < T_DEC; ++s) {
    const float* nrow = noise + ((size_t)s * B + b) * T_ENC + lane * 8;
    float4 n0 = *(const float4*)nrow;
    float4 n1 = *(const float4*)(nrow + 4);
    float nz[8] = {n0.x, n0.y, n0.z, n0.w, n1.x, n1.y, n1.z, n1.w};
    const float* psm = pe + (size_t)s * 512 + lane * 8;
    const float* pec = pe + (size_t)(32 + s) * 512 + lane * 8;
    float4 m0 = *(const float4*)psm;
    float4 m1 = *(const float4*)(psm + 4);
    float4 e0 = *(const float4*)pec;
    float4 e1 = *(const float4*)(pec + 4);
    float smv[8] = {m0.x, m0.y, m0.z, m0.w, m1.x, m1.y, m1.z, m1.w};
    float ec[8]  = {e0.x, e0.y, e0.z, e0.w, e1.x, e1.y, e1.z, e1.w};
    float p[8];
#pragma unroll
    for (int i = 0; i < 8; ++i) p[i] = fsigmoid(smv[i] + nz[i]);
    float lgv[8], lci[8], run = 0.f;
#pragma unroll
    for (int i = 0; i < 8; ++i) {
      float omp = fminf(fmaxf(1.f - p[i], 1e-10f), 1.f);
      lgv[i] = __logf(omp);
      run += lgv[i];
      lci[i] = run;
    }
    float ex1 = wexcl(run, lane);
    float cp[8], ao[8];
#pragma unroll
    for (int i = 0; i < 8; ++i) {
      float incl = lci[i] + ex1;
      cp[i] = __expf(incl - lgv[i]);               // exclusive cumprod
      float cpc = fminf(fmaxf(cp[i], 1e-10f), 1.f);
      ao[i] = alpha[i] * __builtin_amdgcn_rcpf(cpc);
    }
    float run2 = 0.f, lc2[8];
#pragma unroll
    for (int i = 0; i < 8; ++i) { run2 += ao[i]; lc2[i] = run2; }
    float ex2 = wexcl(run2, lane);
    float alpha_new[8];
#pragma unroll
    for (int i = 0; i < 8; ++i) alpha_new[i] = p[i] * cp[i] * (lc2[i] + ex2);
    float mloc = ec[0];
#pragma unroll
    for (int i = 1; i < 8; ++i) mloc = fmaxf(mloc, ec[i]);
    float mx = wredmax(mloc);
    float eu[8];
#pragma unroll
    for (int i = 0; i < 8; ++i) eu[i] = __expf(ec[i] - mx);
    float run3 = 0.f, c1[8];
#pragma unroll
    for (int i = 0; i < 8; ++i) { run3 += eu[i]; c1[i] = run3; }
    float ex3 = wexcl(run3, lane);
#pragma unroll
    for (int i = 0; i < 8; ++i) c1[i] += ex3;
    float r[8];
#pragma unroll
    for (int i = 0; i < 8; ++i) {
      float up = __shfl_up(c1[i], 1, 64);
      float prev = (lane == 0) ? 0.f : up;
      float denom = fmaxf(c1[i] - prev, 1e-10f);
      r[i] = alpha_new[i] * __builtin_amdgcn_rcpf(denom);
    }
    float run4 = 0.f, c2[8];
#pragma unroll
    for (int i = 0; i < 8; ++i) { run4 += r[i]; c2[i] = run4; }
    float ex4 = wexcl(run4, lane);
#pragma unroll
    for (int i = 0; i < 8; ++i) c2[i] += ex4;
    float c2_7 = c2[7];
    float dn[8];
#pragma unroll
    for (int i = 0; i < 8; ++i) dn[i] = __shfl_down(c2[i], 1, 64);
    float up7 = __shfl_up(c2_7, 1, 64);
    float beta[8];
#pragma unroll
    for (int i = 0; i < 8; ++i) {
      float hi = (i == 0) ? c2_7 : ((lane == 63) ? c2_7 : dn[i - 1]);
      float lo = (i == 0) ? ((lane == 0) ? 0.f : up7) : c2[i - 1];
      beta[i] = eu[i] * (hi - lo);
    }
    float* bp = beta_all + ((size_t)(b * T_DEC + s)) * T_ENC + lane * 8;
    *(float4*)bp       = (float4){beta[0], beta[1], beta[2], beta[3]};
    *(float4*)(bp + 4) = (float4){beta[4], beta[5], beta[6], beta[7]};
#pragma unroll
    for (int i = 0; i < 8; ++i) alpha[i] = alpha_new[i];
  }
}

// ---------------- context: ctx[b,s,:] = sum_t beta[b,s,t] * enc[b,t,:] -----
__global__ __launch_bounds__(256) void context_kernel(
    const float* __restrict__ beta_all, const float* __restrict__ enc,
    float* __restrict__ A_comb)
{
  __shared__ float smem[T_ENC * 36];                 // [t][36] padded, 73.7 KB
  const int b = blockIdx.x, e0 = blockIdx.y << 6;
  const int tid = threadIdx.x;
  const float* bp = beta_all + (size_t)b * T_DEC * T_ENC;
  for (int i = tid; i < T_DEC * T_ENC; i += 256) {
    int s2 = i >> 9, t = i & 511;
    smem[t * 36 + s2] = bp[i];
  }
  __syncthreads();
  const int el = tid & 63, tg = tid >> 6;
  float4 a8[8];
#pragma unroll
  for (int u = 0; u < 8; ++u) a8[u] = (float4){0.f, 0.f, 0.f, 0.f};
  const float* ep = enc + (size_t)b * T_ENC * E + e0 + el;
  for (int t = tg; t < T_ENC; t += 4) {
    float v = ep[(size_t)t * E];
    const float4* bt = (const float4*)&smem[t * 36];
#pragma unroll
    for (int u = 0; u < 8; ++u) {
      float4 bv = bt[u];
      a8[u].x += bv.x * v; a8[u].y += bv.y * v;
      a8[u].z += bv.z * v; a8[u].w += bv.w * v;
    }
  }
  __syncthreads();
#pragma unroll
  for (int u = 0; u < 8; ++u) {
    smem[((tg * T_DEC + u * 4 + 0) << 6) + el] = a8[u].x;
    smem[((tg * T_DEC + u * 4 + 1) << 6) + el] = a8[u].y;
    smem[((tg * T_DEC + u * 4 + 2) << 6) + el] = a8[u].z;
    smem[((tg * T_DEC + u * 4 + 3) << 6) + el] = a8[u].w;
  }
  __syncthreads();
  for (int o = tid; o < T_DEC * 64; o += 256) {
    int s2 = o >> 6, e = o & 63;
    float v = smem[(s2 << 6) + e] + smem[((T_DEC + s2) << 6) + e]
            + smem[((2 * T_DEC + s2) << 6) + e] + smem[((3 * T_DEC + s2) << 6) + e];
    A_comb[((size_t)(b * T_DEC + s2)) * (2 * E) + e0 + e] = v;
  }
}

// ---------------- attn = tanh(A_comb[1024,512] @ Wt[512,256]) -> bf16 ------
__global__ __launch_bounds__(256) void comb_tanh_kernel(
    const float* __restrict__ A, const float* __restrict__ Wt,
    unsigned short* __restrict__ attn_bf)
{
  __shared__ float As[64][68];
  __shared__ float Ws[64][68];
  const int tid = threadIdx.x, tx = tid & 15, ty = tid >> 4;
  const int row0 = blockIdx.y * 64, col0 = blockIdx.x * 64;
  float acc[4][4];
#pragma unroll
  for (int i = 0; i < 4; i++)
#pragma unroll
    for (int jj = 0; jj < 4; jj++) acc[i][jj] = 0.f;

  for (int k0 = 0; k0 < 2 * E; k0 += 64) {
#pragma unroll
    for (int ss = 0; ss < 4; ss++) {
      int i = (ss << 4) + ty;
      int jj = tx << 2;
      float4 av = *(const float4*)(A + (size_t)(row0 + i) * (2 * E) + k0 + jj);
      As[jj][i] = av.x; As[jj + 1][i] = av.y; As[jj + 2][i] = av.z; As[jj + 3][i] = av.w;
      float4 wv = *(const float4*)(Wt + (size_t)(k0 + i) * E + col0 + jj);
      *(float4*)&Ws[i][jj] = wv;
    }
    __syncthreads();
#pragma unroll
    for (int kk = 0; kk < 64; kk++) {
      const float4 af = *(const float4*)&As[kk][ty << 2];
      const float4 bf = *(const float4*)&Ws[kk][tx << 2];
      acc[0][0] += af.x * bf.x; acc[0][1] += af.x * bf.y; acc[0][2] += af.x * bf.z; acc[0][3] += af.x * bf.w;
      acc[1][0] += af.y * bf.x; acc[1][1] += af.y * bf.y; acc[1][2] += af.y * bf.z; acc[1][3] += af.y * bf.w;
      acc[2][0] += af.z * bf.x; acc[2][1] += af.z * bf.y; acc[2][2] += af.z * bf.z; acc[2][3] += af.z * bf.w;
      acc[3][0] += af.w * bf.x; acc[3][1] += af.w * bf.y; acc[3][2] += af.w * bf.z; acc[3][3] += af.w * bf.w;
    }
    __syncthreads();
  }
#pragma unroll
  for (int i = 0; i < 4; i++) {
    ushort4 o;
    o.x = f2bf(ftanh(acc[i][0])); o.y = f2bf(ftanh(acc[i][1]));
    o.z = f2bf(ftanh(acc[i][2])); o.w = f2bf(ftanh(acc[i][3]));
    *(ushort4*)(attn_bf + (size_t)(row0 + (ty << 2) + i) * E + col0 + (tx << 2)) = o;
  }
}

// ---------------- projection: one block per 64-col W panel, loop M ---------
__global__ __launch_bounds__(256) void proj_mfma(
    const unsigned short* __restrict__ A, const unsigned short* __restrict__ Bw,
    const float* __restrict__ bias, float* __restrict__ Y)
{
  __shared__ unsigned short wl[64][264];   // 33.8 KB
  __shared__ float tile[64][68];           // 17.4 KB
  const int tid = threadIdx.x;
  const int wave = tid >> 6, lane = tid & 63;
  const int m = lane & 15, q = lane >> 4;
  const int col0 = blockIdx.x * 64;
#pragma unroll
  for (int u = 0; u < 16; ++u) {
    int f = tid + (u << 8);
    int r = f >> 6, c = (f & 63) << 2;
    *(ushort4*)&wl[r][c] = *(const ushort4*)(Bw + (size_t)(col0 + r) * E + c);
  }
  __syncthreads();

  for (int mt = 0; mt < 16; ++mt) {
    const int rowa = mt * 64 + wave * 16;
    floatx4 acc0 = {0.f, 0.f, 0.f, 0.f}, acc1 = acc0, acc2 = acc0, acc3 = acc0;
    const unsigned short* ar = A + (size_t)(rowa + m) * E + q * 8;
#pragma unroll
    for (int k0 = 0; k0 < E; k0 += 32) {
      short8 af = *(const short8*)(ar + k0);
      short8 b0 = *(const short8*)&wl[ 0 + m][q * 8 + k0];
      short8 b1 = *(const short8*)&wl[16 + m][q * 8 + k0];
      short8 b2 = *(const short8*)&wl[32 + m][q * 8 + k0];
      short8 b3 = *(const short8*)&wl[48 + m][q * 8 + k0];
      acc0 = __builtin_amdgcn_mfma_f32_16x16x32_bf16(af, b0, acc0, 0, 0, 0);
      acc1 = __builtin_amdgcn_mfma_f32_16x16x32_bf16(af, b1, acc1, 0, 0, 0);
      acc2 = __builtin_amdgcn_mfma_f32_16x16x32_bf16(af, b2, acc2, 0, 0, 0);
      acc3 = __builtin_amdgcn_mfma_f32_16x16x32_bf16(af, b3, acc3, 0, 0, 0);
    }
    const int rl = wave * 16 + q * 4;
#pragma unroll
    for (int r = 0; r < 4; r++) {
      tile[rl + r][ 0 + m] = acc0[r];
      tile[rl + r][16 + m] = acc1[r];
      tile[rl + r][32 + m] = acc2[r];
      tile[rl + r][48 + m] = acc3[r];
    }
    __syncthreads();
    const int row = tid >> 2, seg = tid & 3;
    const size_t yb = ((size_t)mt * 64 + row) * VOCAB + col0;
#pragma unroll
    for (int u = 0; u < 4; u++) {
      int cc = seg * 16 + u * 4;
      float4 v = *(const float4*)&tile[row][cc];
      float4 bb = *(const float4*)(bias + col0 + cc);
      v.x += bb.x; v.y += bb.y; v.z += bb.z; v.w += bb.w;
      *(float4*)(Y + yb + cc) = v;
    }
    __syncthreads();
  }
}

// ---------------- launch ----------------
extern "C" void kernel_launch(void* const* d_in, const int* in_sizes, int n_in,
                              void* d_out, int out_size, void* d_ws, size_t ws_size,
                              hipStream_t stream)
{
  (void)in_sizes; (void)n_in; (void)out_size; (void)ws_size;
  const float* enc    = (const float*)d_in[0];
  const int*   dec    = (const int*)d_in[1];
  const float* h0     = (const float*)d_in[2];
  const float* noise  = (const float*)d_in[3];
  const float* emb    = (const float*)d_in[4];
  const float* W_ih   = (const float*)d_in[5];
  const float* b_ih   = (const float*)d_in[6];
  const float* W_hh   = (const float*)d_in[7];
  const float* b_hh   = (const float*)d_in[8];
  const float* Wm     = (const float*)d_in[9];
  const float* Vm     = (const float*)d_in[10];
  const float* bm     = (const float*)d_in[11];
  const float* vvm    = (const float*)d_in[12];
  const float* gm     = (const float*)d_in[13];
  const float* vbm    = (const float*)d_in[14];
  const float* rmp    = (const float*)d_in[15];
  const float* Wc     = (const float*)d_in[16];
  const float* Vc     = (const float*)d_in[17];
  const float* bc     = (const float*)d_in[18];
  const float* vvc    = (const float*)d_in[19];
  const float* gc     = (const float*)d_in[20];
  const float* vbc    = (const float*)d_in[21];
  const float* rcp_   = (const float*)d_in[22];
  const float* W_comb = (const float*)d_in[23];
  const float* W_proj = (const float*)d_in[24];
  const float* b_proj = (const float*)d_in[25];

  float* ws = (float*)d_ws;
  float* encW    = ws + OFF_ENCW;
  float* w_effm  = ws + OFF_WEFFM;
  float* w_effc  = ws + OFF_WEFFC;
  float* bsum    = ws + OFF_BSUM;
  float* Xih     = ws + OFF_XIH;
  float* W_hhT   = ws + OFF_WHHT;
  float* W_combT = ws + OFF_WCOMBT;
  unsigned short* attn_bf = (unsigned short*)(ws + OFF_ATTNB);
  unsigned short* Wp_bf   = (unsigned short*)(ws + OFF_WPBF);

  float* outF = (float*)d_out;
  float* embX     = outF + OUT_EMBX;     // scratch in d_out, all consumed
  float* beta_all = outF + OUT_BETA;     //   before proj_mfma overwrites it
  float* A_comb   = outF + OUT_ACOMB;
  float* h_all    = outF + OUT_HALL;
  float* g_hv     = outF + OUT_HV;
  float* g_pe     = outF + OUT_PE;
  float* Vmc      = outF + OUT_VMC;
  float* zero512  = outF + OUT_ZERO;
  unsigned short* Whi = (unsigned short*)(outF + OUT_WHI);
  unsigned short* Wlo = (unsigned short*)(outF + OUT_WLO);
  float* bias512  = outF + OUT_B512;

  // ---- step-invariant prep ----
  prep_misc<<<259, 256, 0, stream>>>(vvm, gm, w_effm, vvc, gc, w_effc,
                                     b_ih, b_hh, bsum, bm, bc, bias512,
                                     Vm, Vc, Vmc, zero512, Wm, Wc, Whi, Wlo);
  transpose2<<<192, 256, 0, stream>>>(W_hh, W_hhT, W_comb, W_combT);
  gather_emb<<<T_DEC * B, 256, 0, stream>>>(dec, emb, embX);
  gemm_xwt<<<dim3(E / 64, (T_DEC * B) / 64), 256, 0, stream>>>(embX, W_ih, bsum, Xih,
                                                               T_DEC * B, E, E);
  enc_mfma<<<(B * T_ENC) / 64, 256, 0, stream>>>(enc, Whi, Wlo, bias512, encW);
  cvt_bf16<<<(VOCAB * E) / 1024, 256, 0, stream>>>(W_proj, Wp_bf);

  // ---- sequential part 1: the h-chain ----
  hchain_kernel<<<B, 1024, 0, stream>>>(Xih, W_hhT, h0, A_comb, h_all);

  // ---- hV = [Vm;Vc] h for all (b,s) ----
  gemm_xwt<<<dim3((2 * E) / 64, (T_DEC * B) / 64), 256, 0, stream>>>(
      h_all, Vmc, zero512, g_hv, T_DEC * B, 2 * E, E);

  // ---- energies: 1024 blocks x 512 thr = exactly one full-occupancy round
  energy_kernel<<<dim3(B, 16, 2), 512, 0, stream>>>(
      encW, g_hv, w_effm, w_effc, vbm, rmp, vbc, rcp_, g_pe);

  // ---- sequential part 2: alpha/beta scans, one wave per b ----
  scan_kernel<<<B, 64, 0, stream>>>(g_pe, noise, beta_all);

  // ---- hoisted epilogue ----
  context_kernel<<<dim3(B, 4), 256, 0, stream>>>(beta_all, enc, A_comb);
  comb_tanh_kernel<<<dim3(E / 64, (T_DEC * B) / 64), 256, 0, stream>>>(A_comb, W_combT, attn_bf);
  proj_mfma<<<VOCAB / 64, 256, 0, stream>>>(attn_bf, Wp_bf, b_proj, outF);
}

// Round 6
// 580.023 us; speedup vs baseline: 4.1038x; 1.0001x over previous
//
#include <hip/hip_runtime.h>
#include <cstddef>

#define B 32
#define T_ENC 512
#define T_DEC 32
#define E 256
#define VOCAB 32000
#define SOS 1
#define NEG2LOG2E -2.885390081777927f   // -2 * log2(e)

typedef __attribute__((ext_vector_type(8))) short short8;   // 8 x bf16
typedef __attribute__((ext_vector_type(4))) float floatx4;  // MFMA acc

// ---------------- workspace layout (float offsets) ----------------
static const size_t OFF_ENCW   = 0;                                    // 8388608: fused [16384][512]
static const size_t OFF_WEFFM  = OFF_ENCW + (size_t)B * T_ENC * 2 * E; // 256
static const size_t OFF_WEFFC  = OFF_WEFFM + E;                        // 256
static const size_t OFF_BSUM   = OFF_WEFFC + E;                        // 256
static const size_t OFF_XIH    = OFF_BSUM + E;                         // 262144
static const size_t OFF_WHHT   = OFF_XIH + (size_t)T_DEC * B * E;      // 65536
static const size_t OFF_VMT    = OFF_WHHT + (size_t)E * E;             // 65536 (unused)
static const size_t OFF_VCT    = OFF_VMT + (size_t)E * E;              // 65536 (unused)
static const size_t OFF_WCOMBT = OFF_VCT + (size_t)E * E;              // 131072
static const size_t OFF_ATTNB  = OFF_WCOMBT + (size_t)2 * E * E;       // 131072 floats (ushort x2)
static const size_t OFF_WPBF   = OFF_ATTNB + (size_t)T_DEC * B * E / 2;// 4096000 floats (ushort x2)

// ---------------- d_out scratch layout (float offsets) ----------------
static const size_t OUT_EMBX  = 0;         // 262144 (consumed by Xih gemm)
static const size_t OUT_BETA  = 262144;    // 524288: beta[b][s][t]
static const size_t OUT_ACOMB = 786432;    // 524288: [ctx | h] rows (b*32+s) x 512
static const size_t OUT_HALL  = 1310720;   // 262144: h[b][s][256]
static const size_t OUT_HV    = 1572864;   // 524288: [hVm | hVc] rows (b*32+s) x 512
static const size_t OUT_PE    = 2097152;   // 1048576: g_pe[b][col][t], col = type*32+s
static const size_t OUT_VMC   = 3145728;   // 131072: [Vm ; Vc]
static const size_t OUT_ZERO  = 3276800;   // 512 zeros
static const size_t OUT_WHI   = 3277312;   // 65536 floats = 131072 ushort: W split hi [512][256]
static const size_t OUT_WLO   = 3342848;   // 65536 floats: W split lo
static const size_t OUT_B512  = 3408384;   // 512: [bm ; bc]

// ---------------- helpers ----------------
__device__ __forceinline__ float ftanh(float x) {
  float ax = __builtin_fabsf(x);
  float e  = __expf(-2.f * ax);
  float r  = (1.f - e) * __builtin_amdgcn_rcpf(1.f + e);
  return __builtin_copysignf(r, x);
}

__device__ __forceinline__ float fsigmoid(float z) {
  return __builtin_amdgcn_rcpf(1.f + __expf(-z));
}

__device__ __forceinline__ float wredmax(float s) {
  s = fmaxf(s, __shfl_xor(s, 1, 64));  s = fmaxf(s, __shfl_xor(s, 2, 64));
  s = fmaxf(s, __shfl_xor(s, 4, 64));  s = fmaxf(s, __shfl_xor(s, 8, 64));
  s = fmaxf(s, __shfl_xor(s, 16, 64)); s = fmaxf(s, __shfl_xor(s, 32, 64));
  return s;
}

__device__ __forceinline__ unsigned short f2bf(float f) {
  unsigned int u = __float_as_uint(f);
  u = (u + 0x7fffu + ((u >> 16) & 1u)) >> 16;   // RNE
  return (unsigned short)u;
}

__device__ __forceinline__ float bf2f(unsigned short h) {
  return __uint_as_float((unsigned int)h << 16);
}

// exclusive prefix (across 64 lanes) of per-lane totals
__device__ __forceinline__ float wexcl(float tot, int lane) {
  float v = tot;
#pragma unroll
  for (int off = 1; off < 64; off <<= 1) {
    float y = __shfl_up(v, off, 64);
    if (lane >= off) v += y;
  }
  return v - tot;
}

// sum_i w_i * tanh(x_i); inputs PRE-SCALED by -2*log2(e) so the hw exp2
// (v_exp_f32) is used directly -- one fewer mul per element than __expf.
// tanh(x) = (1 - 2^{-2x log2e})/(1 + 2^{-2x log2e}). |arg| < ~35, safe.
__device__ __forceinline__ float dot4_wtanh(float4 s2a, float4 s2b, float4 w4) {
  float e, num, acc;
  e = __builtin_exp2f(s2a.x + s2b.x); num = __builtin_fmaf(-e, w4.x, w4.x);
  acc = num * __builtin_amdgcn_rcpf(1.f + e);
  e = __builtin_exp2f(s2a.y + s2b.y); num = __builtin_fmaf(-e, w4.y, w4.y);
  acc = __builtin_fmaf(num, __builtin_amdgcn_rcpf(1.f + e), acc);
  e = __builtin_exp2f(s2a.z + s2b.z); num = __builtin_fmaf(-e, w4.z, w4.z);
  acc = __builtin_fmaf(num, __builtin_amdgcn_rcpf(1.f + e), acc);
  e = __builtin_exp2f(s2a.w + s2b.w); num = __builtin_fmaf(-e, w4.w, w4.w);
  acc = __builtin_fmaf(num, __builtin_amdgcn_rcpf(1.f + e), acc);
  return acc;
}

__device__ __forceinline__ float4 scalem2(float4 v) {
  float4 r;
  r.x = NEG2LOG2E * v.x; r.y = NEG2LOG2E * v.y;
  r.z = NEG2LOG2E * v.z; r.w = NEG2LOG2E * v.w;
  return r;
}

// ---- fused prep: weff/biases/Vmc/Wsplit + transposes + gather + cvt -------
// All branches write disjoint outputs; single launch so they co-schedule.
__global__ __launch_bounds__(256) void prep_all(
    const float* __restrict__ vvm, const float* __restrict__ gm, float* __restrict__ w_effm,
    const float* __restrict__ vvc, const float* __restrict__ gc, float* __restrict__ w_effc,
    const float* __restrict__ b_ih, const float* __restrict__ b_hh, float* __restrict__ bsum,
    const float* __restrict__ bm, const float* __restrict__ bc, float* __restrict__ bias512,
    const float* __restrict__ Vm, const float* __restrict__ Vc,
    float* __restrict__ Vmc, float* __restrict__ zero512,
    const float* __restrict__ Wm, const float* __restrict__ Wc,
    unsigned short* __restrict__ Whi, unsigned short* __restrict__ Wlo,
    const float* __restrict__ W_hh, float* __restrict__ W_hhT,
    const float* __restrict__ W_comb, float* __restrict__ W_combT,
    const int* __restrict__ dec, const float* __restrict__ emb, float* __restrict__ embX,
    const float* __restrict__ W_proj, unsigned short* __restrict__ Wp_bf)
{
  __shared__ float red[256];
  __shared__ float tl[32][33];
  const int blk = blockIdx.x, tid = threadIdx.x;
  if (blk < 2) {
    const float* vv = blk ? vvc : vvm;
    const float* g  = blk ? gc  : gm;
    float* out      = blk ? w_effc : w_effm;
    float v = vv[tid];
    red[tid] = v * v;
    __syncthreads();
    for (int off = 128; off > 0; off >>= 1) {
      if (tid < off) red[tid] += red[tid + off];
      __syncthreads();
    }
    float norm = sqrtf(red[0]);
    out[tid] = (g[0] / norm) * v;
  } else if (blk == 2) {
    bsum[tid] = b_ih[tid] + b_hh[tid];
    bias512[tid]       = bm[tid];
    bias512[256 + tid] = bc[tid];
    zero512[tid] = 0.f;
    zero512[256 + tid] = 0.f;
  } else if (blk < 131) {
    int i = (blk - 3) * 1024 + tid * 4;
    float4 v = (i < E * E) ? *(const float4*)(Vm + i) : *(const float4*)(Vc + i - E * E);
    *(float4*)(Vmc + i) = v;
  } else if (blk < 259) {
    int i = (blk - 131) * 1024 + tid * 4;
    float4 v = (i < E * E) ? *(const float4*)(Wm + i) : *(const float4*)(Wc + i - E * E);
    ushort4 h, l;
    h.x = f2bf(v.x); l.x = f2bf(v.x - bf2f(h.x));
    h.y = f2bf(v.y); l.y = f2bf(v.y - bf2f(h.y));
    h.z = f2bf(v.z); l.z = f2bf(v.z - bf2f(h.z));
    h.w = f2bf(v.w); l.w = f2bf(v.w - bf2f(h.w));
    *(ushort4*)(Whi + i) = h;
    *(ushort4*)(Wlo + i) = l;
  } else if (blk < 451) {
    // transposes: W_hh (64 blocks), W_comb (128 blocks)
    int k2 = blk - 259;
    const float* in; float* out; int C, bx, by;
    if (k2 < 64) { in = W_hh;   out = W_hhT;   C = 256; bx = k2 & 7;  by = k2 >> 3; }
    else { int k = k2 - 64; in = W_comb; out = W_combT; C = 512; bx = k & 15; by = k >> 4; }
    const int R = 256;
    const int tx = tid & 31, ty = tid >> 5;
    const int c0 = bx * 32, r0 = by * 32;
#pragma unroll
    for (int k = 0; k < 4; k++)
      tl[ty + 8 * k][tx] = in[(size_t)(r0 + ty + 8 * k) * C + c0 + tx];
    __syncthreads();
#pragma unroll
    for (int k = 0; k < 4; k++)
      out[(size_t)(c0 + ty + 8 * k) * R + r0 + tx] = tl[tx][ty + 8 * k];
  } else if (blk < 1475) {
    // gather embeddings
    int r = blk - 451;
    int s = r >> 5, b = r & 31;
    int tok = (s == 0) ? SOS : dec[b * T_DEC + s - 1];
    embX[(size_t)r * E + tid] = emb[(size_t)tok * E + tid];
  } else {
    // W_proj -> bf16
    size_t i = ((size_t)(blk - 1475) * 256 + tid) * 4;
    float4 v = *(const float4*)(W_proj + i);
    ushort4 o;
    o.x = f2bf(v.x); o.y = f2bf(v.y); o.z = f2bf(v.z); o.w = f2bf(v.w);
    *(ushort4*)(Wp_bf + i) = o;
  }
}

// ---------------- Y[r,n] = bias[n] + sum_k A[r,k]*W[n,k] (f32, small) ------
__global__ __launch_bounds__(256) void gemm_xwt(
    const float* __restrict__ A, const float* __restrict__ W,
    const float* __restrict__ bias, float* __restrict__ Y,
    int M, int N, int K)
{
  __shared__ float As[64][68];
  __shared__ float Ws[64][68];
  const int tid = threadIdx.x;
  const int tx = tid & 15, ty = tid >> 4;
  const int row0 = blockIdx.y * 64, col0 = blockIdx.x * 64;
  float acc[4][4];
#pragma unroll
  for (int i = 0; i < 4; i++)
#pragma unroll
    for (int j = 0; j < 4; j++) acc[i][j] = 0.f;

  for (int k0 = 0; k0 < K; k0 += 64) {
#pragma unroll
    for (int s = 0; s < 4; s++) {
      int i = (s << 4) + ty;
      int j = tx << 2;
      float4 av = *(const float4*)(A + (size_t)(row0 + i) * K + k0 + j);
      As[j][i] = av.x; As[j + 1][i] = av.y; As[j + 2][i] = av.z; As[j + 3][i] = av.w;
      float4 wv = *(const float4*)(W + (size_t)(col0 + i) * K + k0 + j);
      Ws[j][i] = wv.x; Ws[j + 1][i] = wv.y; Ws[j + 2][i] = wv.z; Ws[j + 3][i] = wv.w;
    }
    __syncthreads();
#pragma unroll
    for (int kk = 0; kk < 64; kk++) {
      const float4 af = *(const float4*)&As[kk][ty << 2];
      const float4 bf = *(const float4*)&Ws[kk][tx << 2];
      acc[0][0] += af.x * bf.x; acc[0][1] += af.x * bf.y; acc[0][2] += af.x * bf.z; acc[0][3] += af.x * bf.w;
      acc[1][0] += af.y * bf.x; acc[1][1] += af.y * bf.y; acc[1][2] += af.y * bf.z; acc[1][3] += af.y * bf.w;
      acc[2][0] += af.z * bf.x; acc[2][1] += af.z * bf.y; acc[2][2] += af.z * bf.z; acc[2][3] += af.z * bf.w;
      acc[3][0] += af.w * bf.x; acc[3][1] += af.w * bf.y; acc[3][2] += af.w * bf.z; acc[3][3] += af.w * bf.w;
    }
    __syncthreads();
  }
  const float4 bv = *(const float4*)(bias + col0 + (tx << 2));
#pragma unroll
  for (int i = 0; i < 4; i++) {
    float4 o;
    o.x = acc[i][0] + bv.x; o.y = acc[i][1] + bv.y;
    o.z = acc[i][2] + bv.z; o.w = acc[i][3] + bv.w;
    *(float4*)(Y + (size_t)(row0 + (ty << 2) + i) * N + col0 + (tx << 2)) = o;
  }
}

// ---- FUSED: h-chain (blocks 0..31) + encW split-bf16 MFMA (blocks 32..287)
// The 32-block latency-bound h-chain leaves 224 CUs idle; enc_mfma's work
// runs concurrently in the same launch.
__global__ __launch_bounds__(1024, 1) void hchain_enc(
    const float* __restrict__ Xih, const float* __restrict__ W_hhT,
    const float* __restrict__ h0,
    float* __restrict__ A_comb, float* __restrict__ h_all,
    const float* __restrict__ encA,
    const unsigned short* __restrict__ Whi, const unsigned short* __restrict__ Wlo,
    const float* __restrict__ bias512, float* __restrict__ encW)
{
  __shared__ __align__(16) unsigned char smem_raw[67584];   // max(enc 66KB, hchain 5KB)
  const int tid = threadIdx.x;

  if (blockIdx.x < B) {
    // ---------------- h-chain ----------------
    float* h_s = (float*)smem_raw;        // 256
    float* red = h_s + 256;               // 1024
    const int b = blockIdx.x;
    const int c = tid >> 8, d = tid & 255, k0 = c * 64;
    float wreg[64];
#pragma unroll
    for (int j = 0; j < 64; ++j) wreg[j] = W_hhT[(size_t)(k0 + j) * E + d];
    if (tid < E) h_s[tid] = h0[(size_t)b * E + tid];
    __syncthreads();
    for (int s = 0; s < T_DEC; ++s) {
      float acc = 0.f;
#pragma unroll
      for (int j = 0; j < 64; j += 4) {
        float4 hh = *(const float4*)&h_s[k0 + j];
        acc += hh.x * wreg[j] + hh.y * wreg[j + 1] + hh.z * wreg[j + 2] + hh.w * wreg[j + 3];
      }
      red[tid] = acc;
      __syncthreads();
      if (tid < E) {
        float v = red[tid] + red[256 + tid] + red[512 + tid] + red[768 + tid]
                + Xih[((size_t)s * B + b) * E + tid];
        float hh = ftanh(v);
        h_s[tid] = hh;
        A_comb[((size_t)(b * T_DEC + s)) * (2 * E) + E + tid] = hh;
        h_all[((size_t)(b * T_DEC + s)) * E + tid] = hh;
      }
      __syncthreads();
    }
  } else {
    // ---------------- encW: 64 rows, 16 waves x 32 cols ----------------
    unsigned short* a_hi = (unsigned short*)smem_raw;       // [64][264]
    unsigned short* a_lo = a_hi + 64 * 264;
    const int row0 = (int)(blockIdx.x - B) * 64;
#pragma unroll
    for (int u = 0; u < 4; ++u) {
      int f = tid + (u << 10);
      int r = f >> 6, cc = (f & 63) << 2;
      float4 v = *(const float4*)(encA + (size_t)(row0 + r) * E + cc);
      ushort4 h, l;
      h.x = f2bf(v.x); l.x = f2bf(v.x - bf2f(h.x));
      h.y = f2bf(v.y); l.y = f2bf(v.y - bf2f(h.y));
      h.z = f2bf(v.z); l.z = f2bf(v.z - bf2f(h.z));
      h.w = f2bf(v.w); l.w = f2bf(v.w - bf2f(h.w));
      *(ushort4*)&a_hi[r * 264 + cc] = h;
      *(ushort4*)&a_lo[r * 264 + cc] = l;
    }
    __syncthreads();
    const int lane = tid & 63, w = tid >> 6;
    const int m = lane & 15, q = lane >> 4;
    const int c0 = w << 5;               // 32 cols per wave
    floatx4 acc[4][2] = {};
    for (int k0 = 0; k0 < E; k0 += 32) {
      const size_t w0 = (size_t)(c0 + m) * E + (q << 3) + k0;
      const size_t w1 = (size_t)(c0 + 16 + m) * E + (q << 3) + k0;
      short8 bh0 = *(const short8*)(Whi + w0);
      short8 bl0 = *(const short8*)(Wlo + w0);
      short8 bh1 = *(const short8*)(Whi + w1);
      short8 bl1 = *(const short8*)(Wlo + w1);
#pragma unroll
      for (int rg = 0; rg < 4; ++rg) {
        short8 ah = *(const short8*)&a_hi[((rg << 4) + m) * 264 + (q << 3) + k0];
        short8 al = *(const short8*)&a_lo[((rg << 4) + m) * 264 + (q << 3) + k0];
        acc[rg][0] = __builtin_amdgcn_mfma_f32_16x16x32_bf16(ah, bh0, acc[rg][0], 0, 0, 0);
        acc[rg][0] = __builtin_amdgcn_mfma_f32_16x16x32_bf16(al, bh0, acc[rg][0], 0, 0, 0);
        acc[rg][0] = __builtin_amdgcn_mfma_f32_16x16x32_bf16(ah, bl0, acc[rg][0], 0, 0, 0);
        acc[rg][0] = __builtin_amdgcn_mfma_f32_16x16x32_bf16(al, bl0, acc[rg][0], 0, 0, 0);
        acc[rg][1] = __builtin_amdgcn_mfma_f32_16x16x32_bf16(ah, bh1, acc[rg][1], 0, 0, 0);
        acc[rg][1] = __builtin_amdgcn_mfma_f32_16x16x32_bf16(al, bh1, acc[rg][1], 0, 0, 0);
        acc[rg][1] = __builtin_amdgcn_mfma_f32_16x16x32_bf16(ah, bl1, acc[rg][1], 0, 0, 0);
        acc[rg][1] = __builtin_amdgcn_mfma_f32_16x16x32_bf16(al, bl1, acc[rg][1], 0, 0, 0);
      }
    }
    const float bia0 = bias512[c0 + m], bia1 = bias512[c0 + 16 + m];
#pragma unroll
    for (int rg = 0; rg < 4; ++rg)
#pragma unroll
      for (int r = 0; r < 4; ++r) {
        const size_t row = row0 + (rg << 4) + (q << 2) + r;
        encW[row * (2 * E) + c0 + m]      = acc[rg][0][r] + bia0;
        encW[row * (2 * E) + c0 + 16 + m] = acc[rg][1][r] + bia1;
      }
  }
}

// ---------------- energies for ALL (b,s,t): fully parallel ----------------
// Grid (B, 16, 2), 512 threads: block = 32 t's x 16 s's; 1024 blocks = one
// full-occupancy round. Inputs pre-scaled by -2*log2e -> exp2 path.
__global__ __launch_bounds__(512) void energy_kernel(
    const float* __restrict__ encW, const float* __restrict__ g_hv,
    const float* __restrict__ w_effm, const float* __restrict__ w_effc,
    const float* __restrict__ vbm, const float* __restrict__ rmp,
    const float* __restrict__ vbc, const float* __restrict__ rcp_,
    float* __restrict__ g_pe)
{
  __shared__ float hv_s[16 * 512];   // 32 KB
  const int b = blockIdx.x, t0 = blockIdx.y << 5, s0 = blockIdx.z << 4;
  const int tid = threadIdx.x, lane = tid & 63, w = tid >> 6;
  const float* hvb = g_hv + ((size_t)(b * T_DEC + s0)) * 512;
  for (int i = tid * 4; i < 16 * 512; i += 2048) {
    float4 v = *(const float4*)(hvb + i);
    *(float4*)&hv_s[i] = scalem2(v);
  }
  __syncthreads();

  const float embias = vbm[0] + rmp[0];
  const float ecbias = vbc[0] + rcp_[0];
  const float bias_l = ((lane >> 2) & 1) ? ecbias : embias;
  const float4 wm4 = *(const float4*)(w_effm + lane * 4);
  const float4 wc4 = *(const float4*)(w_effc + lane * 4);
  const int t = t0 + (w << 2);
  const size_t rb = ((size_t)(b * T_ENC + t)) * 512 + lane * 4;
  const float4 em0 = scalem2(*(const float4*)(encW + rb));
  const float4 em1 = scalem2(*(const float4*)(encW + rb + 512));
  const float4 em2 = scalem2(*(const float4*)(encW + rb + 1024));
  const float4 em3 = scalem2(*(const float4*)(encW + rb + 1536));
  const float4 ec0 = scalem2(*(const float4*)(encW + rb + 256));
  const float4 ec1 = scalem2(*(const float4*)(encW + rb + 768));
  const float4 ec2 = scalem2(*(const float4*)(encW + rb + 1280));
  const float4 ec3 = scalem2(*(const float4*)(encW + rb + 1792));

  const bool sb0 = lane & 1, sb1 = lane & 2, sb2 = lane & 4;
  const int myr = lane >> 3;     // step residue this lane captures
  float pv0 = 0.f, pv1 = 0.f;

  for (int sl = 0; sl < 16; ++sl) {
    const float4 hm4 = *(const float4*)&hv_s[(sl << 9) + lane * 4];
    const float4 hc4 = *(const float4*)&hv_s[(sl << 9) + 256 + lane * 4];
    float v0 = dot4_wtanh(em0, hm4, wm4);
    float v1 = dot4_wtanh(em1, hm4, wm4);
    float v2 = dot4_wtanh(em2, hm4, wm4);
    float v3 = dot4_wtanh(em3, hm4, wm4);
    float v4 = dot4_wtanh(ec0, hc4, wc4);
    float v5 = dot4_wtanh(ec1, hc4, wc4);
    float v6 = dot4_wtanh(ec2, hc4, wc4);
    float v7 = dot4_wtanh(ec3, hc4, wc4);
    // two-register multi-value butterfly (bit-identical tree to wredsum)
    float k0_ = sb0 ? v1 : v0, s0_ = sb0 ? v0 : v1; k0_ += __shfl_xor(s0_, 1, 64);
    float k1_ = sb0 ? v3 : v2, s1_ = sb0 ? v2 : v3; k1_ += __shfl_xor(s1_, 1, 64);
    float k2_ = sb0 ? v5 : v4, s2_ = sb0 ? v4 : v5; k2_ += __shfl_xor(s2_, 1, 64);
    float k3_ = sb0 ? v7 : v6, s3_ = sb0 ? v6 : v7; k3_ += __shfl_xor(s3_, 1, 64);
    float kA = sb1 ? k1_ : k0_, sA = sb1 ? k0_ : k1_; kA += __shfl_xor(sA, 2, 64);
    float kB = sb1 ? k3_ : k2_, sB = sb1 ? k2_ : k3_; kB += __shfl_xor(sB, 2, 64);
    float dd = sb2 ? kB : kA, sD = sb2 ? kA : kB; dd += __shfl_xor(sD, 4, 64);
    dd += __shfl_xor(dd, 8, 64);
    dd += __shfl_xor(dd, 16, 64);
    dd += __shfl_xor(dd, 32, 64);
    float val = dd + bias_l;
    if ((sl & 7) == myr) {
      if (sl & 8) pv1 = val; else pv0 = val;
    }
  }
  const int row_l = lane & 3, type = (lane >> 2) & 1;
  const int tS = t + row_l;
  const int col = type * 32 + s0 + myr;
  g_pe[((size_t)((b << 6) + col)) * 512 + tS]     = pv0;
  g_pe[((size_t)((b << 6) + col + 8)) * 512 + tS] = pv1;
}

// ---------------- alpha/beta recurrence: ONE WAVE per b ----------------
// Independent reduction chains paired so dependent shfl chains interleave.
__global__ __launch_bounds__(64) void scan_kernel(
    const float* __restrict__ g_pe, const float* __restrict__ noise,
    float* __restrict__ beta_all)
{
  const int b = blockIdx.x, lane = threadIdx.x;
  const float* pe = g_pe + ((size_t)b << 15);   // b*64*512
  float alpha[8];
#pragma unroll
  for (int i = 0; i < 8; ++i) alpha[i] = 0.f;
  if (lane == 0) alpha[0] = 1.f;

  for (int s = 0; s < T_DEC; ++s) {
    const float* nrow = noise + ((size_t)s * B + b) * T_ENC + lane * 8;
    float4 n0 = *(const float4*)nrow;
    float4 n1 = *(const float4*)(nrow + 4);
    float nz[8] = {n0.x, n0.y, n0.z, n0.w, n1.x, n1.y, n1.z, n1.w};
    const float* psm = pe + (size_t)s * 512 + lane * 8;
    const float* pec = pe + (size_t)(32 + s) * 512 + lane * 8;
    float4 m0 = *(const float4*)psm;
    float4 m1 = *(const float4*)(psm + 4);
    float4 e0 = *(const float4*)pec;
    float4 e1 = *(const float4*)(pec + 4);
    float smv[8] = {m0.x, m0.y, m0.z, m0.w, m1.x, m1.y, m1.z, m1.w};
    float ec[8]  = {e0.x, e0.y, e0.z, e0.w, e1.x, e1.y, e1.z, e1.w};
    float p[8];
#pragma unroll
    for (int i = 0; i < 8; ++i) p[i] = fsigmoid(smv[i] + nz[i]);
    // serial per-lane sums (chain A: log-cumsum; chain B: max)
    float lgv[8], lci[8], run = 0.f;
#pragma unroll
    for (int i = 0; i < 8; ++i) {
      float omp = fminf(fmaxf(1.f - p[i], 1e-10f), 1.f);
      lgv[i] = __logf(omp);
      run += lgv[i];
      lci[i] = run;
    }
    float mloc = ec[0];
#pragma unroll
    for (int i = 1; i < 8; ++i) mloc = fmaxf(mloc, ec[i]);
    // paired independent reductions (shfl chains interleave)
    float ex1 = wexcl(run, lane);
    float mx  = wredmax(mloc);
    float cp[8], ao[8], eu[8];
#pragma unroll
    for (int i = 0; i < 8; ++i) {
      float incl = lci[i] + ex1;
      cp[i] = __expf(incl - lgv[i]);               // exclusive cumprod
      float cpc = fminf(fmaxf(cp[i], 1e-10f), 1.f);
      ao[i] = alpha[i] * __builtin_amdgcn_rcpf(cpc);
      eu[i] = __expf(ec[i] - mx);
    }
    float run2 = 0.f, lc2[8], run3 = 0.f, c1[8];
#pragma unroll
    for (int i = 0; i < 8; ++i) {
      run2 += ao[i]; lc2[i] = run2;
      run3 += eu[i]; c1[i] = run3;
    }
    float ex2 = wexcl(run2, lane);
    float ex3 = wexcl(run3, lane);
    float alpha_new[8];
#pragma unroll
    for (int i = 0; i < 8; ++i) {
      alpha_new[i] = p[i] * cp[i] * (lc2[i] + ex2);
      c1[i] += ex3;
    }
    float r[8];
#pragma unroll
    for (int i = 0; i < 8; ++i) {
      float up = __shfl_up(c1[i], 1, 64);
      float prev = (lane == 0) ? 0.f : up;
      float denom = fmaxf(c1[i] - prev, 1e-10f);
      r[i] = alpha_new[i] * __builtin_amdgcn_rcpf(denom);
    }
    float run4 = 0.f, c2[8];
#pragma unroll
    for (int i = 0; i < 8; ++i) { run4 += r[i]; c2[i] = run4; }
    float ex4 = wexcl(run4, lane);
#pragma unroll
    for (int i = 0; i < 8; ++i) c2[i] += ex4;
    float c2_7 = c2[7];
    float dn[8];
#pragma unroll
    for (int i = 0; i < 8; ++i) dn[i] = __shfl_down(c2[i], 1, 64);
    float up7 = __shfl_up(c2_7, 1, 64);
    float beta[8];
#pragma unroll
    for (int i = 0; i < 8; ++i) {
      float hi = (i == 0) ? c2_7 : ((lane == 63) ? c2_7 : dn[i - 1]);
      float lo = (i == 0) ? ((lane == 0) ? 0.f : up7) : c2[i - 1];
      beta[i] = eu[i] * (hi - lo);
    }
    float* bp = beta_all + ((size_t)(b * T_DEC + s)) * T_ENC + lane * 8;
    *(float4*)bp       = (float4){beta[0], beta[1], beta[2], beta[3]};
    *(float4*)(bp + 4) = (float4){beta[4], beta[5], beta[6], beta[7]};
#pragma unroll
    for (int i = 0; i < 8; ++i) alpha[i] = alpha_new[i];
  }
}

// ---------------- context: ctx[b,s,:] = sum_t beta[b,s,t] * enc[b,t,:] -----
__global__ __launch_bounds__(256) void context_kernel(
    const float* __restrict__ beta_all, const float* __restrict__ enc,
    float* __restrict__ A_comb)
{
  __shared__ float smem[T_ENC * 36];                 // [t][36] padded, 73.7 KB
  const int b = blockIdx.x, e0 = blockIdx.y << 6;
  const int tid = threadIdx.x;
  const float* bp = beta_all + (size_t)b * T_DEC * T_ENC;
  for (int i = tid; i < T_DEC * T_ENC; i += 256) {
    int s2 = i >> 9, t = i & 511;
    smem[t * 36 + s2] = bp[i];
  }
  __syncthreads();
  const int el = tid & 63, tg = tid >> 6;
  float4 a8[8];
#pragma unroll
  for (int u = 0; u < 8; ++u) a8[u] = (float4){0.f, 0.f, 0.f, 0.f};
  const float* ep = enc + (size_t)b * T_ENC * E + e0 + el;
  for (int t = tg; t < T_ENC; t += 4) {
    float v = ep[(size_t)t * E];
    const float4* bt = (const float4*)&smem[t * 36];
#pragma unroll
    for (int u = 0; u < 8; ++u) {
      float4 bv = bt[u];
      a8[u].x += bv.x * v; a8[u].y += bv.y * v;
      a8[u].z += bv.z * v; a8[u].w += bv.w * v;
    }
  }
  __syncthreads();
#pragma unroll
  for (int u = 0; u < 8; ++u) {
    smem[((tg * T_DEC + u * 4 + 0) << 6) + el] = a8[u].x;
    smem[((tg * T_DEC + u * 4 + 1) << 6) + el] = a8[u].y;
    smem[((tg * T_DEC + u * 4 + 2) << 6) + el] = a8[u].z;
    smem[((tg * T_DEC + u * 4 + 3) << 6) + el] = a8[u].w;
  }
  __syncthreads();
  for (int o = tid; o < T_DEC * 64; o += 256) {
    int s2 = o >> 6, e = o & 63;
    float v = smem[(s2 << 6) + e] + smem[((T_DEC + s2) << 6) + e]
            + smem[((2 * T_DEC + s2) << 6) + e] + smem[((3 * T_DEC + s2) << 6) + e];
    A_comb[((size_t)(b * T_DEC + s2)) * (2 * E) + e0 + e] = v;
  }
}

// ---------------- attn = tanh(A_comb[1024,512] @ Wt[512,256]) -> bf16 ------
__global__ __launch_bounds__(256) void comb_tanh_kernel(
    const float* __restrict__ A, const float* __restrict__ Wt,
    unsigned short* __restrict__ attn_bf)
{
  __shared__ float As[64][68];
  __shared__ float Ws[64][68];
  const int tid = threadIdx.x, tx = tid & 15, ty = tid >> 4;
  const int row0 = blockIdx.y * 64, col0 = blockIdx.x * 64;
  float acc[4][4];
#pragma unroll
  for (int i = 0; i < 4; i++)
#pragma unroll
    for (int jj = 0; jj < 4; jj++) acc[i][jj] = 0.f;

  for (int k0 = 0; k0 < 2 * E; k0 += 64) {
#pragma unroll
    for (int ss = 0; ss < 4; ss++) {
      int i = (ss << 4) + ty;
      int jj = tx << 2;
      float4 av = *(const float4*)(A + (size_t)(row0 + i) * (2 * E) + k0 + jj);
      As[jj][i] = av.x; As[jj + 1][i] = av.y; As[jj + 2][i] = av.z; As[jj + 3][i] = av.w;
      float4 wv = *(const float4*)(Wt + (size_t)(k0 + i) * E + col0 + jj);
      *(float4*)&Ws[i][jj] = wv;
    }
    __syncthreads();
#pragma unroll
    for (int kk = 0; kk < 64; kk++) {
      const float4 af = *(const float4*)&As[kk][ty << 2];
      const float4 bf = *(const float4*)&Ws[kk][tx << 2];
      acc[0][0] += af.x * bf.x; acc[0][1] += af.x * bf.y; acc[0][2] += af.x * bf.z; acc[0][3] += af.x * bf.w;
      acc[1][0] += af.y * bf.x; acc[1][1] += af.y * bf.y; acc[1][2] += af.y * bf.z; acc[1][3] += af.y * bf.w;
      acc[2][0] += af.z * bf.x; acc[2][1] += af.z * bf.y; acc[2][2] += af.z * bf.z; acc[2][3] += af.z * bf.w;
      acc[3][0] += af.w * bf.x; acc[3][1] += af.w * bf.y; acc[3][2] += af.w * bf.z; acc[3][3] += af.w * bf.w;
    }
    __syncthreads();
  }
#pragma unroll
  for (int i = 0; i < 4; i++) {
    ushort4 o;
    o.x = f2bf(ftanh(acc[i][0])); o.y = f2bf(ftanh(acc[i][1]));
    o.z = f2bf(ftanh(acc[i][2])); o.w = f2bf(ftanh(acc[i][3]));
    *(ushort4*)(attn_bf + (size_t)(row0 + (ty << 2) + i) * E + col0 + (tx << 2)) = o;
  }
}

// ---------------- projection: (col-panel, M-half) per block ---------------
__global__ __launch_bounds__(256) void proj_mfma(
    const unsigned short* __restrict__ A, const unsigned short* __restrict__ Bw,
    const float* __restrict__ bias, float* __restrict__ Y)
{
  __shared__ unsigned short wl[64][264];   // 33.8 KB
  __shared__ float tile[64][68];           // 17.4 KB
  const int tid = threadIdx.x;
  const int wave = tid >> 6, lane = tid & 63;
  const int m = lane & 15, q = lane >> 4;
  const int col0 = (blockIdx.x >> 1) * 64;
  const int mt0 = (blockIdx.x & 1) * 8;
#pragma unroll
  for (int u = 0; u < 16; ++u) {
    int f = tid + (u << 8);
    int r = f >> 6, c = (f & 63) << 2;
    *(ushort4*)&wl[r][c] = *(const ushort4*)(Bw + (size_t)(col0 + r) * E + c);
  }
  __syncthreads();

  for (int mt = mt0; mt < mt0 + 8; ++mt) {
    const int rowa = mt * 64 + wave * 16;
    floatx4 acc0 = {0.f, 0.f, 0.f, 0.f}, acc1 = acc0, acc2 = acc0, acc3 = acc0;
    const unsigned short* ar = A + (size_t)(rowa + m) * E + q * 8;
#pragma unroll
    for (int k0 = 0; k0 < E; k0 += 32) {
      short8 af = *(const short8*)(ar + k0);
      short8 b0 = *(const short8*)&wl[ 0 + m][q * 8 + k0];
      short8 b1 = *(const short8*)&wl[16 + m][q * 8 + k0];
      short8 b2 = *(const short8*)&wl[32 + m][q * 8 + k0];
      short8 b3 = *(const short8*)&wl[48 + m][q * 8 + k0];
      acc0 = __builtin_amdgcn_mfma_f32_16x16x32_bf16(af, b0, acc0, 0, 0, 0);
      acc1 = __builtin_amdgcn_mfma_f32_16x16x32_bf16(af, b1, acc1, 0, 0, 0);
      acc2 = __builtin_amdgcn_mfma_f32_16x16x32_bf16(af, b2, acc2, 0, 0, 0);
      acc3 = __builtin_amdgcn_mfma_f32_16x16x32_bf16(af, b3, acc3, 0, 0, 0);
    }
    const int rl = wave * 16 + q * 4;
#pragma unroll
    for (int r = 0; r < 4; r++) {
      tile[rl + r][ 0 + m] = acc0[r];
      tile[rl + r][16 + m] = acc1[r];
      tile[rl + r][32 + m] = acc2[r];
      tile[rl + r][48 + m] = acc3[r];
    }
    __syncthreads();
    const int row = tid >> 2, seg = tid & 3;
    const size_t yb = ((size_t)mt * 64 + row) * VOCAB + col0;
#pragma unroll
    for (int u = 0; u < 4; u++) {
      int cc = seg * 16 + u * 4;
      float4 v = *(const float4*)&tile[row][cc];
      float4 bb = *(const float4*)(bias + col0 + cc);
      v.x += bb.x; v.y += bb.y; v.z += bb.z; v.w += bb.w;
      *(float4*)(Y + yb + cc) = v;
    }
    __syncthreads();
  }
}

// ---------------- launch ----------------
extern "C" void kernel_launch(void* const* d_in, const int* in_sizes, int n_in,
                              void* d_out, int out_size, void* d_ws, size_t ws_size,
                              hipStream_t stream)
{
  (void)in_sizes; (void)n_in; (void)out_size; (void)ws_size;
  const float* enc    = (const float*)d_in[0];
  const int*   dec    = (const int*)d_in[1];
  const float* h0     = (const float*)d_in[2];
  const float* noise  = (const float*)d_in[3];
  const float* emb    = (const float*)d_in[4];
  const float* W_ih   = (const float*)d_in[5];
  const float* b_ih   = (const float*)d_in[6];
  const float* W_hh   = (const float*)d_in[7];
  const float* b_hh   = (const float*)d_in[8];
  const float* Wm     = (const float*)d_in[9];
  const float* Vm     = (const float*)d_in[10];
  const float* bm     = (const float*)d_in[11];
  const float* vvm    = (const float*)d_in[12];
  const float* gm     = (const float*)d_in[13];
  const float* vbm    = (const float*)d_in[14];
  const float* rmp    = (const float*)d_in[15];
  const float* Wc     = (const float*)d_in[16];
  const float* Vc     = (const float*)d_in[17];
  const float* bc     = (const float*)d_in[18];
  const float* vvc    = (const float*)d_in[19];
  const float* gc     = (const float*)d_in[20];
  const float* vbc    = (const float*)d_in[21];
  const float* rcp_   = (const float*)d_in[22];
  const float* W_comb = (const float*)d_in[23];
  const float* W_proj = (const float*)d_in[24];
  const float* b_proj = (const float*)d_in[25];

  float* ws = (float*)d_ws;
  float* encW    = ws + OFF_ENCW;
  float* w_effm  = ws + OFF_WEFFM;
  float* w_effc  = ws + OFF_WEFFC;
  float* bsum    = ws + OFF_BSUM;
  float* Xih     = ws + OFF_XIH;
  float* W_hhT   = ws + OFF_WHHT;
  float* W_combT = ws + OFF_WCOMBT;
  unsigned short* attn_bf = (unsigned short*)(ws + OFF_ATTNB);
  unsigned short* Wp_bf   = (unsigned short*)(ws + OFF_WPBF);

  float* outF = (float*)d_out;
  float* embX     = outF + OUT_EMBX;     // scratch in d_out, all consumed
  float* beta_all = outF + OUT_BETA;     //   before proj_mfma overwrites it
  float* A_comb   = outF + OUT_ACOMB;
  float* h_all    = outF + OUT_HALL;
  float* g_hv     = outF + OUT_HV;
  float* g_pe     = outF + OUT_PE;
  float* Vmc      = outF + OUT_VMC;
  float* zero512  = outF + OUT_ZERO;
  unsigned short* Whi = (unsigned short*)(outF + OUT_WHI);
  unsigned short* Wlo = (unsigned short*)(outF + OUT_WLO);
  float* bias512  = outF + OUT_B512;

  // 1. all step-invariant prep in ONE launch (indep. branches co-schedule)
  prep_all<<<9475, 256, 0, stream>>>(vvm, gm, w_effm, vvc, gc, w_effc,
                                     b_ih, b_hh, bsum, bm, bc, bias512,
                                     Vm, Vc, Vmc, zero512, Wm, Wc, Whi, Wlo,
                                     W_hh, W_hhT, W_comb, W_combT,
                                     dec, emb, embX, W_proj, Wp_bf);
  // 2. Xih = embX @ W_ih.T + (b_ih + b_hh)
  gemm_xwt<<<dim3(E / 64, (T_DEC * B) / 64), 256, 0, stream>>>(embX, W_ih, bsum, Xih,
                                                               T_DEC * B, E, E);
  // 3. h-chain (32 blocks) + encW MFMA (256 blocks) concurrently
  hchain_enc<<<B + (B * T_ENC) / 64, 1024, 0, stream>>>(
      Xih, W_hhT, h0, A_comb, h_all, enc, Whi, Wlo, bias512, encW);
  // 4. hV = [Vm;Vc] h for all (b,s)
  gemm_xwt<<<dim3((2 * E) / 64, (T_DEC * B) / 64), 256, 0, stream>>>(
      h_all, Vmc, zero512, g_hv, T_DEC * B, 2 * E, E);
  // 5. energies (exp2 path)
  energy_kernel<<<dim3(B, 16, 2), 512, 0, stream>>>(
      encW, g_hv, w_effm, w_effc, vbm, rmp, vbc, rcp_, g_pe);
  // 6. alpha/beta scans
  scan_kernel<<<B, 64, 0, stream>>>(g_pe, noise, beta_all);
  // 7-9. context, attn, projection
  context_kernel<<<dim3(B, 4), 256, 0, stream>>>(beta_all, enc, A_comb);
  comb_tanh_kernel<<<dim3(E / 64, (T_DEC * B) / 64), 256, 0, stream>>>(A_comb, W_combT, attn_bf);
  proj_mfma<<<2 * (VOCAB / 64), 256, 0, stream>>>(attn_bf, Wp_bf, b_proj, outF);
}